// Round 6
// baseline (809.059 us; speedup 1.0000x reference)
//
#include <hip/hip_runtime.h>

typedef unsigned int   u32;
typedef unsigned short u16;

typedef float  f32x4  __attribute__((ext_vector_type(4)));
typedef u32    u32x4  __attribute__((ext_vector_type(4)));
typedef __bf16 bf16x8 __attribute__((ext_vector_type(8)));

union FragU { u16 us[8]; u32x4 q; bf16x8 v; };

__device__ __forceinline__ u32 f2u(float x){ union{float f;u32 u;}c; c.f=x; return c.u; }
__device__ __forceinline__ float u2f(u32 u){ union{float f;u32 u;}c; c.u=u; return c.f; }
__device__ __forceinline__ u16 bfhi(float x){ u32 u=f2u(x); return (u16)((u + 0x7fffu + ((u>>16)&1u))>>16); }
__device__ __forceinline__ float bff(u16 h){ return u2f(((u32)h)<<16); }
// fp32 -> (hi,lo) bf16 pair packed in one u32 (low half = hi part)
__device__ __forceinline__ u32 pack2(float x){
  u16 h = bfhi(x);
  u16 l = bfhi(x - bff(h));
  return (u32)h | ((u32)l << 16);
}

__device__ __forceinline__ void gload16(const void* g, void* l){
  __builtin_amdgcn_global_load_lds(
      (const __attribute__((address_space(1))) unsigned int*)g,
      (__attribute__((address_space(3))) unsigned int*)l, 16, 0, 0);
}

// ---------------------------------------------------------------------------
// Elementwise fp32 -> packed split-bf16 (u32 per element).
// ---------------------------------------------------------------------------
__global__ __launch_bounds__(256)
void split_pack(const float* __restrict__ in, u32* __restrict__ out, int n4)
{
  int i = blockIdx.x*256 + threadIdx.x;
  const int stride = gridDim.x*256;
  for (; i < n4; i += stride){
    float4 v = reinterpret_cast<const float4*>(in)[i];
    reinterpret_cast<u32x4*>(out)[i] =
      (u32x4){ pack2(v.x), pack2(v.y), pack2(v.z), pack2(v.w) };
  }
}

// ---------------------------------------------------------------------------
// 256x192-tile GEMM on pre-packed split-bf16 (full-coverage for M=2048,N=6144
// -> 256 blocks).  8 waves, wave tile 128x48, BK=64 bf16, dbuf 112KB LDS,
// 2 fat phases/K-tile, counted vmcnt(3), both-sides swizzle, setprio.
// ---------------------------------------------------------------------------
__global__ __launch_bounds__(512, 2)
void gemm_pkA(const u32* __restrict__ A, const u32* __restrict__ B,
              float* __restrict__ C, int M, int N, int K)  // K = u32 per row
{
  extern __shared__ char smem[];   // 114688 B: [buf2][ A 32KB | B 24KB ]
  const int tid  = threadIdx.x;
  const int lane = tid & 63;
  const int w    = tid >> 6;       // 0..7
  const int wm = w >> 2, wn = w & 3;
  const int ln = lane & 15, lg = lane >> 4;

  const int nbm = M >> 8;          // 256-row tiles
  const int nbn = N / 192;
  const int nwg = nbm * nbn;
  const int swz = (blockIdx.x & 7) * (nwg >> 3) + (blockIdx.x >> 3);
  const int bm = swz % nbm, bn = swz / nbm;

  const size_t rbA = (size_t)K * 4;          // row bytes
  const int lrow  = lane >> 3;               // 0..7
  const int lslot = (lane & 7) ^ (lrow & 7); // pre-swizzled source slot
  const char* As0 = (const char*)A + (size_t)(bm*256 + w*8 + lrow)*rbA + lslot*16;
  const char* Bs0 = (const char*)B + (size_t)(bn*192 + w*8 + lrow)*rbA + lslot*16;

  auto stA = [&](int buf, int t) {
    const char* s = As0 + ((size_t)t << 7);
    char* d = smem + buf*57344 + w*1024;
    gload16(s,            d);
    gload16(s +  64*rbA,  d + 8192);
    gload16(s + 128*rbA,  d + 16384);
    gload16(s + 192*rbA,  d + 24576);
  };
  auto stB = [&](int buf, int t) {
    const char* s = Bs0 + ((size_t)t << 7);
    char* d = smem + buf*57344 + 32768 + w*1024;
    gload16(s,            d);
    gload16(s +  64*rbA,  d + 8192);
    gload16(s + 128*rbA,  d + 16384);
  };

  f32x4 z = {0.f,0.f,0.f,0.f};
  f32x4 acc[8][3];
  #pragma unroll
  for (int i=0;i<8;i++){
    #pragma unroll
    for (int j=0;j<3;j++) acc[i][j] = z;
  }

  const int nt = K >> 5;           // K-tiles of 32 u32 (=64 bf16)
  stA(0, 0); stB(0, 0);            // 7 loads
  if (nt > 1) { stB(1, 1);         // +3
    asm volatile("s_waitcnt vmcnt(3)" ::: "memory");   // tile0's 7 complete
  } else {
    asm volatile("s_waitcnt vmcnt(0)" ::: "memory");
  }
  __builtin_amdgcn_s_barrier();
  asm volatile("" ::: "memory");

  const int lx7 = ln & 7;

  for (int t = 0; t < nt; ++t){
    const int cur = t & 1;
    const char* bufc = smem + cur*57344;

    // ---- phase 0: all B frags + A m-frags 0..3; stage A(t+1) ----
    FragU bfr[3][2];
    #pragma unroll
    for (int ni=0; ni<3; ni++){
      const int rofs = 32768 + (wn*48 + ni*16 + ln)*128;
      #pragma unroll
      for (int ks=0; ks<2; ks++)
        bfr[ni][ks].q = *reinterpret_cast<const u32x4*>(bufc + rofs + (((ks*4+lg)^lx7)<<4));
    }
    FragU af[4][2];
    #pragma unroll
    for (int mf=0; mf<4; mf++){
      const int rofs = (wm*128 + mf*16 + ln)*128;
      #pragma unroll
      for (int ks=0; ks<2; ks++)
        af[mf][ks].q = *reinterpret_cast<const u32x4*>(bufc + rofs + (((ks*4+lg)^lx7)<<4));
    }
    if (t+1 < nt) stA(cur^1, t+1);
    __builtin_amdgcn_s_barrier();
    __builtin_amdgcn_s_setprio(1);
    #pragma unroll
    for (int ks=0; ks<2; ks++){
      #pragma unroll
      for (int mf=0; mf<4; mf++){
        #pragma unroll
        for (int ni=0; ni<3; ni++)
          acc[mf][ni] = __builtin_amdgcn_mfma_f32_16x16x32_bf16(af[mf][ks].v, bfr[ni][ks].v, acc[mf][ni], 0,0,0);
      }
    }
    __builtin_amdgcn_s_setprio(0);
    asm volatile("s_waitcnt lgkmcnt(0)" ::: "memory");
    __builtin_amdgcn_s_barrier();

    // ---- phase 1: A m-frags 4..7; stage B(t+2) -> B[cur] ----
    FragU ag[4][2];
    #pragma unroll
    for (int mf=0; mf<4; mf++){
      const int rofs = (wm*128 + (mf+4)*16 + ln)*128;
      #pragma unroll
      for (int ks=0; ks<2; ks++)
        ag[mf][ks].q = *reinterpret_cast<const u32x4*>(bufc + rofs + (((ks*4+lg)^lx7)<<4));
    }
    if (t+2 < nt) stB(cur, t+2);
    __builtin_amdgcn_s_barrier();
    __builtin_amdgcn_s_setprio(1);
    #pragma unroll
    for (int ks=0; ks<2; ks++){
      #pragma unroll
      for (int mf=0; mf<4; mf++){
        #pragma unroll
        for (int ni=0; ni<3; ni++)
          acc[mf+4][ni] = __builtin_amdgcn_mfma_f32_16x16x32_bf16(ag[mf][ks].v, bfr[ni][ks].v, acc[mf+4][ni], 0,0,0);
      }
    }
    __builtin_amdgcn_s_setprio(0);
    if (t+1 < nt){
      if (t+2 < nt) asm volatile("s_waitcnt vmcnt(3)" ::: "memory");
      else          asm volatile("s_waitcnt vmcnt(0)" ::: "memory");
    }
    __builtin_amdgcn_s_barrier();
    asm volatile("" ::: "memory");
  }

  #pragma unroll
  for (int mi=0; mi<8; mi++){
    #pragma unroll
    for (int ni=0; ni<3; ni++){
      const int row0 = bm*256 + wm*128 + mi*16 + lg*4;
      const int col  = bn*192 + wn*48  + ni*16 + ln;
      #pragma unroll
      for (int r=0; r<4; r++)
        C[(size_t)(row0+r)*N + col] = acc[mi][ni][r];
    }
  }
}

// ---------------------------------------------------------------------------
// 128x256-tile variant (full-coverage for M=2048,N=4096: 256 blocks).
// 2 fat phases/K-tile; wave = 64x64, acc[4][4].  LDS 96KB.
// ---------------------------------------------------------------------------
__global__ __launch_bounds__(512, 2)
void gemm_pkB(const u32* __restrict__ A, const u32* __restrict__ B,
              float* __restrict__ C, int M, int N, int K)  // K = u32 per row
{
  extern __shared__ char smem[];   // 98304 B: [buf2][ A 16KB | B 32KB ]
  const int tid  = threadIdx.x;
  const int lane = tid & 63;
  const int w    = tid >> 6;       // 0..7
  const int wm = w >> 2, wn = w & 3;
  const int ln = lane & 15, lg = lane >> 4;

  const int nbm = M >> 7, nbn = N >> 8;
  const int nwg = nbm * nbn;
  const int swz = (blockIdx.x & 7) * (nwg >> 3) + (blockIdx.x >> 3);
  const int bm = swz % nbm, bn = swz / nbm;

  const size_t rbA = (size_t)K * 4;          // row bytes
  const int lrow  = lane >> 3;               // 0..7
  const int lslot = (lane & 7) ^ (lrow & 7); // pre-swizzled source slot
  const char* As0 = (const char*)A + (size_t)(bm*128 + w*8 + lrow)*rbA + lslot*16;
  const char* Bs0 = (const char*)B + (size_t)(bn*256 + w*8 + lrow)*rbA + lslot*16;

  auto stA = [&](int buf, int t) {
    const char* s = As0 + ((size_t)t << 7);
    char* d = smem + buf*49152 + w*1024;
    gload16(s,            d);
    gload16(s +  64*rbA,  d + 8192);
  };
  auto stB = [&](int buf, int t) {
    const char* s = Bs0 + ((size_t)t << 7);
    char* d = smem + buf*49152 + 16384 + w*1024;
    gload16(s,            d);
    gload16(s +  64*rbA,  d + 8192);
    gload16(s + 128*rbA,  d + 16384);
    gload16(s + 192*rbA,  d + 24576);
  };

  f32x4 z = {0.f,0.f,0.f,0.f};
  f32x4 acc[4][4];
  #pragma unroll
  for (int i=0;i<4;i++){
    #pragma unroll
    for (int j=0;j<4;j++) acc[i][j] = z;
  }

  const int nt = K >> 5;           // K-tiles of 32 u32 (=64 bf16)
  stA(0, 0); stB(0, 0);            // 6 loads
  if (nt > 1) { stB(1, 1);         // +4
    asm volatile("s_waitcnt vmcnt(4)" ::: "memory");   // tile0's 6 complete
  } else {
    asm volatile("s_waitcnt vmcnt(0)" ::: "memory");
  }
  __builtin_amdgcn_s_barrier();
  asm volatile("" ::: "memory");

  const int boff0 = 16384;
  const int lx7   = ln & 7;

  for (int t = 0; t < nt; ++t){
    const int cur = t & 1;
    const char* bufc = smem + cur*49152;

    // ---- phase 0: all B frags + A m-frags 0..1; stage A(t+1) ----
    FragU bfr[4][2];
    #pragma unroll
    for (int ni=0; ni<4; ni++){
      const int rofs = boff0 + (wn*64 + ni*16 + ln)*128;
      #pragma unroll
      for (int ks=0; ks<2; ks++)
        bfr[ni][ks].q = *reinterpret_cast<const u32x4*>(bufc + rofs + (((ks*4+lg)^lx7)<<4));
    }
    FragU af[2][2];
    #pragma unroll
    for (int mf=0; mf<2; mf++){
      const int rofs = (wm*64 + mf*16 + ln)*128;
      #pragma unroll
      for (int ks=0; ks<2; ks++)
        af[mf][ks].q = *reinterpret_cast<const u32x4*>(bufc + rofs + (((ks*4+lg)^lx7)<<4));
    }
    if (t+1 < nt) stA(cur^1, t+1);
    __builtin_amdgcn_s_barrier();
    __builtin_amdgcn_s_setprio(1);
    #pragma unroll
    for (int ks=0; ks<2; ks++){
      #pragma unroll
      for (int mf=0; mf<2; mf++){
        #pragma unroll
        for (int ni=0; ni<4; ni++)
          acc[mf][ni] = __builtin_amdgcn_mfma_f32_16x16x32_bf16(af[mf][ks].v, bfr[ni][ks].v, acc[mf][ni], 0,0,0);
      }
    }
    __builtin_amdgcn_s_setprio(0);
    asm volatile("s_waitcnt lgkmcnt(0)" ::: "memory");
    __builtin_amdgcn_s_barrier();

    // ---- phase 1: A m-frags 2..3; stage B(t+2) -> B[cur] ----
    FragU ag[2][2];
    #pragma unroll
    for (int mf=0; mf<2; mf++){
      const int rofs = (wm*64 + (mf+2)*16 + ln)*128;
      #pragma unroll
      for (int ks=0; ks<2; ks++)
        ag[mf][ks].q = *reinterpret_cast<const u32x4*>(bufc + rofs + (((ks*4+lg)^lx7)<<4));
    }
    if (t+2 < nt) stB(cur, t+2);
    __builtin_amdgcn_s_barrier();
    __builtin_amdgcn_s_setprio(1);
    #pragma unroll
    for (int ks=0; ks<2; ks++){
      #pragma unroll
      for (int mf=0; mf<2; mf++){
        #pragma unroll
        for (int ni=0; ni<4; ni++)
          acc[mf+2][ni] = __builtin_amdgcn_mfma_f32_16x16x32_bf16(ag[mf][ks].v, bfr[ni][ks].v, acc[mf+2][ni], 0,0,0);
      }
    }
    __builtin_amdgcn_s_setprio(0);
    if (t+1 < nt){
      if (t+2 < nt) asm volatile("s_waitcnt vmcnt(4)" ::: "memory");
      else          asm volatile("s_waitcnt vmcnt(0)" ::: "memory");
    }
    __builtin_amdgcn_s_barrier();
    asm volatile("" ::: "memory");
  }

  #pragma unroll
  for (int mi=0; mi<4; mi++){
    #pragma unroll
    for (int ni=0; ni<4; ni++){
      const int row0 = bm*128 + wm*64 + mi*16 + lg*4;
      const int col  = bn*256 + wn*64 + ni*16 + ln;
      #pragma unroll
      for (int r=0; r<4; r++)
        C[(size_t)(row0+r)*N + col] = acc[mi][ni][r];
    }
  }
}

// ---------------------------------------------------------------------------
// Gather old paged cache into contiguous PACKED ws buffers.
// k_all  : u32 [B][HKV][1024][128]   v_allT : u32 [B][HKV][128][1024]
// ---------------------------------------------------------------------------
__global__ __launch_bounds__(256)
void copy_cache(const float* __restrict__ k_cache, const float* __restrict__ v_cache,
                const int* __restrict__ page_table,
                u32* __restrict__ k_all, u32* __restrict__ v_allT)
{
  __shared__ float tb[32][129];
  const int id = blockIdx.x;
  const int jt = id & 31, h = (id>>5)&7, b = id>>8;
  const int tid = threadIdx.x;
  const int j0 = jt*32;
  {
    int r = tid>>3, c = tid&7;
    int j = j0 + r;
    int page = page_table[b*64 + (j>>4)];
    int slot = j & 15;
    const float* ks = k_cache + (size_t)((page*16 + slot)*8 + h)*128;
    const float* vs = v_cache + (size_t)((page*16 + slot)*8 + h)*128;
    u32* kd = k_all + ((size_t)(b*8+h)*1024 + j)*128;
    #pragma unroll
    for (int i=0;i<4;i++){
      int d0 = (c + 8*i)*4;
      float4 k4 = *reinterpret_cast<const float4*>(ks + d0);
      *reinterpret_cast<u32x4*>(kd + d0) =
        (u32x4){ pack2(k4.x), pack2(k4.y), pack2(k4.z), pack2(k4.w) };
      float4 v4 = *reinterpret_cast<const float4*>(vs + d0);
      tb[r][d0+0]=v4.x; tb[r][d0+1]=v4.y; tb[r][d0+2]=v4.z; tb[r][d0+3]=v4.w;
    }
  }
  __syncthreads();
  {
    int dout = tid>>1, jh = tid&1;
    u32* vd = v_allT + ((size_t)(b*8+h)*128 + dout)*1024 + j0 + jh*16;
    #pragma unroll
    for (int i=0;i<4;i++){
      u32x4 o;
      o.x = pack2(tb[jh*16 + i*4 + 0][dout]);
      o.y = pack2(tb[jh*16 + i*4 + 1][dout]);
      o.z = pack2(tb[jh*16 + i*4 + 2][dout]);
      o.w = pack2(tb[jh*16 + i*4 + 3][dout]);
      *reinterpret_cast<u32x4*>(vd + i*4) = o;
    }
  }
}

// ---------------------------------------------------------------------------
// Per-head RMSNorm + partial RoPE + scatter new K/V (packed) into k_all/v_allT.
// ---------------------------------------------------------------------------
__global__ __launch_bounds__(256)
void norm_rope_scatter(float* __restrict__ qkv, const float* __restrict__ cosT,
                       const float* __restrict__ sinT, const int* __restrict__ positions,
                       const int* __restrict__ cache_seqlens,
                       const float* __restrict__ qw, const float* __restrict__ kw,
                       u32* __restrict__ k_all, u32* __restrict__ v_allT)
{
  const int t = blockIdx.x;
  const int lane = threadIdx.x & 63;
  const int w = threadIdx.x >> 6;
  const int b = t >> 9;        // QL = 512
  const int q = t & 511;
  const int pos  = positions[t];
  const int cpos = cache_seqlens[b] + q;
  for (int it=0; it<12; ++it){
    int h = it*4 + w;          // 0..47
    float* xp = qkv + (size_t)t*6144 + h*128 + 2*lane;
    float2 x = *reinterpret_cast<const float2*>(xp);
    if (h < 40){               // q + k heads get RMSNorm + RoPE
      float ss = x.x*x.x + x.y*x.y;
      #pragma unroll
      for (int mk=1; mk<64; mk<<=1) ss += __shfl_xor(ss, mk);
      float var = ss*(1.0f/128.0f) + 1e-6f;
      float rq = rsqrtf(var);
      rq = rq*(1.5f - 0.5f*var*rq*rq);   // Newton refine
      const float* wt = (h<32) ? qw : kw;
      x.x *= rq*wt[2*lane]; x.y *= rq*wt[2*lane+1];
      float px = __shfl_xor(x.x, 16);
      float py = __shfl_xor(x.y, 16);
      if (lane < 32){
        int ci = pos*32 + 2*(lane&15);
        float2 cc = *reinterpret_cast<const float2*>(cosT + ci);
        float2 sc = *reinterpret_cast<const float2*>(sinT + ci);
        if (lane < 16){ x.x = x.x*cc.x - px*sc.x; x.y = x.y*cc.y - py*sc.y; }
        else          { x.x = x.x*cc.x + px*sc.x; x.y = x.y*cc.y + py*sc.y; }
      }
    }
    if (h < 32){
      *reinterpret_cast<float2*>(xp) = x;   // q back in place (fp32)
    } else if (h < 40){
      u32* kp = k_all + ((size_t)(b*8 + (h-32))*1024 + cpos)*128 + 2*lane;
      kp[0] = pack2(x.x); kp[1] = pack2(x.y);
    } else {
      u32* vp = v_allT + ((size_t)(b*8 + (h-40))*128 + 2*lane)*1024 + cpos;
      vp[0]    = pack2(x.x);
      vp[1024] = pack2(x.y);
    }
  }
}

// ---------------------------------------------------------------------------
// Fused GQA causal attention v2.
// Block = (b, kv-head, g, 128-row q tile): 8 waves x 16 q-rows. KVBLK=32.
// K double-buffered + V single-buffered in LDS via global_load_lds with
// pre-swizzled sources; counted vmcnt; 3 raw barriers/tile; split QK chains.
// ---------------------------------------------------------------------------
__global__ __launch_bounds__(512, 4)
void attn_fused2(const float* __restrict__ qkv, const u32* __restrict__ k_all,
                 const u32* __restrict__ v_allT, const int* __restrict__ cache_seqlens,
                 u32* __restrict__ attnO)
{
  extern __shared__ char smem[];          // 64KB: K dbuf 32K | V 16K | P 16K
  u16*   Ks = (u16*)smem;                 // [2][32][256] swizzled
  u16*   Vs = (u16*)(smem + 32768);       // [128][64] swizzled
  float* Pl = (float*)(smem + 49152);     // [8][512]
  const int tid = threadIdx.x, lane = tid&63, w = tid>>6;
  const int ln = lane&15, lg = lane>>4;
  const int swzid = (blockIdx.x & 7)*64 + (blockIdx.x >> 3);  // XCD-bijective
  const int qt = swzid & 3, g = (swzid>>2)&3, kvh = (swzid>>4)&7, b = swzid>>7;
  const int cs = cache_seqlens[b];
  const int h  = kvh*4 + g;
  const int q0 = qt*128 + w*16;
  const float SCALE = 0.08838834764831845f;  // 1/sqrt(128)
  f32x4 z = {0.f,0.f,0.f,0.f};

  FragU qf[8];
  {
    const float* qp = qkv + (size_t)(b*512 + q0 + ln)*6144 + h*128;
    #pragma unroll
    for (int ks=0; ks<8; ks++){
      int d0 = ks*16 + lg*4;
      float4 v4 = *reinterpret_cast<const float4*>(qp + d0);
      qf[ks].q = (u32x4){ pack2(v4.x*SCALE), pack2(v4.y*SCALE),
                          pack2(v4.z*SCALE), pack2(v4.w*SCALE) };
    }
  }
  f32x4 O[8];
  #pragma unroll
  for (int i=0;i<8;i++) O[i] = z;
  float m[4] = {-1e30f,-1e30f,-1e30f,-1e30f};
  float l[4] = {0.f,0.f,0.f,0.f};
  const int prow0 = cs + q0 + lg*4;
  const int nt = (cs + qt*128 + 128 + 31) >> 5;
  const char* kbase = (const char*)(k_all  + (size_t)(b*8+kvh)*1024*128);
  const char* vbase = (const char*)(v_allT + (size_t)(b*8+kvh)*128*1024);

  // staging geometry (pre-swizzled global source, linear LDS dest)
  const int kr0 = 2*w + (lane>>5);     // local K row, issue 0
  const int kc  = (lane&31)*16;        // byte chunk within 512B K row
  const int vr0 = 8*w + (lane>>3);     // local V d-row, issue 0
  const int vc  = (lane&7)*16;         // byte chunk within 128B V row

  auto stK = [&](int buf, int t){
    const char* s0 = kbase + (size_t)(t*32 + kr0)*512 + (kc ^ ((kr0&7)<<4));
    gload16(s0, smem + buf*16384 + w*1024);
    const int r1 = kr0 + 16;
    const char* s1 = kbase + (size_t)(t*32 + r1)*512 + (kc ^ ((r1&7)<<4));
    gload16(s1, smem + buf*16384 + 8192 + w*1024);
  };
  auto stV = [&](int t){
    const char* s0 = vbase + (size_t)vr0*4096 + (size_t)(t*32)*4 + (vc ^ ((vr0&7)<<4));
    gload16(s0, smem + 32768 + w*1024);
    const int d1 = vr0 + 64;
    const char* s1 = vbase + (size_t)d1*4096 + (size_t)(t*32)*4 + (vc ^ ((d1&7)<<4));
    gload16(s1, smem + 32768 + 8192 + w*1024);
  };

  stK(0, 0);
  stV(0);

  for (int tile=0; tile<nt; ++tile){
    const int cur = tile & 1;
    const int kv0 = tile*32;
    const bool more = (tile+1 < nt);
    if (more) stK(cur^1, tile+1);
    // wait K(tile); leave {V(tile), K(tile+1)} in flight
    if (more) asm volatile("s_waitcnt vmcnt(4)" ::: "memory");
    else      asm volatile("s_waitcnt vmcnt(2)" ::: "memory");
    __builtin_amdgcn_s_barrier();

    // ---- S = Q K^T (split-bf16 over K'=256), two 4-deep chains ----
    const u16* Kc = Ks + cur*8192;
    f32x4 sa0=z, sa1=z, sb0=z, sb1=z;
    const int kxor = (ln&7)<<3;
    #pragma unroll
    for (int ks=0; ks<4; ks++){
      int kb = ks*32 + lg*8;
      FragU kf0, kf1;
      kf0.q = *reinterpret_cast<const u32x4*>(&Kc[(ln*256 + kb) ^ kxor]);
      kf1.q = *reinterpret_cast<const u32x4*>(&Kc[((16+ln)*256 + kb) ^ kxor]);
      sa0 = __builtin_amdgcn_mfma_f32_16x16x32_bf16(qf[ks].v, kf0.v, sa0, 0,0,0);
      sa1 = __builtin_amdgcn_mfma_f32_16x16x32_bf16(qf[ks].v, kf1.v, sa1, 0,0,0);
    }
    #pragma unroll
    for (int ks=4; ks<8; ks++){
      int kb = ks*32 + lg*8;
      FragU kf0, kf1;
      kf0.q = *reinterpret_cast<const u32x4*>(&Kc[(ln*256 + kb) ^ kxor]);
      kf1.q = *reinterpret_cast<const u32x4*>(&Kc[((16+ln)*256 + kb) ^ kxor]);
      sb0 = __builtin_amdgcn_mfma_f32_16x16x32_bf16(qf[ks].v, kf0.v, sb0, 0,0,0);
      sb1 = __builtin_amdgcn_mfma_f32_16x16x32_bf16(qf[ks].v, kf1.v, sb1, 0,0,0);
    }
    f32x4 s[2]; s[0] = sa0 + sb0; s[1] = sa1 + sb1;

    // ---- online softmax (rows = lg*4+r) ----
    float mx[4];
    #pragma unroll
    for (int r=0;r<4;r++){
      int pr = prow0 + r;
      float a0 = (kv0 + ln      <= pr) ? s[0][r] : -1e30f;
      float a1 = (kv0 + 16 + ln <= pr) ? s[1][r] : -1e30f;
      mx[r] = fmaxf(a0, a1);
    }
    #pragma unroll
    for (int off=1; off<16; off<<=1){
      #pragma unroll
      for (int r=0;r<4;r++) mx[r] = fmaxf(mx[r], __shfl_xor(mx[r], off));
    }
    float corr[4];
    #pragma unroll
    for (int r=0;r<4;r++){
      float mn = fmaxf(m[r], mx[r]);
      corr[r] = __expf(m[r] - mn);
      m[r] = mn;
    }
    float pv[2][4], ps[4] = {0.f,0.f,0.f,0.f};
    #pragma unroll
    for (int n=0;n<2;n++){
      #pragma unroll
      for (int r=0;r<4;r++){
        bool ok = (kv0 + n*16 + ln) <= (prow0 + r);
        float p = ok ? __expf(s[n][r] - m[r]) : 0.f;
        pv[n][r] = p;
        ps[r] += p;
      }
    }
    #pragma unroll
    for (int off=1; off<16; off<<=1){
      #pragma unroll
      for (int r=0;r<4;r++) ps[r] += __shfl_xor(ps[r], off);
    }
    #pragma unroll
    for (int r=0;r<4;r++) l[r] = l[r]*corr[r] + ps[r];
    #pragma unroll
    for (int nf=0; nf<8; nf++){
      #pragma unroll
      for (int r=0;r<4;r++) O[nf][r] = O[nf][r]*corr[r];
    }
    // ---- P -> per-wave LDS (swizzled), read back as hi/lo A-frags ----
    #pragma unroll
    for (int n=0;n<2;n++){
      #pragma unroll
      for (int r=0;r<4;r++){
        int row = lg*4 + r;
        Pl[w*512 + ((row*32 + n*16 + ln) ^ ((row&7)<<2))] = pv[n][r];
      }
    }
    FragU pah[2], pal[2];
    #pragma unroll
    for (int ks2=0; ks2<2; ks2++){
      int fi = (ln*32 + ks2*16 + lg*4) ^ ((ln&7)<<2);
      float4 pp = *reinterpret_cast<const float4*>(&Pl[w*512 + fi]);
      float parr[4] = {pp.x, pp.y, pp.z, pp.w};
      #pragma unroll
      for (int i=0;i<4;i++){
        u16 hh = bfhi(parr[i]);
        u16 ll = bfhi(parr[i] - bff(hh));
        pah[ks2].us[2*i] = hh; pah[ks2].us[2*i+1] = hh;
        pal[ks2].us[2*i] = ll; pal[ks2].us[2*i+1] = ll;
      }
    }
    // wait V(tile); leave K(tile+1) in flight
    if (more) asm volatile("s_waitcnt vmcnt(2)" ::: "memory");
    else      asm volatile("s_waitcnt vmcnt(0)" ::: "memory");
    __builtin_amdgcn_s_barrier();

    // ---- O += (Ph+Pl) x (Vh+Vl) ----
    #pragma unroll
    for (int nf=0; nf<8; nf++){
      int dr = nf*16 + ln;
      #pragma unroll
      for (int ks2=0; ks2<2; ks2++){
        FragU vf;
        vf.q = *reinterpret_cast<const u32x4*>(&Vs[(dr*64 + ks2*32 + lg*8) ^ ((dr&7)<<3)]);
        O[nf] = __builtin_amdgcn_mfma_f32_16x16x32_bf16(pah[ks2].v, vf.v, O[nf], 0,0,0);
        O[nf] = __builtin_amdgcn_mfma_f32_16x16x32_bf16(pal[ks2].v, vf.v, O[nf], 0,0,0);
      }
    }
    // all V reads landed in regs -> license V(tile+1) writes
    asm volatile("s_waitcnt lgkmcnt(0)" ::: "memory");
    __builtin_amdgcn_s_barrier();
    if (more) stV(tile+1);
  }

  float il[4];
  #pragma unroll
  for (int r=0;r<4;r++) il[r] = 1.0f / l[r];
  u32* op = attnO + (size_t)(b*512 + q0 + lg*4)*4096 + h*128 + ln;
  #pragma unroll
  for (int nf=0; nf<8; nf++){
    #pragma unroll
    for (int r=0;r<4;r++)
      op[(size_t)r*4096 + nf*16] = pack2(O[nf][r] * il[r]);
  }
}

// ---------------------------------------------------------------------------
extern "C" void kernel_launch(void* const* d_in, const int* in_sizes, int n_in,
                              void* d_out, int out_size, void* d_ws, size_t ws_size,
                              hipStream_t stream) {
  const float* hidden    = (const float*)d_in[0];
  const float* cosT      = (const float*)d_in[1];
  const float* sinT      = (const float*)d_in[2];
  const int*   positions = (const int*)  d_in[3];
  const float* k_cache   = (const float*)d_in[4];
  const float* v_cache   = (const float*)d_in[5];
  const int*   page_tab  = (const int*)  d_in[6];
  const int*   cache_sl  = (const int*)  d_in[7];
  const float* qkv_w     = (const float*)d_in[9];
  const float* o_w       = (const float*)d_in[10];
  const float* qnw       = (const float*)d_in[11];
  const float* knw       = (const float*)d_in[12];
  float* out = (float*)d_out;

  u32* ws      = (u32*)d_ws;
  float* qkv   = (float*)ws;                // 2048*6144        = 12582912
  u32* k_all   = ws      + 12582912;        // 4*8*1024*128     =  4194304
  u32* v_allT  = k_all   + 4194304;         //                  =  4194304
  u32* attnPk  = v_allT  + 4194304;         // 2048*4096        =  8388608
  u32* hidPk   = attnPk  + 8388608;         // 2048*4096        =  8388608
  u32* qkvwPk  = hidPk   + 8388608;         // 6144*4096        = 25165824
  u32* owPk    = qkvwPk  + 25165824;        // 4096*4096        = 16777216
  (void)in_sizes; (void)n_in; (void)out_size; (void)ws_size;

  (void)hipFuncSetAttribute(reinterpret_cast<const void*>(gemm_pkA),
                            hipFuncAttributeMaxDynamicSharedMemorySize, 114688);
  (void)hipFuncSetAttribute(reinterpret_cast<const void*>(gemm_pkB),
                            hipFuncAttributeMaxDynamicSharedMemorySize, 98304);
  (void)hipFuncSetAttribute(reinterpret_cast<const void*>(attn_fused2),
                            hipFuncAttributeMaxDynamicSharedMemorySize, 65536);

  hipLaunchKernelGGL(split_pack, dim3(1024), dim3(256), 0, stream,
                     hidden, hidPk, 2097152);
  hipLaunchKernelGGL(split_pack, dim3(1024), dim3(256), 0, stream,
                     qkv_w, qkvwPk, 6291456);
  hipLaunchKernelGGL(split_pack, dim3(1024), dim3(256), 0, stream,
                     o_w, owPk, 4194304);
  hipLaunchKernelGGL(copy_cache, dim3(1024), dim3(256), 0, stream,
                     k_cache, v_cache, page_tab, k_all, v_allT);
  hipLaunchKernelGGL(gemm_pkA, dim3(256), dim3(512), 114688, stream,
                     hidPk, qkvwPk, qkv, 2048, 6144, 4096);
  hipLaunchKernelGGL(norm_rope_scatter, dim3(2048), dim3(256), 0, stream,
                     qkv, cosT, sinT, positions, cache_sl, qnw, knw, k_all, v_allT);
  hipLaunchKernelGGL(attn_fused2, dim3(512), dim3(512), 65536, stream,
                     qkv, k_all, v_allT, cache_sl, attnPk);
  hipLaunchKernelGGL(gemm_pkB, dim3(256), dim3(512), 98304, stream,
                     attnPk, owPk, out, 2048, 4096, 4096);
}

// Round 7
// 623.268 us; speedup vs baseline: 1.2981x; 1.2981x over previous
//
#include <hip/hip_runtime.h>

typedef unsigned int   u32;
typedef unsigned short u16;

typedef float  f32x4  __attribute__((ext_vector_type(4)));
typedef u32    u32x4  __attribute__((ext_vector_type(4)));
typedef __bf16 bf16x8 __attribute__((ext_vector_type(8)));

union FragU { u16 us[8]; u32x4 q; bf16x8 v; };

__device__ __forceinline__ u32 f2u(float x){ union{float f;u32 u;}c; c.f=x; return c.u; }
__device__ __forceinline__ float u2f(u32 u){ union{float f;u32 u;}c; c.u=u; return c.f; }
__device__ __forceinline__ u16 bfhi(float x){ u32 u=f2u(x); return (u16)((u + 0x7fffu + ((u>>16)&1u))>>16); }
__device__ __forceinline__ float bff(u16 h){ return u2f(((u32)h)<<16); }
// fp32 -> (hi,lo) bf16 pair packed in one u32 (low half = hi part)
__device__ __forceinline__ u32 pack2(float x){
  u16 h = bfhi(x);
  u16 l = bfhi(x - bff(h));
  return (u32)h | ((u32)l << 16);
}

__device__ __forceinline__ void gload16(const void* g, void* l){
  __builtin_amdgcn_global_load_lds(
      (const __attribute__((address_space(1))) unsigned int*)g,
      (__attribute__((address_space(3))) unsigned int*)l, 16, 0, 0);
}

// ---------------------------------------------------------------------------
// Elementwise fp32 -> packed split-bf16 (u32 per element).
// ---------------------------------------------------------------------------
__global__ __launch_bounds__(256)
void split_pack(const float* __restrict__ in, u32* __restrict__ out, int n4)
{
  int i = blockIdx.x*256 + threadIdx.x;
  const int stride = gridDim.x*256;
  for (; i < n4; i += stride){
    float4 v = reinterpret_cast<const float4*>(in)[i];
    reinterpret_cast<u32x4*>(out)[i] =
      (u32x4){ pack2(v.x), pack2(v.y), pack2(v.z), pack2(v.w) };
  }
}

// ---------------------------------------------------------------------------
// 256x192-tile GEMM on pre-packed split-bf16 (full-coverage for M=2048,N=6144
// -> 256 blocks).  8 waves, wave tile 128x48, BK=64 bf16, dbuf 112KB LDS,
// 2 fat phases/K-tile, counted vmcnt(3), both-sides swizzle, setprio.
// ---------------------------------------------------------------------------
__global__ __launch_bounds__(512, 2)
void gemm_pkA(const u32* __restrict__ A, const u32* __restrict__ B,
              float* __restrict__ C, int M, int N, int K)  // K = u32 per row
{
  extern __shared__ char smem[];   // 114688 B: [buf2][ A 32KB | B 24KB ]
  const int tid  = threadIdx.x;
  const int lane = tid & 63;
  const int w    = tid >> 6;       // 0..7
  const int wm = w >> 2, wn = w & 3;
  const int ln = lane & 15, lg = lane >> 4;

  const int nbm = M >> 8;          // 256-row tiles
  const int nbn = N / 192;
  const int nwg = nbm * nbn;
  const int swz = (blockIdx.x & 7) * (nwg >> 3) + (blockIdx.x >> 3);
  const int bm = swz % nbm, bn = swz / nbm;

  const size_t rbA = (size_t)K * 4;          // row bytes
  const int lrow  = lane >> 3;               // 0..7
  const int lslot = (lane & 7) ^ (lrow & 7); // pre-swizzled source slot
  const char* As0 = (const char*)A + (size_t)(bm*256 + w*8 + lrow)*rbA + lslot*16;
  const char* Bs0 = (const char*)B + (size_t)(bn*192 + w*8 + lrow)*rbA + lslot*16;

  auto stA = [&](int buf, int t) {
    const char* s = As0 + ((size_t)t << 7);
    char* d = smem + buf*57344 + w*1024;
    gload16(s,            d);
    gload16(s +  64*rbA,  d + 8192);
    gload16(s + 128*rbA,  d + 16384);
    gload16(s + 192*rbA,  d + 24576);
  };
  auto stB = [&](int buf, int t) {
    const char* s = Bs0 + ((size_t)t << 7);
    char* d = smem + buf*57344 + 32768 + w*1024;
    gload16(s,            d);
    gload16(s +  64*rbA,  d + 8192);
    gload16(s + 128*rbA,  d + 16384);
  };

  f32x4 z = {0.f,0.f,0.f,0.f};
  f32x4 acc[8][3];
  #pragma unroll
  for (int i=0;i<8;i++){
    #pragma unroll
    for (int j=0;j<3;j++) acc[i][j] = z;
  }

  const int nt = K >> 5;           // K-tiles of 32 u32 (=64 bf16)
  stA(0, 0); stB(0, 0);            // 7 loads
  if (nt > 1) { stB(1, 1);         // +3
    asm volatile("s_waitcnt vmcnt(3)" ::: "memory");   // tile0's 7 complete
  } else {
    asm volatile("s_waitcnt vmcnt(0)" ::: "memory");
  }
  __builtin_amdgcn_s_barrier();
  asm volatile("" ::: "memory");

  const int lx7 = ln & 7;

  for (int t = 0; t < nt; ++t){
    const int cur = t & 1;
    const char* bufc = smem + cur*57344;

    // ---- phase 0: all B frags + A m-frags 0..3; stage A(t+1) ----
    FragU bfr[3][2];
    #pragma unroll
    for (int ni=0; ni<3; ni++){
      const int rofs = 32768 + (wn*48 + ni*16 + ln)*128;
      #pragma unroll
      for (int ks=0; ks<2; ks++)
        bfr[ni][ks].q = *reinterpret_cast<const u32x4*>(bufc + rofs + (((ks*4+lg)^lx7)<<4));
    }
    FragU af[4][2];
    #pragma unroll
    for (int mf=0; mf<4; mf++){
      const int rofs = (wm*128 + mf*16 + ln)*128;
      #pragma unroll
      for (int ks=0; ks<2; ks++)
        af[mf][ks].q = *reinterpret_cast<const u32x4*>(bufc + rofs + (((ks*4+lg)^lx7)<<4));
    }
    if (t+1 < nt) stA(cur^1, t+1);
    __builtin_amdgcn_s_barrier();
    __builtin_amdgcn_s_setprio(1);
    #pragma unroll
    for (int ks=0; ks<2; ks++){
      #pragma unroll
      for (int mf=0; mf<4; mf++){
        #pragma unroll
        for (int ni=0; ni<3; ni++)
          acc[mf][ni] = __builtin_amdgcn_mfma_f32_16x16x32_bf16(af[mf][ks].v, bfr[ni][ks].v, acc[mf][ni], 0,0,0);
      }
    }
    __builtin_amdgcn_s_setprio(0);
    asm volatile("s_waitcnt lgkmcnt(0)" ::: "memory");
    __builtin_amdgcn_s_barrier();

    // ---- phase 1: A m-frags 4..7; stage B(t+2) -> B[cur] ----
    FragU ag[4][2];
    #pragma unroll
    for (int mf=0; mf<4; mf++){
      const int rofs = (wm*128 + (mf+4)*16 + ln)*128;
      #pragma unroll
      for (int ks=0; ks<2; ks++)
        ag[mf][ks].q = *reinterpret_cast<const u32x4*>(bufc + rofs + (((ks*4+lg)^lx7)<<4));
    }
    if (t+2 < nt) stB(cur, t+2);
    __builtin_amdgcn_s_barrier();
    __builtin_amdgcn_s_setprio(1);
    #pragma unroll
    for (int ks=0; ks<2; ks++){
      #pragma unroll
      for (int mf=0; mf<4; mf++){
        #pragma unroll
        for (int ni=0; ni<3; ni++)
          acc[mf+4][ni] = __builtin_amdgcn_mfma_f32_16x16x32_bf16(ag[mf][ks].v, bfr[ni][ks].v, acc[mf+4][ni], 0,0,0);
      }
    }
    __builtin_amdgcn_s_setprio(0);
    if (t+1 < nt){
      if (t+2 < nt) asm volatile("s_waitcnt vmcnt(3)" ::: "memory");
      else          asm volatile("s_waitcnt vmcnt(0)" ::: "memory");
    }
    __builtin_amdgcn_s_barrier();
    asm volatile("" ::: "memory");
  }

  #pragma unroll
  for (int mi=0; mi<8; mi++){
    #pragma unroll
    for (int ni=0; ni<3; ni++){
      const int row0 = bm*256 + wm*128 + mi*16 + lg*4;
      const int col  = bn*192 + wn*48  + ni*16 + ln;
      #pragma unroll
      for (int r=0; r<4; r++)
        C[(size_t)(row0+r)*N + col] = acc[mi][ni][r];
    }
  }
}

// ---------------------------------------------------------------------------
// 128x256-tile variant (full-coverage for M=2048,N=4096: 256 blocks).
// 2 fat phases/K-tile; wave = 64x64, acc[4][4].  LDS 96KB.
// ---------------------------------------------------------------------------
__global__ __launch_bounds__(512, 2)
void gemm_pkB(const u32* __restrict__ A, const u32* __restrict__ B,
              float* __restrict__ C, int M, int N, int K)  // K = u32 per row
{
  extern __shared__ char smem[];   // 98304 B: [buf2][ A 16KB | B 32KB ]
  const int tid  = threadIdx.x;
  const int lane = tid & 63;
  const int w    = tid >> 6;       // 0..7
  const int wm = w >> 2, wn = w & 3;
  const int ln = lane & 15, lg = lane >> 4;

  const int nbm = M >> 7, nbn = N >> 8;
  const int nwg = nbm * nbn;
  const int swz = (blockIdx.x & 7) * (nwg >> 3) + (blockIdx.x >> 3);
  const int bm = swz % nbm, bn = swz / nbm;

  const size_t rbA = (size_t)K * 4;          // row bytes
  const int lrow  = lane >> 3;               // 0..7
  const int lslot = (lane & 7) ^ (lrow & 7); // pre-swizzled source slot
  const char* As0 = (const char*)A + (size_t)(bm*128 + w*8 + lrow)*rbA + lslot*16;
  const char* Bs0 = (const char*)B + (size_t)(bn*256 + w*8 + lrow)*rbA + lslot*16;

  auto stA = [&](int buf, int t) {
    const char* s = As0 + ((size_t)t << 7);
    char* d = smem + buf*49152 + w*1024;
    gload16(s,            d);
    gload16(s +  64*rbA,  d + 8192);
  };
  auto stB = [&](int buf, int t) {
    const char* s = Bs0 + ((size_t)t << 7);
    char* d = smem + buf*49152 + 16384 + w*1024;
    gload16(s,            d);
    gload16(s +  64*rbA,  d + 8192);
    gload16(s + 128*rbA,  d + 16384);
    gload16(s + 192*rbA,  d + 24576);
  };

  f32x4 z = {0.f,0.f,0.f,0.f};
  f32x4 acc[4][4];
  #pragma unroll
  for (int i=0;i<4;i++){
    #pragma unroll
    for (int j=0;j<4;j++) acc[i][j] = z;
  }

  const int nt = K >> 5;           // K-tiles of 32 u32 (=64 bf16)
  stA(0, 0); stB(0, 0);            // 6 loads
  if (nt > 1) { stB(1, 1);         // +4
    asm volatile("s_waitcnt vmcnt(4)" ::: "memory");   // tile0's 6 complete
  } else {
    asm volatile("s_waitcnt vmcnt(0)" ::: "memory");
  }
  __builtin_amdgcn_s_barrier();
  asm volatile("" ::: "memory");

  const int boff0 = 16384;
  const int lx7   = ln & 7;

  for (int t = 0; t < nt; ++t){
    const int cur = t & 1;
    const char* bufc = smem + cur*49152;

    // ---- phase 0: all B frags + A m-frags 0..1; stage A(t+1) ----
    FragU bfr[4][2];
    #pragma unroll
    for (int ni=0; ni<4; ni++){
      const int rofs = boff0 + (wn*64 + ni*16 + ln)*128;
      #pragma unroll
      for (int ks=0; ks<2; ks++)
        bfr[ni][ks].q = *reinterpret_cast<const u32x4*>(bufc + rofs + (((ks*4+lg)^lx7)<<4));
    }
    FragU af[2][2];
    #pragma unroll
    for (int mf=0; mf<2; mf++){
      const int rofs = (wm*64 + mf*16 + ln)*128;
      #pragma unroll
      for (int ks=0; ks<2; ks++)
        af[mf][ks].q = *reinterpret_cast<const u32x4*>(bufc + rofs + (((ks*4+lg)^lx7)<<4));
    }
    if (t+1 < nt) stA(cur^1, t+1);
    __builtin_amdgcn_s_barrier();
    __builtin_amdgcn_s_setprio(1);
    #pragma unroll
    for (int ks=0; ks<2; ks++){
      #pragma unroll
      for (int mf=0; mf<2; mf++){
        #pragma unroll
        for (int ni=0; ni<4; ni++)
          acc[mf][ni] = __builtin_amdgcn_mfma_f32_16x16x32_bf16(af[mf][ks].v, bfr[ni][ks].v, acc[mf][ni], 0,0,0);
      }
    }
    __builtin_amdgcn_s_setprio(0);
    asm volatile("s_waitcnt lgkmcnt(0)" ::: "memory");
    __builtin_amdgcn_s_barrier();

    // ---- phase 1: A m-frags 2..3; stage B(t+2) -> B[cur] ----
    FragU ag[2][2];
    #pragma unroll
    for (int mf=0; mf<2; mf++){
      const int rofs = (wm*64 + (mf+2)*16 + ln)*128;
      #pragma unroll
      for (int ks=0; ks<2; ks++)
        ag[mf][ks].q = *reinterpret_cast<const u32x4*>(bufc + rofs + (((ks*4+lg)^lx7)<<4));
    }
    if (t+2 < nt) stB(cur, t+2);
    __builtin_amdgcn_s_barrier();
    __builtin_amdgcn_s_setprio(1);
    #pragma unroll
    for (int ks=0; ks<2; ks++){
      #pragma unroll
      for (int mf=0; mf<2; mf++){
        #pragma unroll
        for (int ni=0; ni<4; ni++)
          acc[mf+2][ni] = __builtin_amdgcn_mfma_f32_16x16x32_bf16(ag[mf][ks].v, bfr[ni][ks].v, acc[mf+2][ni], 0,0,0);
      }
    }
    __builtin_amdgcn_s_setprio(0);
    if (t+1 < nt){
      if (t+2 < nt) asm volatile("s_waitcnt vmcnt(4)" ::: "memory");
      else          asm volatile("s_waitcnt vmcnt(0)" ::: "memory");
    }
    __builtin_amdgcn_s_barrier();
    asm volatile("" ::: "memory");
  }

  #pragma unroll
  for (int mi=0; mi<4; mi++){
    #pragma unroll
    for (int ni=0; ni<4; ni++){
      const int row0 = bm*128 + wm*64 + mi*16 + lg*4;
      const int col  = bn*256 + wn*64 + ni*16 + ln;
      #pragma unroll
      for (int r=0; r<4; r++)
        C[(size_t)(row0+r)*N + col] = acc[mi][ni][r];
    }
  }
}

// ---------------------------------------------------------------------------
// Gather old paged cache into contiguous PACKED ws buffers.
// k_all  : u32 [B][HKV][1024][128]   v_allT : u32 [B][HKV][128][1024]
// ---------------------------------------------------------------------------
__global__ __launch_bounds__(256)
void copy_cache(const float* __restrict__ k_cache, const float* __restrict__ v_cache,
                const int* __restrict__ page_table,
                u32* __restrict__ k_all, u32* __restrict__ v_allT)
{
  __shared__ float tb[32][129];
  const int id = blockIdx.x;
  const int jt = id & 31, h = (id>>5)&7, b = id>>8;
  const int tid = threadIdx.x;
  const int j0 = jt*32;
  {
    int r = tid>>3, c = tid&7;
    int j = j0 + r;
    int page = page_table[b*64 + (j>>4)];
    int slot = j & 15;
    const float* ks = k_cache + (size_t)((page*16 + slot)*8 + h)*128;
    const float* vs = v_cache + (size_t)((page*16 + slot)*8 + h)*128;
    u32* kd = k_all + ((size_t)(b*8+h)*1024 + j)*128;
    #pragma unroll
    for (int i=0;i<4;i++){
      int d0 = (c + 8*i)*4;
      float4 k4 = *reinterpret_cast<const float4*>(ks + d0);
      *reinterpret_cast<u32x4*>(kd + d0) =
        (u32x4){ pack2(k4.x), pack2(k4.y), pack2(k4.z), pack2(k4.w) };
      float4 v4 = *reinterpret_cast<const float4*>(vs + d0);
      tb[r][d0+0]=v4.x; tb[r][d0+1]=v4.y; tb[r][d0+2]=v4.z; tb[r][d0+3]=v4.w;
    }
  }
  __syncthreads();
  {
    int dout = tid>>1, jh = tid&1;
    u32* vd = v_allT + ((size_t)(b*8+h)*128 + dout)*1024 + j0 + jh*16;
    #pragma unroll
    for (int i=0;i<4;i++){
      u32x4 o;
      o.x = pack2(tb[jh*16 + i*4 + 0][dout]);
      o.y = pack2(tb[jh*16 + i*4 + 1][dout]);
      o.z = pack2(tb[jh*16 + i*4 + 2][dout]);
      o.w = pack2(tb[jh*16 + i*4 + 3][dout]);
      *reinterpret_cast<u32x4*>(vd + i*4) = o;
    }
  }
}

// ---------------------------------------------------------------------------
// Per-head RMSNorm + partial RoPE + scatter new K/V (packed) into k_all/v_allT.
// ---------------------------------------------------------------------------
__global__ __launch_bounds__(256)
void norm_rope_scatter(float* __restrict__ qkv, const float* __restrict__ cosT,
                       const float* __restrict__ sinT, const int* __restrict__ positions,
                       const int* __restrict__ cache_seqlens,
                       const float* __restrict__ qw, const float* __restrict__ kw,
                       u32* __restrict__ k_all, u32* __restrict__ v_allT)
{
  const int t = blockIdx.x;
  const int lane = threadIdx.x & 63;
  const int w = threadIdx.x >> 6;
  const int b = t >> 9;        // QL = 512
  const int q = t & 511;
  const int pos  = positions[t];
  const int cpos = cache_seqlens[b] + q;
  for (int it=0; it<12; ++it){
    int h = it*4 + w;          // 0..47
    float* xp = qkv + (size_t)t*6144 + h*128 + 2*lane;
    float2 x = *reinterpret_cast<const float2*>(xp);
    if (h < 40){               // q + k heads get RMSNorm + RoPE
      float ss = x.x*x.x + x.y*x.y;
      #pragma unroll
      for (int mk=1; mk<64; mk<<=1) ss += __shfl_xor(ss, mk);
      float var = ss*(1.0f/128.0f) + 1e-6f;
      float rq = rsqrtf(var);
      rq = rq*(1.5f - 0.5f*var*rq*rq);   // Newton refine
      const float* wt = (h<32) ? qw : kw;
      x.x *= rq*wt[2*lane]; x.y *= rq*wt[2*lane+1];
      float px = __shfl_xor(x.x, 16);
      float py = __shfl_xor(x.y, 16);
      if (lane < 32){
        int ci = pos*32 + 2*(lane&15);
        float2 cc = *reinterpret_cast<const float2*>(cosT + ci);
        float2 sc = *reinterpret_cast<const float2*>(sinT + ci);
        if (lane < 16){ x.x = x.x*cc.x - px*sc.x; x.y = x.y*cc.y - py*sc.y; }
        else          { x.x = x.x*cc.x + px*sc.x; x.y = x.y*cc.y + py*sc.y; }
      }
    }
    if (h < 32){
      *reinterpret_cast<float2*>(xp) = x;   // q back in place (fp32)
    } else if (h < 40){
      u32* kp = k_all + ((size_t)(b*8 + (h-32))*1024 + cpos)*128 + 2*lane;
      kp[0] = pack2(x.x); kp[1] = pack2(x.y);
    } else {
      u32* vp = v_allT + ((size_t)(b*8 + (h-40))*128 + 2*lane)*1024 + cpos;
      vp[0]    = pack2(x.x);
      vp[1024] = pack2(x.y);
    }
  }
}

// ---------------------------------------------------------------------------
// Fused GQA causal attention v3 = v1 shape (4 waves, QBLK=64, KVBLK=32,
// grid 1024 natural order) + async double-buffered K/V staging via
// global_load_lds (pre-swizzled global source, linear LDS dest, v1 read XOR)
// + counted vmcnt (8 = next tile's loads stay in flight) + 2 barriers/tile.
// ---------------------------------------------------------------------------
__global__ __launch_bounds__(256)
void attn_fused3(const float* __restrict__ qkv, const u32* __restrict__ k_all,
                 const u32* __restrict__ v_allT, const int* __restrict__ cache_seqlens,
                 u32* __restrict__ attnO)
{
  extern __shared__ char smem[];          // 72KB: K dbuf 32K | V dbuf 32K | P 8K
  float* Pl = (float*)(smem + 65536);     // [4][512]
  const int tid = threadIdx.x, lane = tid&63, w = tid>>6;
  const int ln = lane&15, lg = lane>>4;
  const int id = blockIdx.x;
  const int qt = id & 7, g = (id>>3)&3, kvh = (id>>5)&7, b = id>>8;
  const int cs = cache_seqlens[b];
  const int h  = kvh*4 + g;
  const int q0 = qt*64 + w*16;
  const float SCALE = 0.08838834764831845f;  // 1/sqrt(128)
  f32x4 z = {0.f,0.f,0.f,0.f};

  FragU qf[8];
  {
    const float* qp = qkv + (size_t)(b*512 + q0 + ln)*6144 + h*128;
    #pragma unroll
    for (int ks=0; ks<8; ks++){
      int d0 = ks*16 + lg*4;
      float4 v4 = *reinterpret_cast<const float4*>(qp + d0);
      qf[ks].q = (u32x4){ pack2(v4.x*SCALE), pack2(v4.y*SCALE),
                          pack2(v4.z*SCALE), pack2(v4.w*SCALE) };
    }
  }
  f32x4 O[8];
  #pragma unroll
  for (int i=0;i<8;i++) O[i] = z;
  float m[4] = {-1e30f,-1e30f,-1e30f,-1e30f};
  float l[4] = {0.f,0.f,0.f,0.f};
  const int prow0 = cs + q0 + lg*4;
  const int nt = (cs + qt*64 + 64 + 31) >> 5;
  const char* kbase = (const char*)(k_all  + (size_t)(b*8+kvh)*1024*128);
  const char* vbase = (const char*)(v_allT + (size_t)(b*8+kvh)*128*1024);

  // staging geometry: per issue i, this lane's LDS dest = base + lane*16
  const int krb = w*2 + (lane>>5);     // K row within issue block (i*8 + krb)
  const int ksl = lane & 31;           // 16B slot within 512B K row
  const int vrb = w*8 + (lane>>3);     // V d-row within issue block (i*32 + vrb)
  const int vsl = lane & 7;            // 16B slot within 128B V row-chunk

  auto stK = [&](int buf, int t){
    #pragma unroll
    for (int i=0;i<4;i++){
      int row = i*8 + krb;
      const char* s = kbase + (size_t)(t*32 + row)*512 + ((ksl ^ (row&7))<<4);
      gload16(s, smem + buf*16384 + i*4096 + w*1024);
    }
  };
  auto stV = [&](int buf, int t){
    #pragma unroll
    for (int i=0;i<4;i++){
      int d = i*32 + vrb;
      const char* s = vbase + (size_t)d*4096 + (size_t)t*128 + ((vsl ^ (d&7))<<4);
      gload16(s, smem + 32768 + buf*16384 + i*4096 + w*1024);
    }
  };

  stK(0, 0); stV(0, 0);
  if (nt > 1){ stK(1, 1); stV(1, 1); }

  for (int tile=0; tile<nt; ++tile){
    const int cur = tile & 1;
    const int kv0 = tile*32;
    // wait tile's 8 loads; leave tile+1's 8 in flight
    if (tile+1 < nt) asm volatile("s_waitcnt vmcnt(8)" ::: "memory");
    else             asm volatile("s_waitcnt vmcnt(0)" ::: "memory");
    __builtin_amdgcn_s_barrier();

    // ---- S = Q K^T (split-bf16 over K'=256), two 4-deep chains ----
    const u16* Kc = (const u16*)(smem + cur*16384);
    f32x4 sa0=z, sa1=z, sb0=z, sb1=z;
    #pragma unroll
    for (int ks=0; ks<4; ks++){
      int kb = ks*32 + lg*8;
      FragU kf0, kf1;
      kf0.q = *reinterpret_cast<const u32x4*>(&Kc[(ln*256 + kb) ^ ((ln&7)<<3)]);
      kf1.q = *reinterpret_cast<const u32x4*>(&Kc[((16+ln)*256 + kb) ^ (((16+ln)&7)<<3)]);
      sa0 = __builtin_amdgcn_mfma_f32_16x16x32_bf16(qf[ks].v, kf0.v, sa0, 0,0,0);
      sa1 = __builtin_amdgcn_mfma_f32_16x16x32_bf16(qf[ks].v, kf1.v, sa1, 0,0,0);
    }
    #pragma unroll
    for (int ks=4; ks<8; ks++){
      int kb = ks*32 + lg*8;
      FragU kf0, kf1;
      kf0.q = *reinterpret_cast<const u32x4*>(&Kc[(ln*256 + kb) ^ ((ln&7)<<3)]);
      kf1.q = *reinterpret_cast<const u32x4*>(&Kc[((16+ln)*256 + kb) ^ (((16+ln)&7)<<3)]);
      sb0 = __builtin_amdgcn_mfma_f32_16x16x32_bf16(qf[ks].v, kf0.v, sb0, 0,0,0);
      sb1 = __builtin_amdgcn_mfma_f32_16x16x32_bf16(qf[ks].v, kf1.v, sb1, 0,0,0);
    }
    f32x4 s[2]; s[0] = sa0 + sb0; s[1] = sa1 + sb1;

    // ---- online softmax (rows = lg*4+r) ----
    float mx[4];
    #pragma unroll
    for (int r=0;r<4;r++){
      int pr = prow0 + r;
      float a0 = (kv0 + ln      <= pr) ? s[0][r] : -1e30f;
      float a1 = (kv0 + 16 + ln <= pr) ? s[1][r] : -1e30f;
      mx[r] = fmaxf(a0, a1);
    }
    #pragma unroll
    for (int off=1; off<16; off<<=1){
      #pragma unroll
      for (int r=0;r<4;r++) mx[r] = fmaxf(mx[r], __shfl_xor(mx[r], off));
    }
    float corr[4];
    #pragma unroll
    for (int r=0;r<4;r++){
      float mn = fmaxf(m[r], mx[r]);
      corr[r] = __expf(m[r] - mn);
      m[r] = mn;
    }
    float pv[2][4], ps[4] = {0.f,0.f,0.f,0.f};
    #pragma unroll
    for (int n=0;n<2;n++){
      #pragma unroll
      for (int r=0;r<4;r++){
        bool ok = (kv0 + n*16 + ln) <= (prow0 + r);
        float p = ok ? __expf(s[n][r] - m[r]) : 0.f;
        pv[n][r] = p;
        ps[r] += p;
      }
    }
    #pragma unroll
    for (int off=1; off<16; off<<=1){
      #pragma unroll
      for (int r=0;r<4;r++) ps[r] += __shfl_xor(ps[r], off);
    }
    #pragma unroll
    for (int r=0;r<4;r++) l[r] = l[r]*corr[r] + ps[r];
    #pragma unroll
    for (int nf=0; nf<8; nf++){
      #pragma unroll
      for (int r=0;r<4;r++) O[nf][r] = O[nf][r]*corr[r];
    }
    // ---- P -> per-wave LDS (swizzled), read back as hi/lo A-frags ----
    #pragma unroll
    for (int n=0;n<2;n++){
      #pragma unroll
      for (int r=0;r<4;r++){
        int row = lg*4 + r;
        Pl[w*512 + ((row*32 + n*16 + ln) ^ ((row&7)<<2))] = pv[n][r];
      }
    }
    FragU pah[2], pal[2];
    #pragma unroll
    for (int ks2=0; ks2<2; ks2++){
      int fi = (ln*32 + ks2*16 + lg*4) ^ ((ln&7)<<2);
      float4 pp = *reinterpret_cast<const float4*>(&Pl[w*512 + fi]);
      float parr[4] = {pp.x, pp.y, pp.z, pp.w};
      #pragma unroll
      for (int i=0;i<4;i++){
        u16 hh = bfhi(parr[i]);
        u16 ll = bfhi(parr[i] - bff(hh));
        pah[ks2].us[2*i] = hh; pah[ks2].us[2*i+1] = hh;
        pal[ks2].us[2*i] = ll; pal[ks2].us[2*i+1] = ll;
      }
    }
    // ---- O += (Ph+Pl) x (Vh+Vl) ----
    const u16* Vc = (const u16*)(smem + 32768 + cur*16384);
    #pragma unroll
    for (int nf=0; nf<8; nf++){
      int dr = nf*16 + ln;
      #pragma unroll
      for (int ks2=0; ks2<2; ks2++){
        FragU vf;
        vf.q = *reinterpret_cast<const u32x4*>(&Vc[(dr*64 + ks2*32 + lg*8) ^ ((dr&7)<<3)]);
        O[nf] = __builtin_amdgcn_mfma_f32_16x16x32_bf16(pah[ks2].v, vf.v, O[nf], 0,0,0);
        O[nf] = __builtin_amdgcn_mfma_f32_16x16x32_bf16(pal[ks2].v, vf.v, O[nf], 0,0,0);
      }
    }
    // all LDS reads of buf[cur] landed -> license staging tile+2 into it
    asm volatile("s_waitcnt lgkmcnt(0)" ::: "memory");
    __builtin_amdgcn_s_barrier();
    if (tile+2 < nt){ stK(cur, tile+2); stV(cur, tile+2); }
  }

  float il[4];
  #pragma unroll
  for (int r=0;r<4;r++) il[r] = 1.0f / l[r];
  u32* op = attnO + (size_t)(b*512 + q0 + lg*4)*4096 + h*128 + ln;
  #pragma unroll
  for (int nf=0; nf<8; nf++){
    #pragma unroll
    for (int r=0;r<4;r++)
      op[(size_t)r*4096 + nf*16] = pack2(O[nf][r] * il[r]);
  }
}

// ---------------------------------------------------------------------------
extern "C" void kernel_launch(void* const* d_in, const int* in_sizes, int n_in,
                              void* d_out, int out_size, void* d_ws, size_t ws_size,
                              hipStream_t stream) {
  const float* hidden    = (const float*)d_in[0];
  const float* cosT      = (const float*)d_in[1];
  const float* sinT      = (const float*)d_in[2];
  const int*   positions = (const int*)  d_in[3];
  const float* k_cache   = (const float*)d_in[4];
  const float* v_cache   = (const float*)d_in[5];
  const int*   page_tab  = (const int*)  d_in[6];
  const int*   cache_sl  = (const int*)  d_in[7];
  const float* qkv_w     = (const float*)d_in[9];
  const float* o_w       = (const float*)d_in[10];
  const float* qnw       = (const float*)d_in[11];
  const float* knw       = (const float*)d_in[12];
  float* out = (float*)d_out;

  u32* ws      = (u32*)d_ws;
  float* qkv   = (float*)ws;                // 2048*6144        = 12582912
  u32* k_all   = ws      + 12582912;        // 4*8*1024*128     =  4194304
  u32* v_allT  = k_all   + 4194304;         //                  =  4194304
  u32* attnPk  = v_allT  + 4194304;         // 2048*4096        =  8388608
  u32* hidPk   = attnPk  + 8388608;         // 2048*4096        =  8388608
  u32* qkvwPk  = hidPk   + 8388608;         // 6144*4096        = 25165824
  u32* owPk    = qkvwPk  + 25165824;        // 4096*4096        = 16777216
  (void)in_sizes; (void)n_in; (void)out_size; (void)ws_size;

  (void)hipFuncSetAttribute(reinterpret_cast<const void*>(gemm_pkA),
                            hipFuncAttributeMaxDynamicSharedMemorySize, 114688);
  (void)hipFuncSetAttribute(reinterpret_cast<const void*>(gemm_pkB),
                            hipFuncAttributeMaxDynamicSharedMemorySize, 98304);
  (void)hipFuncSetAttribute(reinterpret_cast<const void*>(attn_fused3),
                            hipFuncAttributeMaxDynamicSharedMemorySize, 73728);

  hipLaunchKernelGGL(split_pack, dim3(1024), dim3(256), 0, stream,
                     hidden, hidPk, 2097152);
  hipLaunchKernelGGL(split_pack, dim3(1024), dim3(256), 0, stream,
                     qkv_w, qkvwPk, 6291456);
  hipLaunchKernelGGL(split_pack, dim3(1024), dim3(256), 0, stream,
                     o_w, owPk, 4194304);
  hipLaunchKernelGGL(copy_cache, dim3(1024), dim3(256), 0, stream,
                     k_cache, v_cache, page_tab, k_all, v_allT);
  hipLaunchKernelGGL(gemm_pkA, dim3(256), dim3(512), 114688, stream,
                     hidPk, qkvwPk, qkv, 2048, 6144, 4096);
  hipLaunchKernelGGL(norm_rope_scatter, dim3(2048), dim3(256), 0, stream,
                     qkv, cosT, sinT, positions, cache_sl, qnw, knw, k_all, v_allT);
  hipLaunchKernelGGL(attn_fused3, dim3(1024), dim3(256), 73728, stream,
                     qkv, k_all, v_allT, cache_sl, attnPk);
  hipLaunchKernelGGL(gemm_pkB, dim3(256), dim3(512), 98304, stream,
                     attnPk, owPk, out, 2048, 4096, 4096);
}

// Round 8
// 570.639 us; speedup vs baseline: 1.4178x; 1.0922x over previous
//
#include <hip/hip_runtime.h>

typedef unsigned int   u32;
typedef unsigned short u16;

typedef float  f32x4  __attribute__((ext_vector_type(4)));
typedef u32    u32x4  __attribute__((ext_vector_type(4)));
typedef __bf16 bf16x8 __attribute__((ext_vector_type(8)));

union FragU { u16 us[8]; u32x4 q; bf16x8 v; };

__device__ __forceinline__ u32 f2u(float x){ union{float f;u32 u;}c; c.f=x; return c.u; }
__device__ __forceinline__ float u2f(u32 u){ union{float f;u32 u;}c; c.u=u; return c.f; }
__device__ __forceinline__ u16 bfhi(float x){ u32 u=f2u(x); return (u16)((u + 0x7fffu + ((u>>16)&1u))>>16); }
__device__ __forceinline__ float bff(u16 h){ return u2f(((u32)h)<<16); }
// fp32 -> (hi,lo) bf16 pair packed in one u32 (low half = hi part)
__device__ __forceinline__ u32 pack2(float x){
  u16 h = bfhi(x);
  u16 l = bfhi(x - bff(h));
  return (u32)h | ((u32)l << 16);
}

__device__ __forceinline__ void gload16(const void* g, void* l){
  __builtin_amdgcn_global_load_lds(
      (const __attribute__((address_space(1))) unsigned int*)g,
      (__attribute__((address_space(3))) unsigned int*)l, 16, 0, 0);
}

// ---------------------------------------------------------------------------
// Elementwise fp32 -> packed split-bf16 (u32 per element).
// ---------------------------------------------------------------------------
__global__ __launch_bounds__(256)
void split_pack(const float* __restrict__ in, u32* __restrict__ out, int n4)
{
  int i = blockIdx.x*256 + threadIdx.x;
  const int stride = gridDim.x*256;
  for (; i < n4; i += stride){
    float4 v = reinterpret_cast<const float4*>(in)[i];
    reinterpret_cast<u32x4*>(out)[i] =
      (u32x4){ pack2(v.x), pack2(v.y), pack2(v.z), pack2(v.w) };
  }
}

// ---------------------------------------------------------------------------
// 256x192-tile GEMM on pre-packed split-bf16 (full-coverage for M=2048,N=6144
// -> 256 blocks).  8 waves, wave tile 128x48, BK=64 bf16, dbuf 112KB LDS,
// 2 fat phases/K-tile, counted vmcnt(3), both-sides swizzle, setprio.
// ---------------------------------------------------------------------------
__global__ __launch_bounds__(512, 2)
void gemm_pkA(const u32* __restrict__ A, const u32* __restrict__ B,
              float* __restrict__ C, int M, int N, int K)  // K = u32 per row
{
  extern __shared__ char smem[];   // 114688 B: [buf2][ A 32KB | B 24KB ]
  const int tid  = threadIdx.x;
  const int lane = tid & 63;
  const int w    = tid >> 6;       // 0..7
  const int wm = w >> 2, wn = w & 3;
  const int ln = lane & 15, lg = lane >> 4;

  const int nbm = M >> 8;          // 256-row tiles
  const int nbn = N / 192;
  const int nwg = nbm * nbn;
  const int swz = (blockIdx.x & 7) * (nwg >> 3) + (blockIdx.x >> 3);
  const int bm = swz % nbm, bn = swz / nbm;

  const size_t rbA = (size_t)K * 4;          // row bytes
  const int lrow  = lane >> 3;               // 0..7
  const int lslot = (lane & 7) ^ (lrow & 7); // pre-swizzled source slot
  const char* As0 = (const char*)A + (size_t)(bm*256 + w*8 + lrow)*rbA + lslot*16;
  const char* Bs0 = (const char*)B + (size_t)(bn*192 + w*8 + lrow)*rbA + lslot*16;

  auto stA = [&](int buf, int t) {
    const char* s = As0 + ((size_t)t << 7);
    char* d = smem + buf*57344 + w*1024;
    gload16(s,            d);
    gload16(s +  64*rbA,  d + 8192);
    gload16(s + 128*rbA,  d + 16384);
    gload16(s + 192*rbA,  d + 24576);
  };
  auto stB = [&](int buf, int t) {
    const char* s = Bs0 + ((size_t)t << 7);
    char* d = smem + buf*57344 + 32768 + w*1024;
    gload16(s,            d);
    gload16(s +  64*rbA,  d + 8192);
    gload16(s + 128*rbA,  d + 16384);
  };

  f32x4 z = {0.f,0.f,0.f,0.f};
  f32x4 acc[8][3];
  #pragma unroll
  for (int i=0;i<8;i++){
    #pragma unroll
    for (int j=0;j<3;j++) acc[i][j] = z;
  }

  const int nt = K >> 5;           // K-tiles of 32 u32 (=64 bf16)
  stA(0, 0); stB(0, 0);            // 7 loads
  if (nt > 1) { stB(1, 1);         // +3
    asm volatile("s_waitcnt vmcnt(3)" ::: "memory");   // tile0's 7 complete
  } else {
    asm volatile("s_waitcnt vmcnt(0)" ::: "memory");
  }
  __builtin_amdgcn_s_barrier();
  asm volatile("" ::: "memory");

  const int lx7 = ln & 7;

  for (int t = 0; t < nt; ++t){
    const int cur = t & 1;
    const char* bufc = smem + cur*57344;

    // ---- phase 0: all B frags + A m-frags 0..3; stage A(t+1) ----
    FragU bfr[3][2];
    #pragma unroll
    for (int ni=0; ni<3; ni++){
      const int rofs = 32768 + (wn*48 + ni*16 + ln)*128;
      #pragma unroll
      for (int ks=0; ks<2; ks++)
        bfr[ni][ks].q = *reinterpret_cast<const u32x4*>(bufc + rofs + (((ks*4+lg)^lx7)<<4));
    }
    FragU af[4][2];
    #pragma unroll
    for (int mf=0; mf<4; mf++){
      const int rofs = (wm*128 + mf*16 + ln)*128;
      #pragma unroll
      for (int ks=0; ks<2; ks++)
        af[mf][ks].q = *reinterpret_cast<const u32x4*>(bufc + rofs + (((ks*4+lg)^lx7)<<4));
    }
    if (t+1 < nt) stA(cur^1, t+1);
    __builtin_amdgcn_s_barrier();
    __builtin_amdgcn_s_setprio(1);
    #pragma unroll
    for (int ks=0; ks<2; ks++){
      #pragma unroll
      for (int mf=0; mf<4; mf++){
        #pragma unroll
        for (int ni=0; ni<3; ni++)
          acc[mf][ni] = __builtin_amdgcn_mfma_f32_16x16x32_bf16(af[mf][ks].v, bfr[ni][ks].v, acc[mf][ni], 0,0,0);
      }
    }
    __builtin_amdgcn_s_setprio(0);
    asm volatile("s_waitcnt lgkmcnt(0)" ::: "memory");
    __builtin_amdgcn_s_barrier();

    // ---- phase 1: A m-frags 4..7; stage B(t+2) -> B[cur] ----
    FragU ag[4][2];
    #pragma unroll
    for (int mf=0; mf<4; mf++){
      const int rofs = (wm*128 + (mf+4)*16 + ln)*128;
      #pragma unroll
      for (int ks=0; ks<2; ks++)
        ag[mf][ks].q = *reinterpret_cast<const u32x4*>(bufc + rofs + (((ks*4+lg)^lx7)<<4));
    }
    if (t+2 < nt) stB(cur, t+2);
    __builtin_amdgcn_s_barrier();
    __builtin_amdgcn_s_setprio(1);
    #pragma unroll
    for (int ks=0; ks<2; ks++){
      #pragma unroll
      for (int mf=0; mf<4; mf++){
        #pragma unroll
        for (int ni=0; ni<3; ni++)
          acc[mf+4][ni] = __builtin_amdgcn_mfma_f32_16x16x32_bf16(ag[mf][ks].v, bfr[ni][ks].v, acc[mf+4][ni], 0,0,0);
      }
    }
    __builtin_amdgcn_s_setprio(0);
    if (t+1 < nt){
      if (t+2 < nt) asm volatile("s_waitcnt vmcnt(3)" ::: "memory");
      else          asm volatile("s_waitcnt vmcnt(0)" ::: "memory");
    }
    __builtin_amdgcn_s_barrier();
    asm volatile("" ::: "memory");
  }

  #pragma unroll
  for (int mi=0; mi<8; mi++){
    #pragma unroll
    for (int ni=0; ni<3; ni++){
      const int row0 = bm*256 + wm*128 + mi*16 + lg*4;
      const int col  = bn*192 + wn*48  + ni*16 + ln;
      #pragma unroll
      for (int r=0; r<4; r++)
        C[(size_t)(row0+r)*N + col] = acc[mi][ni][r];
    }
  }
}

// ---------------------------------------------------------------------------
// 128x256-tile variant (full-coverage for M=2048,N=4096: 256 blocks).
// 2 fat phases/K-tile; wave = 64x64, acc[4][4].  LDS 96KB.
// ---------------------------------------------------------------------------
__global__ __launch_bounds__(512, 2)
void gemm_pkB(const u32* __restrict__ A, const u32* __restrict__ B,
              float* __restrict__ C, int M, int N, int K)  // K = u32 per row
{
  extern __shared__ char smem[];   // 98304 B: [buf2][ A 16KB | B 32KB ]
  const int tid  = threadIdx.x;
  const int lane = tid & 63;
  const int w    = tid >> 6;       // 0..7
  const int wm = w >> 2, wn = w & 3;
  const int ln = lane & 15, lg = lane >> 4;

  const int nbm = M >> 7, nbn = N >> 8;
  const int nwg = nbm * nbn;
  const int swz = (blockIdx.x & 7) * (nwg >> 3) + (blockIdx.x >> 3);
  const int bm = swz % nbm, bn = swz / nbm;

  const size_t rbA = (size_t)K * 4;          // row bytes
  const int lrow  = lane >> 3;               // 0..7
  const int lslot = (lane & 7) ^ (lrow & 7); // pre-swizzled source slot
  const char* As0 = (const char*)A + (size_t)(bm*128 + w*8 + lrow)*rbA + lslot*16;
  const char* Bs0 = (const char*)B + (size_t)(bn*256 + w*8 + lrow)*rbA + lslot*16;

  auto stA = [&](int buf, int t) {
    const char* s = As0 + ((size_t)t << 7);
    char* d = smem + buf*49152 + w*1024;
    gload16(s,            d);
    gload16(s +  64*rbA,  d + 8192);
  };
  auto stB = [&](int buf, int t) {
    const char* s = Bs0 + ((size_t)t << 7);
    char* d = smem + buf*49152 + 16384 + w*1024;
    gload16(s,            d);
    gload16(s +  64*rbA,  d + 8192);
    gload16(s + 128*rbA,  d + 16384);
    gload16(s + 192*rbA,  d + 24576);
  };

  f32x4 z = {0.f,0.f,0.f,0.f};
  f32x4 acc[4][4];
  #pragma unroll
  for (int i=0;i<4;i++){
    #pragma unroll
    for (int j=0;j<4;j++) acc[i][j] = z;
  }

  const int nt = K >> 5;           // K-tiles of 32 u32 (=64 bf16)
  stA(0, 0); stB(0, 0);            // 6 loads
  if (nt > 1) { stB(1, 1);         // +4
    asm volatile("s_waitcnt vmcnt(4)" ::: "memory");   // tile0's 6 complete
  } else {
    asm volatile("s_waitcnt vmcnt(0)" ::: "memory");
  }
  __builtin_amdgcn_s_barrier();
  asm volatile("" ::: "memory");

  const int boff0 = 16384;
  const int lx7   = ln & 7;

  for (int t = 0; t < nt; ++t){
    const int cur = t & 1;
    const char* bufc = smem + cur*49152;

    // ---- phase 0: all B frags + A m-frags 0..1; stage A(t+1) ----
    FragU bfr[4][2];
    #pragma unroll
    for (int ni=0; ni<4; ni++){
      const int rofs = boff0 + (wn*64 + ni*16 + ln)*128;
      #pragma unroll
      for (int ks=0; ks<2; ks++)
        bfr[ni][ks].q = *reinterpret_cast<const u32x4*>(bufc + rofs + (((ks*4+lg)^lx7)<<4));
    }
    FragU af[2][2];
    #pragma unroll
    for (int mf=0; mf<2; mf++){
      const int rofs = (wm*64 + mf*16 + ln)*128;
      #pragma unroll
      for (int ks=0; ks<2; ks++)
        af[mf][ks].q = *reinterpret_cast<const u32x4*>(bufc + rofs + (((ks*4+lg)^lx7)<<4));
    }
    if (t+1 < nt) stA(cur^1, t+1);
    __builtin_amdgcn_s_barrier();
    __builtin_amdgcn_s_setprio(1);
    #pragma unroll
    for (int ks=0; ks<2; ks++){
      #pragma unroll
      for (int mf=0; mf<2; mf++){
        #pragma unroll
        for (int ni=0; ni<4; ni++)
          acc[mf][ni] = __builtin_amdgcn_mfma_f32_16x16x32_bf16(af[mf][ks].v, bfr[ni][ks].v, acc[mf][ni], 0,0,0);
      }
    }
    __builtin_amdgcn_s_setprio(0);
    asm volatile("s_waitcnt lgkmcnt(0)" ::: "memory");
    __builtin_amdgcn_s_barrier();

    // ---- phase 1: A m-frags 2..3; stage B(t+2) -> B[cur] ----
    FragU ag[2][2];
    #pragma unroll
    for (int mf=0; mf<2; mf++){
      const int rofs = (wm*64 + (mf+2)*16 + ln)*128;
      #pragma unroll
      for (int ks=0; ks<2; ks++)
        ag[mf][ks].q = *reinterpret_cast<const u32x4*>(bufc + rofs + (((ks*4+lg)^lx7)<<4));
    }
    if (t+2 < nt) stB(cur, t+2);
    __builtin_amdgcn_s_barrier();
    __builtin_amdgcn_s_setprio(1);
    #pragma unroll
    for (int ks=0; ks<2; ks++){
      #pragma unroll
      for (int mf=0; mf<2; mf++){
        #pragma unroll
        for (int ni=0; ni<4; ni++)
          acc[mf+2][ni] = __builtin_amdgcn_mfma_f32_16x16x32_bf16(ag[mf][ks].v, bfr[ni][ks].v, acc[mf+2][ni], 0,0,0);
      }
    }
    __builtin_amdgcn_s_setprio(0);
    if (t+1 < nt){
      if (t+2 < nt) asm volatile("s_waitcnt vmcnt(4)" ::: "memory");
      else          asm volatile("s_waitcnt vmcnt(0)" ::: "memory");
    }
    __builtin_amdgcn_s_barrier();
    asm volatile("" ::: "memory");
  }

  #pragma unroll
  for (int mi=0; mi<4; mi++){
    #pragma unroll
    for (int ni=0; ni<4; ni++){
      const int row0 = bm*128 + wm*64 + mi*16 + lg*4;
      const int col  = bn*256 + wn*64 + ni*16 + ln;
      #pragma unroll
      for (int r=0; r<4; r++)
        C[(size_t)(row0+r)*N + col] = acc[mi][ni][r];
    }
  }
}

// ---------------------------------------------------------------------------
// Gather old paged cache into contiguous PACKED ws buffers.
// k_all  : u32 [B][HKV][1024][128]   v_allT : u32 [B][HKV][128][1024]
// ---------------------------------------------------------------------------
__global__ __launch_bounds__(256)
void copy_cache(const float* __restrict__ k_cache, const float* __restrict__ v_cache,
                const int* __restrict__ page_table,
                u32* __restrict__ k_all, u32* __restrict__ v_allT)
{
  __shared__ float tb[32][129];
  const int id = blockIdx.x;
  const int jt = id & 31, h = (id>>5)&7, b = id>>8;
  const int tid = threadIdx.x;
  const int j0 = jt*32;
  {
    int r = tid>>3, c = tid&7;
    int j = j0 + r;
    int page = page_table[b*64 + (j>>4)];
    int slot = j & 15;
    const float* ks = k_cache + (size_t)((page*16 + slot)*8 + h)*128;
    const float* vs = v_cache + (size_t)((page*16 + slot)*8 + h)*128;
    u32* kd = k_all + ((size_t)(b*8+h)*1024 + j)*128;
    #pragma unroll
    for (int i=0;i<4;i++){
      int d0 = (c + 8*i)*4;
      float4 k4 = *reinterpret_cast<const float4*>(ks + d0);
      *reinterpret_cast<u32x4*>(kd + d0) =
        (u32x4){ pack2(k4.x), pack2(k4.y), pack2(k4.z), pack2(k4.w) };
      float4 v4 = *reinterpret_cast<const float4*>(vs + d0);
      tb[r][d0+0]=v4.x; tb[r][d0+1]=v4.y; tb[r][d0+2]=v4.z; tb[r][d0+3]=v4.w;
    }
  }
  __syncthreads();
  {
    int dout = tid>>1, jh = tid&1;
    u32* vd = v_allT + ((size_t)(b*8+h)*128 + dout)*1024 + j0 + jh*16;
    #pragma unroll
    for (int i=0;i<4;i++){
      u32x4 o;
      o.x = pack2(tb[jh*16 + i*4 + 0][dout]);
      o.y = pack2(tb[jh*16 + i*4 + 1][dout]);
      o.z = pack2(tb[jh*16 + i*4 + 2][dout]);
      o.w = pack2(tb[jh*16 + i*4 + 3][dout]);
      *reinterpret_cast<u32x4*>(vd + i*4) = o;
    }
  }
}

// ---------------------------------------------------------------------------
// Per-head RMSNorm + partial RoPE + scatter new K/V (packed) into k_all/v_allT.
// ---------------------------------------------------------------------------
__global__ __launch_bounds__(256)
void norm_rope_scatter(float* __restrict__ qkv, const float* __restrict__ cosT,
                       const float* __restrict__ sinT, const int* __restrict__ positions,
                       const int* __restrict__ cache_seqlens,
                       const float* __restrict__ qw, const float* __restrict__ kw,
                       u32* __restrict__ k_all, u32* __restrict__ v_allT)
{
  const int t = blockIdx.x;
  const int lane = threadIdx.x & 63;
  const int w = threadIdx.x >> 6;
  const int b = t >> 9;        // QL = 512
  const int q = t & 511;
  const int pos  = positions[t];
  const int cpos = cache_seqlens[b] + q;
  for (int it=0; it<12; ++it){
    int h = it*4 + w;          // 0..47
    float* xp = qkv + (size_t)t*6144 + h*128 + 2*lane;
    float2 x = *reinterpret_cast<const float2*>(xp);
    if (h < 40){               // q + k heads get RMSNorm + RoPE
      float ss = x.x*x.x + x.y*x.y;
      #pragma unroll
      for (int mk=1; mk<64; mk<<=1) ss += __shfl_xor(ss, mk);
      float var = ss*(1.0f/128.0f) + 1e-6f;
      float rq = rsqrtf(var);
      rq = rq*(1.5f - 0.5f*var*rq*rq);   // Newton refine
      const float* wt = (h<32) ? qw : kw;
      x.x *= rq*wt[2*lane]; x.y *= rq*wt[2*lane+1];
      float px = __shfl_xor(x.x, 16);
      float py = __shfl_xor(x.y, 16);
      if (lane < 32){
        int ci = pos*32 + 2*(lane&15);
        float2 cc = *reinterpret_cast<const float2*>(cosT + ci);
        float2 sc = *reinterpret_cast<const float2*>(sinT + ci);
        if (lane < 16){ x.x = x.x*cc.x - px*sc.x; x.y = x.y*cc.y - py*sc.y; }
        else          { x.x = x.x*cc.x + px*sc.x; x.y = x.y*cc.y + py*sc.y; }
      }
    }
    if (h < 32){
      *reinterpret_cast<float2*>(xp) = x;   // q back in place (fp32)
    } else if (h < 40){
      u32* kp = k_all + ((size_t)(b*8 + (h-32))*1024 + cpos)*128 + 2*lane;
      kp[0] = pack2(x.x); kp[1] = pack2(x.y);
    } else {
      u32* vp = v_allT + ((size_t)(b*8 + (h-40))*128 + 2*lane)*1024 + cpos;
      vp[0]    = pack2(x.x);
      vp[1024] = pack2(x.y);
    }
  }
}

// ---------------------------------------------------------------------------
// Fused GQA causal attention v4 = v3 staging (async dbuf K/V, counted vmcnt)
// + NO-MAX softmax (scores provably bounded: |q|=sqrt(128) after RMSNorm,
//   so s <= |k| ~ 14; exp(s) <= ~1e6, l <= ~1e9 -- f32/bf16 safe)
// + deferred l-reduce (per-lane partials, one shuffle tree after the loop)
// + cvt_pk/perm-based split-pack of P + interior-tile mask skip.
// ---------------------------------------------------------------------------
__global__ __launch_bounds__(256)
void attn_fused4(const float* __restrict__ qkv, const u32* __restrict__ k_all,
                 const u32* __restrict__ v_allT, const int* __restrict__ cache_seqlens,
                 u32* __restrict__ attnO)
{
  extern __shared__ char smem[];          // 72KB: K dbuf 32K | V dbuf 32K | P 8K
  u32* Pl = (u32*)(smem + 65536);         // [4][512] packed split-bf16
  const int tid = threadIdx.x, lane = tid&63, w = tid>>6;
  const int ln = lane&15, lg = lane>>4;
  const int id = blockIdx.x;
  const int qt = id & 7, g = (id>>3)&3, kvh = (id>>5)&7, b = id>>8;
  const int cs = cache_seqlens[b];
  const int h  = kvh*4 + g;
  const int q0 = qt*64 + w*16;
  const float SCALE = 0.08838834764831845f;  // 1/sqrt(128)
  f32x4 z = {0.f,0.f,0.f,0.f};

  FragU qf[8];
  {
    const float* qp = qkv + (size_t)(b*512 + q0 + ln)*6144 + h*128;
    #pragma unroll
    for (int ks=0; ks<8; ks++){
      int d0 = ks*16 + lg*4;
      float4 v4 = *reinterpret_cast<const float4*>(qp + d0);
      qf[ks].q = (u32x4){ pack2(v4.x*SCALE), pack2(v4.y*SCALE),
                          pack2(v4.z*SCALE), pack2(v4.w*SCALE) };
    }
  }
  f32x4 O[8];
  #pragma unroll
  for (int i=0;i<8;i++) O[i] = z;
  float lacc[4] = {0.f,0.f,0.f,0.f};
  const int prow0 = cs + q0 + lg*4;
  const int nt = (cs + qt*64 + 64 + 31) >> 5;
  const char* kbase = (const char*)(k_all  + (size_t)(b*8+kvh)*1024*128);
  const char* vbase = (const char*)(v_allT + (size_t)(b*8+kvh)*128*1024);

  // staging geometry: per issue i, this lane's LDS dest = base + lane*16
  const int krb = w*2 + (lane>>5);     // K row within issue block (i*8 + krb)
  const int ksl = lane & 31;           // 16B slot within 512B K row
  const int vrb = w*8 + (lane>>3);     // V d-row within issue block (i*32 + vrb)
  const int vsl = lane & 7;            // 16B slot within 128B V row-chunk

  auto stK = [&](int buf, int t){
    #pragma unroll
    for (int i=0;i<4;i++){
      int row = i*8 + krb;
      const char* s = kbase + (size_t)(t*32 + row)*512 + ((ksl ^ (row&7))<<4);
      gload16(s, smem + buf*16384 + i*4096 + w*1024);
    }
  };
  auto stV = [&](int buf, int t){
    #pragma unroll
    for (int i=0;i<4;i++){
      int d = i*32 + vrb;
      const char* s = vbase + (size_t)d*4096 + (size_t)t*128 + ((vsl ^ (d&7))<<4);
      gload16(s, smem + 32768 + buf*16384 + i*4096 + w*1024);
    }
  };

  stK(0, 0); stV(0, 0);
  if (nt > 1){ stK(1, 1); stV(1, 1); }

  for (int tile=0; tile<nt; ++tile){
    const int cur = tile & 1;
    const int kv0 = tile*32;
    // wait tile's 8 loads; leave tile+1's 8 in flight
    if (tile+1 < nt) asm volatile("s_waitcnt vmcnt(8)" ::: "memory");
    else             asm volatile("s_waitcnt vmcnt(0)" ::: "memory");
    __builtin_amdgcn_s_barrier();

    // ---- S = Q K^T (split-bf16 over K'=256), two 4-deep chains ----
    const u16* Kc = (const u16*)(smem + cur*16384);
    f32x4 sa0=z, sa1=z, sb0=z, sb1=z;
    #pragma unroll
    for (int ks=0; ks<4; ks++){
      int kb = ks*32 + lg*8;
      FragU kf0, kf1;
      kf0.q = *reinterpret_cast<const u32x4*>(&Kc[(ln*256 + kb) ^ ((ln&7)<<3)]);
      kf1.q = *reinterpret_cast<const u32x4*>(&Kc[((16+ln)*256 + kb) ^ (((16+ln)&7)<<3)]);
      sa0 = __builtin_amdgcn_mfma_f32_16x16x32_bf16(qf[ks].v, kf0.v, sa0, 0,0,0);
      sa1 = __builtin_amdgcn_mfma_f32_16x16x32_bf16(qf[ks].v, kf1.v, sa1, 0,0,0);
    }
    #pragma unroll
    for (int ks=4; ks<8; ks++){
      int kb = ks*32 + lg*8;
      FragU kf0, kf1;
      kf0.q = *reinterpret_cast<const u32x4*>(&Kc[(ln*256 + kb) ^ ((ln&7)<<3)]);
      kf1.q = *reinterpret_cast<const u32x4*>(&Kc[((16+ln)*256 + kb) ^ (((16+ln)&7)<<3)]);
      sb0 = __builtin_amdgcn_mfma_f32_16x16x32_bf16(qf[ks].v, kf0.v, sb0, 0,0,0);
      sb1 = __builtin_amdgcn_mfma_f32_16x16x32_bf16(qf[ks].v, kf1.v, sb1, 0,0,0);
    }
    f32x4 s[2]; s[0] = sa0 + sb0; s[1] = sa1 + sb1;

    // ---- no-max softmax: p = exp(s), causal mask only on boundary tiles ----
    float pv[2][4];
    if (kv0 + 31 <= cs + q0){          // interior: wave-uniform, no mask
      #pragma unroll
      for (int n=0;n<2;n++){
        #pragma unroll
        for (int r=0;r<4;r++) pv[n][r] = __expf(s[n][r]);
      }
    } else {
      #pragma unroll
      for (int n=0;n<2;n++){
        #pragma unroll
        for (int r=0;r<4;r++){
          bool ok = (kv0 + n*16 + ln) <= (prow0 + r);
          pv[n][r] = ok ? __expf(s[n][r]) : 0.f;
        }
      }
    }
    #pragma unroll
    for (int r=0;r<4;r++) lacc[r] += pv[0][r] + pv[1][r];

    // ---- split-pack P via cvt_pk + perm, store packed u32 to LDS ----
    #pragma unroll
    for (int n=0;n<2;n++){
      #pragma unroll
      for (int rp=0; rp<2; rp++){
        float p0 = pv[n][rp*2], p1 = pv[n][rp*2+1];
        u32 hpk, lpk;
        asm("v_cvt_pk_bf16_f32 %0, %1, %2" : "=v"(hpk) : "v"(p0), "v"(p1));
        float l0 = p0 - u2f(hpk << 16);
        float l1 = p1 - u2f(hpk & 0xffff0000u);
        asm("v_cvt_pk_bf16_f32 %0, %1, %2" : "=v"(lpk) : "v"(l0), "v"(l1));
        u32 w0 = __builtin_amdgcn_perm(lpk, hpk, 0x05040100u);  // h0|l0<<16
        u32 w1 = __builtin_amdgcn_perm(lpk, hpk, 0x07060302u);  // h1|l1<<16
        int row0 = lg*4 + rp*2;
        Pl[w*512 + ((row0*32 + n*16 + ln) ^ ((row0&7)<<2))] = w0;
        int row1 = row0 + 1;
        Pl[w*512 + ((row1*32 + n*16 + ln) ^ ((row1&7)<<2))] = w1;
      }
    }
    FragU pah[2], pal[2];
    #pragma unroll
    for (int ks2=0; ks2<2; ks2++){
      int fi = (ln*32 + ks2*16 + lg*4) ^ ((ln&7)<<2);
      u32x4 pp = *reinterpret_cast<const u32x4*>(&Pl[w*512 + fi]);
      #pragma unroll
      for (int i=0;i<4;i++){
        pah[ks2].q[i] = __builtin_amdgcn_perm(pp[i], pp[i], 0x01000100u); // h,h
        pal[ks2].q[i] = __builtin_amdgcn_perm(pp[i], pp[i], 0x03020302u); // l,l
      }
    }
    // ---- O += (Ph+Pl) x (Vh+Vl) ----
    const u16* Vc = (const u16*)(smem + 32768 + cur*16384);
    #pragma unroll
    for (int nf=0; nf<8; nf++){
      int dr = nf*16 + ln;
      #pragma unroll
      for (int ks2=0; ks2<2; ks2++){
        FragU vf;
        vf.q = *reinterpret_cast<const u32x4*>(&Vc[(dr*64 + ks2*32 + lg*8) ^ ((dr&7)<<3)]);
        O[nf] = __builtin_amdgcn_mfma_f32_16x16x32_bf16(pah[ks2].v, vf.v, O[nf], 0,0,0);
        O[nf] = __builtin_amdgcn_mfma_f32_16x16x32_bf16(pal[ks2].v, vf.v, O[nf], 0,0,0);
      }
    }
    // all LDS reads of buf[cur] landed -> license staging tile+2 into it
    asm volatile("s_waitcnt lgkmcnt(0)" ::: "memory");
    __builtin_amdgcn_s_barrier();
    if (tile+2 < nt){ stK(cur, tile+2); stV(cur, tile+2); }
  }

  // deferred row-sum reduce (once)
  #pragma unroll
  for (int off=1; off<16; off<<=1){
    #pragma unroll
    for (int r=0;r<4;r++) lacc[r] += __shfl_xor(lacc[r], off);
  }
  float il[4];
  #pragma unroll
  for (int r=0;r<4;r++) il[r] = 1.0f / lacc[r];
  u32* op = attnO + (size_t)(b*512 + q0 + lg*4)*4096 + h*128 + ln;
  #pragma unroll
  for (int nf=0; nf<8; nf++){
    #pragma unroll
    for (int r=0;r<4;r++)
      op[(size_t)r*4096 + nf*16] = pack2(O[nf][r] * il[r]);
  }
}

// ---------------------------------------------------------------------------
extern "C" void kernel_launch(void* const* d_in, const int* in_sizes, int n_in,
                              void* d_out, int out_size, void* d_ws, size_t ws_size,
                              hipStream_t stream) {
  const float* hidden    = (const float*)d_in[0];
  const float* cosT      = (const float*)d_in[1];
  const float* sinT      = (const float*)d_in[2];
  const int*   positions = (const int*)  d_in[3];
  const float* k_cache   = (const float*)d_in[4];
  const float* v_cache   = (const float*)d_in[5];
  const int*   page_tab  = (const int*)  d_in[6];
  const int*   cache_sl  = (const int*)  d_in[7];
  const float* qkv_w     = (const float*)d_in[9];
  const float* o_w       = (const float*)d_in[10];
  const float* qnw       = (const float*)d_in[11];
  const float* knw       = (const float*)d_in[12];
  float* out = (float*)d_out;

  u32* ws      = (u32*)d_ws;
  float* qkv   = (float*)ws;                // 2048*6144        = 12582912
  u32* k_all   = ws      + 12582912;        // 4*8*1024*128     =  4194304
  u32* v_allT  = k_all   + 4194304;         //                  =  4194304
  u32* attnPk  = v_allT  + 4194304;         // 2048*4096        =  8388608
  u32* hidPk   = attnPk  + 8388608;         // 2048*4096        =  8388608
  u32* qkvwPk  = hidPk   + 8388608;         // 6144*4096        = 25165824
  u32* owPk    = qkvwPk  + 25165824;        // 4096*4096        = 16777216
  (void)in_sizes; (void)n_in; (void)out_size; (void)ws_size;

  (void)hipFuncSetAttribute(reinterpret_cast<const void*>(gemm_pkA),
                            hipFuncAttributeMaxDynamicSharedMemorySize, 114688);
  (void)hipFuncSetAttribute(reinterpret_cast<const void*>(gemm_pkB),
                            hipFuncAttributeMaxDynamicSharedMemorySize, 98304);
  (void)hipFuncSetAttribute(reinterpret_cast<const void*>(attn_fused4),
                            hipFuncAttributeMaxDynamicSharedMemorySize, 73728);

  hipLaunchKernelGGL(split_pack, dim3(1024), dim3(256), 0, stream,
                     hidden, hidPk, 2097152);
  hipLaunchKernelGGL(split_pack, dim3(1024), dim3(256), 0, stream,
                     qkv_w, qkvwPk, 6291456);
  hipLaunchKernelGGL(split_pack, dim3(1024), dim3(256), 0, stream,
                     o_w, owPk, 4194304);
  hipLaunchKernelGGL(copy_cache, dim3(1024), dim3(256), 0, stream,
                     k_cache, v_cache, page_tab, k_all, v_allT);
  hipLaunchKernelGGL(gemm_pkA, dim3(256), dim3(512), 114688, stream,
                     hidPk, qkvwPk, qkv, 2048, 6144, 4096);
  hipLaunchKernelGGL(norm_rope_scatter, dim3(2048), dim3(256), 0, stream,
                     qkv, cosT, sinT, positions, cache_sl, qnw, knw, k_all, v_allT);
  hipLaunchKernelGGL(attn_fused4, dim3(1024), dim3(256), 73728, stream,
                     qkv, k_all, v_allT, cache_sl, attnPk);
  hipLaunchKernelGGL(gemm_pkB, dim3(256), dim3(512), 98304, stream,
                     attnPk, owPk, out, 2048, 4096, 4096);
}

// Round 9
// 549.444 us; speedup vs baseline: 1.4725x; 1.0386x over previous
//
#include <hip/hip_runtime.h>

typedef unsigned int   u32;
typedef unsigned short u16;

typedef float  f32x4  __attribute__((ext_vector_type(4)));
typedef u32    u32x4  __attribute__((ext_vector_type(4)));
typedef __bf16 bf16x8 __attribute__((ext_vector_type(8)));

union FragU { u16 us[8]; u32x4 q; bf16x8 v; };

__device__ __forceinline__ u32 f2u(float x){ union{float f;u32 u;}c; c.f=x; return c.u; }
__device__ __forceinline__ float u2f(u32 u){ union{float f;u32 u;}c; c.u=u; return c.f; }
__device__ __forceinline__ u16 bfhi(float x){ u32 u=f2u(x); return (u16)((u + 0x7fffu + ((u>>16)&1u))>>16); }
__device__ __forceinline__ float bff(u16 h){ return u2f(((u32)h)<<16); }
// fp32 -> (hi,lo) bf16 pair packed in one u32 (low half = hi part)
__device__ __forceinline__ u32 pack2(float x){
  u16 h = bfhi(x);
  u16 l = bfhi(x - bff(h));
  return (u32)h | ((u32)l << 16);
}

__device__ __forceinline__ void gload16(const void* g, void* l){
  __builtin_amdgcn_global_load_lds(
      (const __attribute__((address_space(1))) unsigned int*)g,
      (__attribute__((address_space(3))) unsigned int*)l, 16, 0, 0);
}

// ---------------------------------------------------------------------------
// Fused elementwise fp32 -> packed split-bf16 over three buffers.
// ---------------------------------------------------------------------------
__global__ __launch_bounds__(256)
void split_pack3(const float* __restrict__ s0, u32* __restrict__ d0, int n0,
                 const float* __restrict__ s1, u32* __restrict__ d1, int n1,
                 const float* __restrict__ s2, u32* __restrict__ d2, int n2)
{
  const int total = n0 + n1 + n2;
  for (int i = blockIdx.x*256 + threadIdx.x; i < total; i += gridDim.x*256){
    const float* s; u32* d; int j = i;
    if (j < n0)            { s = s0; d = d0; }
    else if (j < n0 + n1)  { s = s1; d = d1; j -= n0; }
    else                   { s = s2; d = d2; j -= n0 + n1; }
    float4 v = reinterpret_cast<const float4*>(s)[j];
    reinterpret_cast<u32x4*>(d)[j] =
      (u32x4){ pack2(v.x), pack2(v.y), pack2(v.z), pack2(v.w) };
  }
}

// ---------------------------------------------------------------------------
// 128x192-tile GEMM on pre-packed split-bf16 (grid 512 = 2 blocks/CU).
// 4 waves (2Mx2N), wave tile 64x96, BK=64 bf16, dbuf 80KB LDS,
// 2 fat phases/K-tile, counted vmcnt(6), both-sides swizzle, setprio.
// ---------------------------------------------------------------------------
__global__ __launch_bounds__(256, 2)
void gemm_pkA2(const u32* __restrict__ A, const u32* __restrict__ B,
               float* __restrict__ C, int M, int N, int K)  // K = u32 per row
{
  extern __shared__ char smem[];   // 81920 B: [buf2][ A 16KB | B 24KB ]
  const int tid  = threadIdx.x;
  const int lane = tid & 63;
  const int w    = tid >> 6;       // 0..3
  const int wm = w >> 1, wn = w & 1;
  const int ln = lane & 15, lg = lane >> 4;

  const int nbm = M >> 7;          // 128-row tiles
  const int nbn = N / 192;
  const int nwg = nbm * nbn;
  const int swz = (blockIdx.x & 7) * (nwg >> 3) + (blockIdx.x >> 3);
  const int bm = swz % nbm, bn = swz / nbm;

  const size_t rb = (size_t)K * 4;           // row bytes
  const int lrow  = lane >> 3;               // 0..7
  const int lslot = (lane & 7) ^ (lrow & 7); // pre-swizzled source slot
  const char* As0 = (const char*)A + (size_t)(bm*128 + w*8 + lrow)*rb + lslot*16;
  const char* Bs0 = (const char*)B + (size_t)(bn*192 + w*8 + lrow)*rb + lslot*16;

  auto stA = [&](int buf, int t) {           // 4 issues: 128 rows
    const char* s = As0 + ((size_t)t << 7);
    char* d = smem + buf*40960 + w*1024;
    gload16(s,           d);
    gload16(s +  32*rb,  d + 4096);
    gload16(s +  64*rb,  d + 8192);
    gload16(s +  96*rb,  d + 12288);
  };
  auto stB = [&](int buf, int t) {           // 6 issues: 192 rows
    const char* s = Bs0 + ((size_t)t << 7);
    char* d = smem + buf*40960 + 16384 + w*1024;
    gload16(s,           d);
    gload16(s +  32*rb,  d + 4096);
    gload16(s +  64*rb,  d + 8192);
    gload16(s +  96*rb,  d + 12288);
    gload16(s + 128*rb,  d + 16384);
    gload16(s + 160*rb,  d + 20480);
  };

  f32x4 z = {0.f,0.f,0.f,0.f};
  f32x4 acc[4][6];
  #pragma unroll
  for (int i=0;i<4;i++){
    #pragma unroll
    for (int j=0;j<6;j++) acc[i][j] = z;
  }

  const int nt = K >> 5;           // K-tiles of 32 u32 (=64 bf16)
  stA(0, 0); stB(0, 0);            // 10 loads
  if (nt > 1) { stB(1, 1);         // +6
    asm volatile("s_waitcnt vmcnt(6)" ::: "memory");   // tile0's 10 complete
  } else {
    asm volatile("s_waitcnt vmcnt(0)" ::: "memory");
  }
  __builtin_amdgcn_s_barrier();
  asm volatile("" ::: "memory");

  const int lx7 = ln & 7;

  for (int t = 0; t < nt; ++t){
    const int cur = t & 1;
    const char* bufc = smem + cur*40960;

    // ---- phase 0: all B frags + A m-frags 0..1; stage A(t+1) ----
    FragU bfr[6][2];
    #pragma unroll
    for (int ni=0; ni<6; ni++){
      const int rofs = 16384 + (wn*96 + ni*16 + ln)*128;
      #pragma unroll
      for (int ks=0; ks<2; ks++)
        bfr[ni][ks].q = *reinterpret_cast<const u32x4*>(bufc + rofs + (((ks*4+lg)^lx7)<<4));
    }
    FragU af[2][2];
    #pragma unroll
    for (int mf=0; mf<2; mf++){
      const int rofs = (wm*64 + mf*16 + ln)*128;
      #pragma unroll
      for (int ks=0; ks<2; ks++)
        af[mf][ks].q = *reinterpret_cast<const u32x4*>(bufc + rofs + (((ks*4+lg)^lx7)<<4));
    }
    if (t+1 < nt) stA(cur^1, t+1);
    __builtin_amdgcn_s_barrier();
    __builtin_amdgcn_s_setprio(1);
    #pragma unroll
    for (int ks=0; ks<2; ks++){
      #pragma unroll
      for (int mf=0; mf<2; mf++){
        #pragma unroll
        for (int ni=0; ni<6; ni++)
          acc[mf][ni] = __builtin_amdgcn_mfma_f32_16x16x32_bf16(af[mf][ks].v, bfr[ni][ks].v, acc[mf][ni], 0,0,0);
      }
    }
    __builtin_amdgcn_s_setprio(0);
    // fence: all waves' B-frag reads done; licenses stB(t+2) into this buffer.
    asm volatile("s_waitcnt lgkmcnt(0)" ::: "memory");
    __builtin_amdgcn_s_barrier();

    // ---- phase 1: A m-frags 2..3; stage B(t+2) -> B[cur] ----
    FragU ag[2][2];
    #pragma unroll
    for (int mf=0; mf<2; mf++){
      const int rofs = (wm*64 + (mf+2)*16 + ln)*128;
      #pragma unroll
      for (int ks=0; ks<2; ks++)
        ag[mf][ks].q = *reinterpret_cast<const u32x4*>(bufc + rofs + (((ks*4+lg)^lx7)<<4));
    }
    if (t+2 < nt) stB(cur, t+2);
    __builtin_amdgcn_s_barrier();
    __builtin_amdgcn_s_setprio(1);
    #pragma unroll
    for (int ks=0; ks<2; ks++){
      #pragma unroll
      for (int mf=0; mf<2; mf++){
        #pragma unroll
        for (int ni=0; ni<6; ni++)
          acc[mf+2][ni] = __builtin_amdgcn_mfma_f32_16x16x32_bf16(ag[mf][ks].v, bfr[ni][ks].v, acc[mf+2][ni], 0,0,0);
      }
    }
    __builtin_amdgcn_s_setprio(0);
    // ---- iteration boundary: counted wait (never 0 mid-loop) ----
    if (t+1 < nt){
      if (t+2 < nt) asm volatile("s_waitcnt vmcnt(6)" ::: "memory");
      else          asm volatile("s_waitcnt vmcnt(0)" ::: "memory");
    }
    __builtin_amdgcn_s_barrier();
    asm volatile("" ::: "memory");
  }

  #pragma unroll
  for (int mi=0; mi<4; mi++){
    #pragma unroll
    for (int ni=0; ni<6; ni++){
      const int row0 = bm*128 + wm*64 + mi*16 + lg*4;
      const int col  = bn*192 + wn*96 + ni*16 + ln;
      #pragma unroll
      for (int r=0; r<4; r++)
        C[(size_t)(row0+r)*N + col] = acc[mi][ni][r];
    }
  }
}

// ---------------------------------------------------------------------------
// 128x128-tile GEMM (grid 512 = 2 blocks/CU for M=2048,N=4096).
// 4 waves (2Mx2N), wave tile 64x64, dbuf 64KB LDS, counted vmcnt(4).
// ---------------------------------------------------------------------------
__global__ __launch_bounds__(256, 2)
void gemm_pkB2(const u32* __restrict__ A, const u32* __restrict__ B,
               float* __restrict__ C, int M, int N, int K)  // K = u32 per row
{
  extern __shared__ char smem[];   // 65536 B: [buf2][ A 16KB | B 16KB ]
  const int tid  = threadIdx.x;
  const int lane = tid & 63;
  const int w    = tid >> 6;       // 0..3
  const int wm = w >> 1, wn = w & 1;
  const int ln = lane & 15, lg = lane >> 4;

  const int nbm = M >> 7, nbn = N >> 7;
  const int nwg = nbm * nbn;
  const int swz = (blockIdx.x & 7) * (nwg >> 3) + (blockIdx.x >> 3);
  const int bm = swz % nbm, bn = swz / nbm;

  const size_t rb = (size_t)K * 4;           // row bytes
  const int lrow  = lane >> 3;               // 0..7
  const int lslot = (lane & 7) ^ (lrow & 7); // pre-swizzled source slot
  const char* As0 = (const char*)A + (size_t)(bm*128 + w*8 + lrow)*rb + lslot*16;
  const char* Bs0 = (const char*)B + (size_t)(bn*128 + w*8 + lrow)*rb + lslot*16;

  auto stA = [&](int buf, int t) {           // 4 issues: 128 rows
    const char* s = As0 + ((size_t)t << 7);
    char* d = smem + buf*32768 + w*1024;
    gload16(s,           d);
    gload16(s +  32*rb,  d + 4096);
    gload16(s +  64*rb,  d + 8192);
    gload16(s +  96*rb,  d + 12288);
  };
  auto stB = [&](int buf, int t) {           // 4 issues: 128 rows
    const char* s = Bs0 + ((size_t)t << 7);
    char* d = smem + buf*32768 + 16384 + w*1024;
    gload16(s,           d);
    gload16(s +  32*rb,  d + 4096);
    gload16(s +  64*rb,  d + 8192);
    gload16(s +  96*rb,  d + 12288);
  };

  f32x4 z = {0.f,0.f,0.f,0.f};
  f32x4 acc[4][4];
  #pragma unroll
  for (int i=0;i<4;i++){
    #pragma unroll
    for (int j=0;j<4;j++) acc[i][j] = z;
  }

  const int nt = K >> 5;           // K-tiles of 32 u32 (=64 bf16)
  stA(0, 0); stB(0, 0);            // 8 loads
  if (nt > 1) { stB(1, 1);         // +4
    asm volatile("s_waitcnt vmcnt(4)" ::: "memory");   // tile0's 8 complete
  } else {
    asm volatile("s_waitcnt vmcnt(0)" ::: "memory");
  }
  __builtin_amdgcn_s_barrier();
  asm volatile("" ::: "memory");

  const int lx7 = ln & 7;

  for (int t = 0; t < nt; ++t){
    const int cur = t & 1;
    const char* bufc = smem + cur*32768;

    // ---- phase 0: all B frags + A m-frags 0..1; stage A(t+1) ----
    FragU bfr[4][2];
    #pragma unroll
    for (int ni=0; ni<4; ni++){
      const int rofs = 16384 + (wn*64 + ni*16 + ln)*128;
      #pragma unroll
      for (int ks=0; ks<2; ks++)
        bfr[ni][ks].q = *reinterpret_cast<const u32x4*>(bufc + rofs + (((ks*4+lg)^lx7)<<4));
    }
    FragU af[2][2];
    #pragma unroll
    for (int mf=0; mf<2; mf++){
      const int rofs = (wm*64 + mf*16 + ln)*128;
      #pragma unroll
      for (int ks=0; ks<2; ks++)
        af[mf][ks].q = *reinterpret_cast<const u32x4*>(bufc + rofs + (((ks*4+lg)^lx7)<<4));
    }
    if (t+1 < nt) stA(cur^1, t+1);
    __builtin_amdgcn_s_barrier();
    __builtin_amdgcn_s_setprio(1);
    #pragma unroll
    for (int ks=0; ks<2; ks++){
      #pragma unroll
      for (int mf=0; mf<2; mf++){
        #pragma unroll
        for (int ni=0; ni<4; ni++)
          acc[mf][ni] = __builtin_amdgcn_mfma_f32_16x16x32_bf16(af[mf][ks].v, bfr[ni][ks].v, acc[mf][ni], 0,0,0);
      }
    }
    __builtin_amdgcn_s_setprio(0);
    asm volatile("s_waitcnt lgkmcnt(0)" ::: "memory");
    __builtin_amdgcn_s_barrier();

    // ---- phase 1: A m-frags 2..3; stage B(t+2) -> B[cur] ----
    FragU ag[2][2];
    #pragma unroll
    for (int mf=0; mf<2; mf++){
      const int rofs = (wm*64 + (mf+2)*16 + ln)*128;
      #pragma unroll
      for (int ks=0; ks<2; ks++)
        ag[mf][ks].q = *reinterpret_cast<const u32x4*>(bufc + rofs + (((ks*4+lg)^lx7)<<4));
    }
    if (t+2 < nt) stB(cur, t+2);
    __builtin_amdgcn_s_barrier();
    __builtin_amdgcn_s_setprio(1);
    #pragma unroll
    for (int ks=0; ks<2; ks++){
      #pragma unroll
      for (int mf=0; mf<2; mf++){
        #pragma unroll
        for (int ni=0; ni<4; ni++)
          acc[mf+2][ni] = __builtin_amdgcn_mfma_f32_16x16x32_bf16(ag[mf][ks].v, bfr[ni][ks].v, acc[mf+2][ni], 0,0,0);
      }
    }
    __builtin_amdgcn_s_setprio(0);
    if (t+1 < nt){
      if (t+2 < nt) asm volatile("s_waitcnt vmcnt(4)" ::: "memory");
      else          asm volatile("s_waitcnt vmcnt(0)" ::: "memory");
    }
    __builtin_amdgcn_s_barrier();
    asm volatile("" ::: "memory");
  }

  #pragma unroll
  for (int mi=0; mi<4; mi++){
    #pragma unroll
    for (int ni=0; ni<4; ni++){
      const int row0 = bm*128 + wm*64 + mi*16 + lg*4;
      const int col  = bn*128 + wn*64 + ni*16 + ln;
      #pragma unroll
      for (int r=0; r<4; r++)
        C[(size_t)(row0+r)*N + col] = acc[mi][ni][r];
    }
  }
}

// ---------------------------------------------------------------------------
// Gather old paged cache into contiguous PACKED ws buffers.
// k_all  : u32 [B][HKV][1024][128]   v_allT : u32 [B][HKV][128][1024]
// ---------------------------------------------------------------------------
__global__ __launch_bounds__(256)
void copy_cache(const float* __restrict__ k_cache, const float* __restrict__ v_cache,
                const int* __restrict__ page_table,
                u32* __restrict__ k_all, u32* __restrict__ v_allT)
{
  __shared__ float tb[32][129];
  const int id = blockIdx.x;
  const int jt = id & 31, h = (id>>5)&7, b = id>>8;
  const int tid = threadIdx.x;
  const int j0 = jt*32;
  {
    int r = tid>>3, c = tid&7;
    int j = j0 + r;
    int page = page_table[b*64 + (j>>4)];
    int slot = j & 15;
    const float* ks = k_cache + (size_t)((page*16 + slot)*8 + h)*128;
    const float* vs = v_cache + (size_t)((page*16 + slot)*8 + h)*128;
    u32* kd = k_all + ((size_t)(b*8+h)*1024 + j)*128;
    #pragma unroll
    for (int i=0;i<4;i++){
      int d0 = (c + 8*i)*4;
      float4 k4 = *reinterpret_cast<const float4*>(ks + d0);
      *reinterpret_cast<u32x4*>(kd + d0) =
        (u32x4){ pack2(k4.x), pack2(k4.y), pack2(k4.z), pack2(k4.w) };
      float4 v4 = *reinterpret_cast<const float4*>(vs + d0);
      tb[r][d0+0]=v4.x; tb[r][d0+1]=v4.y; tb[r][d0+2]=v4.z; tb[r][d0+3]=v4.w;
    }
  }
  __syncthreads();
  {
    int dout = tid>>1, jh = tid&1;
    u32* vd = v_allT + ((size_t)(b*8+h)*128 + dout)*1024 + j0 + jh*16;
    #pragma unroll
    for (int i=0;i<4;i++){
      u32x4 o;
      o.x = pack2(tb[jh*16 + i*4 + 0][dout]);
      o.y = pack2(tb[jh*16 + i*4 + 1][dout]);
      o.z = pack2(tb[jh*16 + i*4 + 2][dout]);
      o.w = pack2(tb[jh*16 + i*4 + 3][dout]);
      *reinterpret_cast<u32x4*>(vd + i*4) = o;
    }
  }
}

// ---------------------------------------------------------------------------
// Per-head RMSNorm + partial RoPE + scatter new K/V (packed) into k_all/v_allT.
// ---------------------------------------------------------------------------
__global__ __launch_bounds__(256)
void norm_rope_scatter(float* __restrict__ qkv, const float* __restrict__ cosT,
                       const float* __restrict__ sinT, const int* __restrict__ positions,
                       const int* __restrict__ cache_seqlens,
                       const float* __restrict__ qw, const float* __restrict__ kw,
                       u32* __restrict__ k_all, u32* __restrict__ v_allT)
{
  const int t = blockIdx.x;
  const int lane = threadIdx.x & 63;
  const int w = threadIdx.x >> 6;
  const int b = t >> 9;        // QL = 512
  const int q = t & 511;
  const int pos  = positions[t];
  const int cpos = cache_seqlens[b] + q;
  for (int it=0; it<12; ++it){
    int h = it*4 + w;          // 0..47
    float* xp = qkv + (size_t)t*6144 + h*128 + 2*lane;
    float2 x = *reinterpret_cast<const float2*>(xp);
    if (h < 40){               // q + k heads get RMSNorm + RoPE
      float ss = x.x*x.x + x.y*x.y;
      #pragma unroll
      for (int mk=1; mk<64; mk<<=1) ss += __shfl_xor(ss, mk);
      float var = ss*(1.0f/128.0f) + 1e-6f;
      float rq = rsqrtf(var);
      rq = rq*(1.5f - 0.5f*var*rq*rq);   // Newton refine
      const float* wt = (h<32) ? qw : kw;
      x.x *= rq*wt[2*lane]; x.y *= rq*wt[2*lane+1];
      float px = __shfl_xor(x.x, 16);
      float py = __shfl_xor(x.y, 16);
      if (lane < 32){
        int ci = pos*32 + 2*(lane&15);
        float2 cc = *reinterpret_cast<const float2*>(cosT + ci);
        float2 sc = *reinterpret_cast<const float2*>(sinT + ci);
        if (lane < 16){ x.x = x.x*cc.x - px*sc.x; x.y = x.y*cc.y - py*sc.y; }
        else          { x.x = x.x*cc.x + px*sc.x; x.y = x.y*cc.y + py*sc.y; }
      }
    }
    if (h < 32){
      *reinterpret_cast<float2*>(xp) = x;   // q back in place (fp32)
    } else if (h < 40){
      u32* kp = k_all + ((size_t)(b*8 + (h-32))*1024 + cpos)*128 + 2*lane;
      kp[0] = pack2(x.x); kp[1] = pack2(x.y);
    } else {
      u32* vp = v_allT + ((size_t)(b*8 + (h-40))*128 + 2*lane)*1024 + cpos;
      vp[0]    = pack2(x.x);
      vp[1024] = pack2(x.y);
    }
  }
}

// ---------------------------------------------------------------------------
// Fused GQA causal attention v4: async dbuf K/V staging, counted vmcnt,
// no-max softmax (scores provably bounded), deferred l-reduce,
// cvt_pk/perm split-pack of P, interior-tile mask skip.
// ---------------------------------------------------------------------------
__global__ __launch_bounds__(256)
void attn_fused4(const float* __restrict__ qkv, const u32* __restrict__ k_all,
                 const u32* __restrict__ v_allT, const int* __restrict__ cache_seqlens,
                 u32* __restrict__ attnO)
{
  extern __shared__ char smem[];          // 72KB: K dbuf 32K | V dbuf 32K | P 8K
  u32* Pl = (u32*)(smem + 65536);         // [4][512] packed split-bf16
  const int tid = threadIdx.x, lane = tid&63, w = tid>>6;
  const int ln = lane&15, lg = lane>>4;
  const int id = blockIdx.x;
  const int qt = id & 7, g = (id>>3)&3, kvh = (id>>5)&7, b = id>>8;
  const int cs = cache_seqlens[b];
  const int h  = kvh*4 + g;
  const int q0 = qt*64 + w*16;
  const float SCALE = 0.08838834764831845f;  // 1/sqrt(128)
  f32x4 z = {0.f,0.f,0.f,0.f};

  FragU qf[8];
  {
    const float* qp = qkv + (size_t)(b*512 + q0 + ln)*6144 + h*128;
    #pragma unroll
    for (int ks=0; ks<8; ks++){
      int d0 = ks*16 + lg*4;
      float4 v4 = *reinterpret_cast<const float4*>(qp + d0);
      qf[ks].q = (u32x4){ pack2(v4.x*SCALE), pack2(v4.y*SCALE),
                          pack2(v4.z*SCALE), pack2(v4.w*SCALE) };
    }
  }
  f32x4 O[8];
  #pragma unroll
  for (int i=0;i<8;i++) O[i] = z;
  float lacc[4] = {0.f,0.f,0.f,0.f};
  const int prow0 = cs + q0 + lg*4;
  const int nt = (cs + qt*64 + 64 + 31) >> 5;
  const char* kbase = (const char*)(k_all  + (size_t)(b*8+kvh)*1024*128);
  const char* vbase = (const char*)(v_allT + (size_t)(b*8+kvh)*128*1024);

  const int krb = w*2 + (lane>>5);
  const int ksl = lane & 31;
  const int vrb = w*8 + (lane>>3);
  const int vsl = lane & 7;

  auto stK = [&](int buf, int t){
    #pragma unroll
    for (int i=0;i<4;i++){
      int row = i*8 + krb;
      const char* s = kbase + (size_t)(t*32 + row)*512 + ((ksl ^ (row&7))<<4);
      gload16(s, smem + buf*16384 + i*4096 + w*1024);
    }
  };
  auto stV = [&](int buf, int t){
    #pragma unroll
    for (int i=0;i<4;i++){
      int d = i*32 + vrb;
      const char* s = vbase + (size_t)d*4096 + (size_t)t*128 + ((vsl ^ (d&7))<<4);
      gload16(s, smem + 32768 + buf*16384 + i*4096 + w*1024);
    }
  };

  stK(0, 0); stV(0, 0);
  if (nt > 1){ stK(1, 1); stV(1, 1); }

  for (int tile=0; tile<nt; ++tile){
    const int cur = tile & 1;
    const int kv0 = tile*32;
    if (tile+1 < nt) asm volatile("s_waitcnt vmcnt(8)" ::: "memory");
    else             asm volatile("s_waitcnt vmcnt(0)" ::: "memory");
    __builtin_amdgcn_s_barrier();

    // ---- S = Q K^T (split-bf16 over K'=256), two 4-deep chains ----
    const u16* Kc = (const u16*)(smem + cur*16384);
    f32x4 sa0=z, sa1=z, sb0=z, sb1=z;
    #pragma unroll
    for (int ks=0; ks<4; ks++){
      int kb = ks*32 + lg*8;
      FragU kf0, kf1;
      kf0.q = *reinterpret_cast<const u32x4*>(&Kc[(ln*256 + kb) ^ ((ln&7)<<3)]);
      kf1.q = *reinterpret_cast<const u32x4*>(&Kc[((16+ln)*256 + kb) ^ (((16+ln)&7)<<3)]);
      sa0 = __builtin_amdgcn_mfma_f32_16x16x32_bf16(qf[ks].v, kf0.v, sa0, 0,0,0);
      sa1 = __builtin_amdgcn_mfma_f32_16x16x32_bf16(qf[ks].v, kf1.v, sa1, 0,0,0);
    }
    #pragma unroll
    for (int ks=4; ks<8; ks++){
      int kb = ks*32 + lg*8;
      FragU kf0, kf1;
      kf0.q = *reinterpret_cast<const u32x4*>(&Kc[(ln*256 + kb) ^ ((ln&7)<<3)]);
      kf1.q = *reinterpret_cast<const u32x4*>(&Kc[((16+ln)*256 + kb) ^ (((16+ln)&7)<<3)]);
      sb0 = __builtin_amdgcn_mfma_f32_16x16x32_bf16(qf[ks].v, kf0.v, sb0, 0,0,0);
      sb1 = __builtin_amdgcn_mfma_f32_16x16x32_bf16(qf[ks].v, kf1.v, sb1, 0,0,0);
    }
    f32x4 s[2]; s[0] = sa0 + sb0; s[1] = sa1 + sb1;

    // ---- no-max softmax: p = exp(s), causal mask only on boundary tiles ----
    float pv[2][4];
    if (kv0 + 31 <= cs + q0){          // interior: wave-uniform, no mask
      #pragma unroll
      for (int n=0;n<2;n++){
        #pragma unroll
        for (int r=0;r<4;r++) pv[n][r] = __expf(s[n][r]);
      }
    } else {
      #pragma unroll
      for (int n=0;n<2;n++){
        #pragma unroll
        for (int r=0;r<4;r++){
          bool ok = (kv0 + n*16 + ln) <= (prow0 + r);
          pv[n][r] = ok ? __expf(s[n][r]) : 0.f;
        }
      }
    }
    #pragma unroll
    for (int r=0;r<4;r++) lacc[r] += pv[0][r] + pv[1][r];

    // ---- split-pack P via cvt_pk + perm, store packed u32 to LDS ----
    #pragma unroll
    for (int n=0;n<2;n++){
      #pragma unroll
      for (int rp=0; rp<2; rp++){
        float p0 = pv[n][rp*2], p1 = pv[n][rp*2+1];
        u32 hpk, lpk;
        asm("v_cvt_pk_bf16_f32 %0, %1, %2" : "=v"(hpk) : "v"(p0), "v"(p1));
        float l0 = p0 - u2f(hpk << 16);
        float l1 = p1 - u2f(hpk & 0xffff0000u);
        asm("v_cvt_pk_bf16_f32 %0, %1, %2" : "=v"(lpk) : "v"(l0), "v"(l1));
        u32 w0 = __builtin_amdgcn_perm(lpk, hpk, 0x05040100u);  // h0|l0<<16
        u32 w1 = __builtin_amdgcn_perm(lpk, hpk, 0x07060302u);  // h1|l1<<16
        int row0 = lg*4 + rp*2;
        Pl[w*512 + ((row0*32 + n*16 + ln) ^ ((row0&7)<<2))] = w0;
        int row1 = row0 + 1;
        Pl[w*512 + ((row1*32 + n*16 + ln) ^ ((row1&7)<<2))] = w1;
      }
    }
    FragU pah[2], pal[2];
    #pragma unroll
    for (int ks2=0; ks2<2; ks2++){
      int fi = (ln*32 + ks2*16 + lg*4) ^ ((ln&7)<<2);
      u32x4 pp = *reinterpret_cast<const u32x4*>(&Pl[w*512 + fi]);
      #pragma unroll
      for (int i=0;i<4;i++){
        pah[ks2].q[i] = __builtin_amdgcn_perm(pp[i], pp[i], 0x01000100u); // h,h
        pal[ks2].q[i] = __builtin_amdgcn_perm(pp[i], pp[i], 0x03020302u); // l,l
      }
    }
    // ---- O += (Ph+Pl) x (Vh+Vl) ----
    const u16* Vc = (const u16*)(smem + 32768 + cur*16384);
    #pragma unroll
    for (int nf=0; nf<8; nf++){
      int dr = nf*16 + ln;
      #pragma unroll
      for (int ks2=0; ks2<2; ks2++){
        FragU vf;
        vf.q = *reinterpret_cast<const u32x4*>(&Vc[(dr*64 + ks2*32 + lg*8) ^ ((dr&7)<<3)]);
        O[nf] = __builtin_amdgcn_mfma_f32_16x16x32_bf16(pah[ks2].v, vf.v, O[nf], 0,0,0);
        O[nf] = __builtin_amdgcn_mfma_f32_16x16x32_bf16(pal[ks2].v, vf.v, O[nf], 0,0,0);
      }
    }
    asm volatile("s_waitcnt lgkmcnt(0)" ::: "memory");
    __builtin_amdgcn_s_barrier();
    if (tile+2 < nt){ stK(cur, tile+2); stV(cur, tile+2); }
  }

  // deferred row-sum reduce (once)
  #pragma unroll
  for (int off=1; off<16; off<<=1){
    #pragma unroll
    for (int r=0;r<4;r++) lacc[r] += __shfl_xor(lacc[r], off);
  }
  float il[4];
  #pragma unroll
  for (int r=0;r<4;r++) il[r] = 1.0f / lacc[r];
  u32* op = attnO + (size_t)(b*512 + q0 + lg*4)*4096 + h*128 + ln;
  #pragma unroll
  for (int nf=0; nf<8; nf++){
    #pragma unroll
    for (int r=0;r<4;r++)
      op[(size_t)r*4096 + nf*16] = pack2(O[nf][r] * il[r]);
  }
}

// ---------------------------------------------------------------------------
extern "C" void kernel_launch(void* const* d_in, const int* in_sizes, int n_in,
                              void* d_out, int out_size, void* d_ws, size_t ws_size,
                              hipStream_t stream) {
  const float* hidden    = (const float*)d_in[0];
  const float* cosT      = (const float*)d_in[1];
  const float* sinT      = (const float*)d_in[2];
  const int*   positions = (const int*)  d_in[3];
  const float* k_cache   = (const float*)d_in[4];
  const float* v_cache   = (const float*)d_in[5];
  const int*   page_tab  = (const int*)  d_in[6];
  const int*   cache_sl  = (const int*)  d_in[7];
  const float* qkv_w     = (const float*)d_in[9];
  const float* o_w       = (const float*)d_in[10];
  const float* qnw       = (const float*)d_in[11];
  const float* knw       = (const float*)d_in[12];
  float* out = (float*)d_out;

  u32* ws      = (u32*)d_ws;
  float* qkv   = (float*)ws;                // 2048*6144        = 12582912
  u32* k_all   = ws      + 12582912;        // 4*8*1024*128     =  4194304
  u32* v_allT  = k_all   + 4194304;         //                  =  4194304
  u32* attnPk  = v_allT  + 4194304;         // 2048*4096        =  8388608
  u32* hidPk   = attnPk  + 8388608;         // 2048*4096        =  8388608
  u32* qkvwPk  = hidPk   + 8388608;         // 6144*4096        = 25165824
  u32* owPk    = qkvwPk  + 25165824;        // 4096*4096        = 16777216
  (void)in_sizes; (void)n_in; (void)out_size; (void)ws_size;

  (void)hipFuncSetAttribute(reinterpret_cast<const void*>(gemm_pkA2),
                            hipFuncAttributeMaxDynamicSharedMemorySize, 81920);
  (void)hipFuncSetAttribute(reinterpret_cast<const void*>(gemm_pkB2),
                            hipFuncAttributeMaxDynamicSharedMemorySize, 65536);
  (void)hipFuncSetAttribute(reinterpret_cast<const void*>(attn_fused4),
                            hipFuncAttributeMaxDynamicSharedMemorySize, 73728);

  hipLaunchKernelGGL(split_pack3, dim3(2048), dim3(256), 0, stream,
                     hidden, hidPk, 2097152,
                     qkv_w, qkvwPk, 6291456,
                     o_w, owPk, 4194304);
  hipLaunchKernelGGL(copy_cache, dim3(1024), dim3(256), 0, stream,
                     k_cache, v_cache, page_tab, k_all, v_allT);
  hipLaunchKernelGGL(gemm_pkA2, dim3(512), dim3(256), 81920, stream,
                     hidPk, qkvwPk, qkv, 2048, 6144, 4096);
  hipLaunchKernelGGL(norm_rope_scatter, dim3(2048), dim3(256), 0, stream,
                     qkv, cosT, sinT, positions, cache_sl, qnw, knw, k_all, v_allT);
  hipLaunchKernelGGL(attn_fused4, dim3(1024), dim3(256), 73728, stream,
                     qkv, k_all, v_allT, cache_sl, attnPk);
  hipLaunchKernelGGL(gemm_pkB2, dim3(512), dim3(256), 65536, stream,
                     attnPk, owPk, out, 2048, 4096, 4096);
}

// Round 11
// 365.440 us; speedup vs baseline: 2.2139x; 1.5035x over previous
//
#include <hip/hip_runtime.h>

typedef unsigned int   u32;
typedef unsigned short u16;

typedef float  f32x4  __attribute__((ext_vector_type(4)));
typedef u32    u32x4  __attribute__((ext_vector_type(4)));
typedef u16    u16x4  __attribute__((ext_vector_type(4)));
typedef __bf16 bf16x8 __attribute__((ext_vector_type(8)));

union FragU { u16 us[8]; u32x4 q; bf16x8 v; };

__device__ __forceinline__ u32 f2u(float x){ union{float f;u32 u;}c; c.f=x; return c.u; }
__device__ __forceinline__ float u2f(u32 u){ union{float f;u32 u;}c; c.u=u; return c.f; }
__device__ __forceinline__ u16 bfhi(float x){ u32 u=f2u(x); return (u16)((u + 0x7fffu + ((u>>16)&1u))>>16); }
__device__ __forceinline__ float bff(u16 h){ return u2f(((u32)h)<<16); }
// fp32 -> (hi,lo) bf16 pair packed in one u32 (low half = hi part)
__device__ __forceinline__ u32 pack2(float x){
  u16 h = bfhi(x);
  u16 l = bfhi(x - bff(h));
  return (u32)h | ((u32)l << 16);
}

__device__ __forceinline__ void gload16(const void* g, void* l){
  __builtin_amdgcn_global_load_lds(
      (const __attribute__((address_space(1))) unsigned int*)g,
      (__attribute__((address_space(3))) unsigned int*)l, 16, 0, 0);
}

// ---------------------------------------------------------------------------
// Fused elementwise fp32 -> bf16 over three buffers (4 elems per index).
// ---------------------------------------------------------------------------
__global__ __launch_bounds__(256)
void bf16_pack3(const float* __restrict__ s0, u16* __restrict__ d0, int n0,
                const float* __restrict__ s1, u16* __restrict__ d1, int n1,
                const float* __restrict__ s2, u16* __restrict__ d2, int n2)
{
  const int total = n0 + n1 + n2;
  for (int i = blockIdx.x*256 + threadIdx.x; i < total; i += gridDim.x*256){
    const float* s; u16* d; int j = i;
    if (j < n0)            { s = s0; d = d0; }
    else if (j < n0 + n1)  { s = s1; d = d1; j -= n0; }
    else                   { s = s2; d = d2; j -= n0 + n1; }
    float4 v = reinterpret_cast<const float4*>(s)[j];
    reinterpret_cast<u16x4*>(d)[j] =
      (u16x4){ bfhi(v.x), bfhi(v.y), bfhi(v.z), bfhi(v.w) };
  }
}

// ---------------------------------------------------------------------------
// 128x192-tile GEMM on bf16 (grid 512 = 2 blocks/CU).
// 4 waves (2Mx2N), wave tile 64x96, BK=64 bf16 (=128B/row), dbuf 80KB LDS,
// 2 fat phases/K-tile, counted vmcnt(6), both-sides swizzle, setprio.
// ---------------------------------------------------------------------------
__global__ __launch_bounds__(256, 2)
void gemm_pkA2(const u16* __restrict__ A, const u16* __restrict__ B,
               float* __restrict__ C, int M, int N, int K)  // K = bf16 per row
{
  extern __shared__ char smem[];   // 81920 B: [buf2][ A 16KB | B 24KB ]
  const int tid  = threadIdx.x;
  const int lane = tid & 63;
  const int w    = tid >> 6;       // 0..3
  const int wm = w >> 1, wn = w & 1;
  const int ln = lane & 15, lg = lane >> 4;

  const int nbm = M >> 7;          // 128-row tiles
  const int nbn = N / 192;
  const int nwg = nbm * nbn;
  const int swz = (blockIdx.x & 7) * (nwg >> 3) + (blockIdx.x >> 3);
  const int bm = swz % nbm, bn = swz / nbm;

  const size_t rb = (size_t)K * 2;           // row bytes
  const int lrow  = lane >> 3;               // 0..7
  const int lslot = (lane & 7) ^ (lrow & 7); // pre-swizzled source slot
  const char* As0 = (const char*)A + (size_t)(bm*128 + w*8 + lrow)*rb + lslot*16;
  const char* Bs0 = (const char*)B + (size_t)(bn*192 + w*8 + lrow)*rb + lslot*16;

  auto stA = [&](int buf, int t) {           // 4 issues: 128 rows
    const char* s = As0 + ((size_t)t << 7);
    char* d = smem + buf*40960 + w*1024;
    gload16(s,           d);
    gload16(s +  32*rb,  d + 4096);
    gload16(s +  64*rb,  d + 8192);
    gload16(s +  96*rb,  d + 12288);
  };
  auto stB = [&](int buf, int t) {           // 6 issues: 192 rows
    const char* s = Bs0 + ((size_t)t << 7);
    char* d = smem + buf*40960 + 16384 + w*1024;
    gload16(s,           d);
    gload16(s +  32*rb,  d + 4096);
    gload16(s +  64*rb,  d + 8192);
    gload16(s +  96*rb,  d + 12288);
    gload16(s + 128*rb,  d + 16384);
    gload16(s + 160*rb,  d + 20480);
  };

  f32x4 z = {0.f,0.f,0.f,0.f};
  f32x4 acc[4][6];
  #pragma unroll
  for (int i=0;i<4;i++){
    #pragma unroll
    for (int j=0;j<6;j++) acc[i][j] = z;
  }

  const int nt = K >> 6;           // K-tiles of 64 bf16
  stA(0, 0); stB(0, 0);            // 10 loads
  if (nt > 1) { stB(1, 1);         // +6
    asm volatile("s_waitcnt vmcnt(6)" ::: "memory");   // tile0's 10 complete
  } else {
    asm volatile("s_waitcnt vmcnt(0)" ::: "memory");
  }
  __builtin_amdgcn_s_barrier();
  asm volatile("" ::: "memory");

  const int lx7 = ln & 7;

  for (int t = 0; t < nt; ++t){
    const int cur = t & 1;
    const char* bufc = smem + cur*40960;

    // ---- phase 0: all B frags + A m-frags 0..1; stage A(t+1) ----
    FragU bfr[6][2];
    #pragma unroll
    for (int ni=0; ni<6; ni++){
      const int rofs = 16384 + (wn*96 + ni*16 + ln)*128;
      #pragma unroll
      for (int ks=0; ks<2; ks++)
        bfr[ni][ks].q = *reinterpret_cast<const u32x4*>(bufc + rofs + (((ks*4+lg)^lx7)<<4));
    }
    FragU af[2][2];
    #pragma unroll
    for (int mf=0; mf<2; mf++){
      const int rofs = (wm*64 + mf*16 + ln)*128;
      #pragma unroll
      for (int ks=0; ks<2; ks++)
        af[mf][ks].q = *reinterpret_cast<const u32x4*>(bufc + rofs + (((ks*4+lg)^lx7)<<4));
    }
    if (t+1 < nt) stA(cur^1, t+1);
    __builtin_amdgcn_s_barrier();
    __builtin_amdgcn_s_setprio(1);
    #pragma unroll
    for (int ks=0; ks<2; ks++){
      #pragma unroll
      for (int mf=0; mf<2; mf++){
        #pragma unroll
        for (int ni=0; ni<6; ni++)
          acc[mf][ni] = __builtin_amdgcn_mfma_f32_16x16x32_bf16(af[mf][ks].v, bfr[ni][ks].v, acc[mf][ni], 0,0,0);
      }
    }
    __builtin_amdgcn_s_setprio(0);
    // fence: all waves' B-frag reads done; licenses stB(t+2) into this buffer.
    asm volatile("s_waitcnt lgkmcnt(0)" ::: "memory");
    __builtin_amdgcn_s_barrier();

    // ---- phase 1: A m-frags 2..3; stage B(t+2) -> B[cur] ----
    FragU ag[2][2];
    #pragma unroll
    for (int mf=0; mf<2; mf++){
      const int rofs = (wm*64 + (mf+2)*16 + ln)*128;
      #pragma unroll
      for (int ks=0; ks<2; ks++)
        ag[mf][ks].q = *reinterpret_cast<const u32x4*>(bufc + rofs + (((ks*4+lg)^lx7)<<4));
    }
    if (t+2 < nt) stB(cur, t+2);
    __builtin_amdgcn_s_barrier();
    __builtin_amdgcn_s_setprio(1);
    #pragma unroll
    for (int ks=0; ks<2; ks++){
      #pragma unroll
      for (int mf=0; mf<2; mf++){
        #pragma unroll
        for (int ni=0; ni<6; ni++)
          acc[mf+2][ni] = __builtin_amdgcn_mfma_f32_16x16x32_bf16(ag[mf][ks].v, bfr[ni][ks].v, acc[mf+2][ni], 0,0,0);
      }
    }
    __builtin_amdgcn_s_setprio(0);
    // ---- iteration boundary: counted wait (never 0 mid-loop) ----
    if (t+1 < nt){
      if (t+2 < nt) asm volatile("s_waitcnt vmcnt(6)" ::: "memory");
      else          asm volatile("s_waitcnt vmcnt(0)" ::: "memory");
    }
    __builtin_amdgcn_s_barrier();
    asm volatile("" ::: "memory");
  }

  #pragma unroll
  for (int mi=0; mi<4; mi++){
    #pragma unroll
    for (int ni=0; ni<6; ni++){
      const int row0 = bm*128 + wm*64 + mi*16 + lg*4;
      const int col  = bn*192 + wn*96 + ni*16 + ln;
      #pragma unroll
      for (int r=0; r<4; r++)
        C[(size_t)(row0+r)*N + col] = acc[mi][ni][r];
    }
  }
}

// ---------------------------------------------------------------------------
// 128x128-tile bf16 GEMM (grid 512 = 2 blocks/CU for M=2048,N=4096).
// 4 waves (2Mx2N), wave tile 64x64, dbuf 64KB LDS, counted vmcnt(4).
// ---------------------------------------------------------------------------
__global__ __launch_bounds__(256, 2)
void gemm_pkB2(const u16* __restrict__ A, const u16* __restrict__ B,
               float* __restrict__ C, int M, int N, int K)  // K = bf16 per row
{
  extern __shared__ char smem[];   // 65536 B: [buf2][ A 16KB | B 16KB ]
  const int tid  = threadIdx.x;
  const int lane = tid & 63;
  const int w    = tid >> 6;       // 0..3
  const int wm = w >> 1, wn = w & 1;
  const int ln = lane & 15, lg = lane >> 4;

  const int nbm = M >> 7, nbn = N >> 7;
  const int nwg = nbm * nbn;
  const int swz = (blockIdx.x & 7) * (nwg >> 3) + (blockIdx.x >> 3);
  const int bm = swz % nbm, bn = swz / nbm;

  const size_t rb = (size_t)K * 2;           // row bytes
  const int lrow  = lane >> 3;               // 0..7
  const int lslot = (lane & 7) ^ (lrow & 7); // pre-swizzled source slot
  const char* As0 = (const char*)A + (size_t)(bm*128 + w*8 + lrow)*rb + lslot*16;
  const char* Bs0 = (const char*)B + (size_t)(bn*128 + w*8 + lrow)*rb + lslot*16;

  auto stA = [&](int buf, int t) {           // 4 issues: 128 rows
    const char* s = As0 + ((size_t)t << 7);
    char* d = smem + buf*32768 + w*1024;
    gload16(s,           d);
    gload16(s +  32*rb,  d + 4096);
    gload16(s +  64*rb,  d + 8192);
    gload16(s +  96*rb,  d + 12288);
  };
  auto stB = [&](int buf, int t) {           // 4 issues: 128 rows
    const char* s = Bs0 + ((size_t)t << 7);
    char* d = smem + buf*32768 + 16384 + w*1024;
    gload16(s,           d);
    gload16(s +  32*rb,  d + 4096);
    gload16(s +  64*rb,  d + 8192);
    gload16(s +  96*rb,  d + 12288);
  };

  f32x4 z = {0.f,0.f,0.f,0.f};
  f32x4 acc[4][4];
  #pragma unroll
  for (int i=0;i<4;i++){
    #pragma unroll
    for (int j=0;j<4;j++) acc[i][j] = z;
  }

  const int nt = K >> 6;           // K-tiles of 64 bf16
  stA(0, 0); stB(0, 0);            // 8 loads
  if (nt > 1) { stB(1, 1);         // +4
    asm volatile("s_waitcnt vmcnt(4)" ::: "memory");   // tile0's 8 complete
  } else {
    asm volatile("s_waitcnt vmcnt(0)" ::: "memory");
  }
  __builtin_amdgcn_s_barrier();
  asm volatile("" ::: "memory");

  const int lx7 = ln & 7;

  for (int t = 0; t < nt; ++t){
    const int cur = t & 1;
    const char* bufc = smem + cur*32768;

    // ---- phase 0: all B frags + A m-frags 0..1; stage A(t+1) ----
    FragU bfr[4][2];
    #pragma unroll
    for (int ni=0; ni<4; ni++){
      const int rofs = 16384 + (wn*64 + ni*16 + ln)*128;
      #pragma unroll
      for (int ks=0; ks<2; ks++)
        bfr[ni][ks].q = *reinterpret_cast<const u32x4*>(bufc + rofs + (((ks*4+lg)^lx7)<<4));
    }
    FragU af[2][2];
    #pragma unroll
    for (int mf=0; mf<2; mf++){
      const int rofs = (wm*64 + mf*16 + ln)*128;
      #pragma unroll
      for (int ks=0; ks<2; ks++)
        af[mf][ks].q = *reinterpret_cast<const u32x4*>(bufc + rofs + (((ks*4+lg)^lx7)<<4));
    }
    if (t+1 < nt) stA(cur^1, t+1);
    __builtin_amdgcn_s_barrier();
    __builtin_amdgcn_s_setprio(1);
    #pragma unroll
    for (int ks=0; ks<2; ks++){
      #pragma unroll
      for (int mf=0; mf<2; mf++){
        #pragma unroll
        for (int ni=0; ni<4; ni++)
          acc[mf][ni] = __builtin_amdgcn_mfma_f32_16x16x32_bf16(af[mf][ks].v, bfr[ni][ks].v, acc[mf][ni], 0,0,0);
      }
    }
    __builtin_amdgcn_s_setprio(0);
    asm volatile("s_waitcnt lgkmcnt(0)" ::: "memory");
    __builtin_amdgcn_s_barrier();

    // ---- phase 1: A m-frags 2..3; stage B(t+2) -> B[cur] ----
    FragU ag[2][2];
    #pragma unroll
    for (int mf=0; mf<2; mf++){
      const int rofs = (wm*64 + (mf+2)*16 + ln)*128;
      #pragma unroll
      for (int ks=0; ks<2; ks++)
        ag[mf][ks].q = *reinterpret_cast<const u32x4*>(bufc + rofs + (((ks*4+lg)^lx7)<<4));
    }
    if (t+2 < nt) stB(cur, t+2);
    __builtin_amdgcn_s_barrier();
    __builtin_amdgcn_s_setprio(1);
    #pragma unroll
    for (int ks=0; ks<2; ks++){
      #pragma unroll
      for (int mf=0; mf<2; mf++){
        #pragma unroll
        for (int ni=0; ni<4; ni++)
          acc[mf+2][ni] = __builtin_amdgcn_mfma_f32_16x16x32_bf16(ag[mf][ks].v, bfr[ni][ks].v, acc[mf+2][ni], 0,0,0);
      }
    }
    __builtin_amdgcn_s_setprio(0);
    if (t+1 < nt){
      if (t+2 < nt) asm volatile("s_waitcnt vmcnt(4)" ::: "memory");
      else          asm volatile("s_waitcnt vmcnt(0)" ::: "memory");
    }
    __builtin_amdgcn_s_barrier();
    asm volatile("" ::: "memory");
  }

  #pragma unroll
  for (int mi=0; mi<4; mi++){
    #pragma unroll
    for (int ni=0; ni<4; ni++){
      const int row0 = bm*128 + wm*64 + mi*16 + lg*4;
      const int col  = bn*128 + wn*64 + ni*16 + ln;
      #pragma unroll
      for (int r=0; r<4; r++)
        C[(size_t)(row0+r)*N + col] = acc[mi][ni][r];
    }
  }
}

// ---------------------------------------------------------------------------
// Gather old paged cache into contiguous ws buffers.
// k_all  : bf16 [B][HKV][1024][128]   v_allT : packed u32 [B][HKV][128][1024]
// ---------------------------------------------------------------------------
__global__ __launch_bounds__(256)
void copy_cache(const float* __restrict__ k_cache, const float* __restrict__ v_cache,
                const int* __restrict__ page_table,
                u16* __restrict__ k_all, u32* __restrict__ v_allT)
{
  __shared__ float tb[32][129];
  const int id = blockIdx.x;
  const int jt = id & 31, h = (id>>5)&7, b = id>>8;
  const int tid = threadIdx.x;
  const int j0 = jt*32;
  {
    int r = tid>>3, c = tid&7;
    int j = j0 + r;
    int page = page_table[b*64 + (j>>4)];
    int slot = j & 15;
    const float* ks = k_cache + (size_t)((page*16 + slot)*8 + h)*128;
    const float* vs = v_cache + (size_t)((page*16 + slot)*8 + h)*128;
    u16* kd = k_all + ((size_t)(b*8+h)*1024 + j)*128;
    #pragma unroll
    for (int i=0;i<4;i++){
      int d0 = (c + 8*i)*4;
      float4 k4 = *reinterpret_cast<const float4*>(ks + d0);
      *reinterpret_cast<u16x4*>(kd + d0) =
        (u16x4){ bfhi(k4.x), bfhi(k4.y), bfhi(k4.z), bfhi(k4.w) };
      float4 v4 = *reinterpret_cast<const float4*>(vs + d0);
      tb[r][d0+0]=v4.x; tb[r][d0+1]=v4.y; tb[r][d0+2]=v4.z; tb[r][d0+3]=v4.w;
    }
  }
  __syncthreads();
  {
    int dout = tid>>1, jh = tid&1;
    u32* vd = v_allT + ((size_t)(b*8+h)*128 + dout)*1024 + j0 + jh*16;
    #pragma unroll
    for (int i=0;i<4;i++){
      u32x4 o;
      o.x = pack2(tb[jh*16 + i*4 + 0][dout]);
      o.y = pack2(tb[jh*16 + i*4 + 1][dout]);
      o.z = pack2(tb[jh*16 + i*4 + 2][dout]);
      o.w = pack2(tb[jh*16 + i*4 + 3][dout]);
      *reinterpret_cast<u32x4*>(vd + i*4) = o;
    }
  }
}

// ---------------------------------------------------------------------------
// Per-head RMSNorm + partial RoPE + scatter new K (bf16) / V (packed).
// ---------------------------------------------------------------------------
__global__ __launch_bounds__(256)
void norm_rope_scatter(float* __restrict__ qkv, const float* __restrict__ cosT,
                       const float* __restrict__ sinT, const int* __restrict__ positions,
                       const int* __restrict__ cache_seqlens,
                       const float* __restrict__ qw, const float* __restrict__ kw,
                       u16* __restrict__ k_all, u32* __restrict__ v_allT)
{
  const int t = blockIdx.x;
  const int lane = threadIdx.x & 63;
  const int w = threadIdx.x >> 6;
  const int b = t >> 9;        // QL = 512
  const int q = t & 511;
  const int pos  = positions[t];
  const int cpos = cache_seqlens[b] + q;
  for (int it=0; it<12; ++it){
    int h = it*4 + w;          // 0..47
    float* xp = qkv + (size_t)t*6144 + h*128 + 2*lane;
    float2 x = *reinterpret_cast<const float2*>(xp);
    if (h < 40){               // q + k heads get RMSNorm + RoPE
      float ss = x.x*x.x + x.y*x.y;
      #pragma unroll
      for (int mk=1; mk<64; mk<<=1) ss += __shfl_xor(ss, mk);
      float var = ss*(1.0f/128.0f) + 1e-6f;
      float rq = rsqrtf(var);
      rq = rq*(1.5f - 0.5f*var*rq*rq);   // Newton refine
      const float* wt = (h<32) ? qw : kw;
      x.x *= rq*wt[2*lane]; x.y *= rq*wt[2*lane+1];
      float px = __shfl_xor(x.x, 16);
      float py = __shfl_xor(x.y, 16);
      if (lane < 32){
        int ci = pos*32 + 2*(lane&15);
        float2 cc = *reinterpret_cast<const float2*>(cosT + ci);
        float2 sc = *reinterpret_cast<const float2*>(sinT + ci);
        if (lane < 16){ x.x = x.x*cc.x - px*sc.x; x.y = x.y*cc.y - py*sc.y; }
        else          { x.x = x.x*cc.x + px*sc.x; x.y = x.y*cc.y + py*sc.y; }
      }
    }
    if (h < 32){
      *reinterpret_cast<float2*>(xp) = x;   // q back in place (fp32)
    } else if (h < 40){
      u16* kp = k_all + ((size_t)(b*8 + (h-32))*1024 + cpos)*128 + 2*lane;
      kp[0] = bfhi(x.x); kp[1] = bfhi(x.y);
    } else {
      u32* vp = v_allT + ((size_t)(b*8 + (h-40))*128 + 2*lane)*1024 + cpos;
      vp[0]    = pack2(x.x);
      vp[1024] = pack2(x.y);
    }
  }
}

// ---------------------------------------------------------------------------
// Fused GQA causal attention v5: bf16 K (QK^T over D=128, 8 MFMA/tile),
// split-packed V (PV exact), async dbuf staging, counted vmcnt(6),
// no-max softmax, deferred l-reduce, bf16 output.  LDS 56KB.
// ---------------------------------------------------------------------------
__global__ __launch_bounds__(256)
void attn_fused5(const float* __restrict__ qkv, const u16* __restrict__ k_all,
                 const u32* __restrict__ v_allT, const int* __restrict__ cache_seqlens,
                 u16* __restrict__ attnO)
{
  extern __shared__ char smem[];          // 56KB: K dbuf 16K | V dbuf 32K | P 8K
  u32* Pl = (u32*)(smem + 49152);         // [4][512] packed split-bf16
  const int tid = threadIdx.x, lane = tid&63, w = tid>>6;
  const int ln = lane&15, lg = lane>>4;
  const int id = blockIdx.x;
  const int qt = id & 7, g = (id>>3)&3, kvh = (id>>5)&7, b = id>>8;
  const int cs = cache_seqlens[b];
  const int h  = kvh*4 + g;
  const int q0 = qt*64 + w*16;
  const float SCALE = 0.08838834764831845f;  // 1/sqrt(128)
  f32x4 z = {0.f,0.f,0.f,0.f};

  FragU qf[4];
  {
    const float* qp = qkv + (size_t)(b*512 + q0 + ln)*6144 + h*128;
    #pragma unroll
    for (int ks=0; ks<4; ks++){
      int d0 = ks*32 + lg*8;
      float4 a = *reinterpret_cast<const float4*>(qp + d0);
      float4 c = *reinterpret_cast<const float4*>(qp + d0 + 4);
      qf[ks].q = (u32x4){
        (u32)bfhi(a.x*SCALE) | ((u32)bfhi(a.y*SCALE)<<16),
        (u32)bfhi(a.z*SCALE) | ((u32)bfhi(a.w*SCALE)<<16),
        (u32)bfhi(c.x*SCALE) | ((u32)bfhi(c.y*SCALE)<<16),
        (u32)bfhi(c.z*SCALE) | ((u32)bfhi(c.w*SCALE)<<16) };
    }
  }
  f32x4 O[8];
  #pragma unroll
  for (int i=0;i<8;i++) O[i] = z;
  float lacc[4] = {0.f,0.f,0.f,0.f};
  const int prow0 = cs + q0 + lg*4;
  const int nt = (cs + qt*64 + 64 + 31) >> 5;
  const char* kbase = (const char*)(k_all  + (size_t)(b*8+kvh)*1024*128);
  const char* vbase = (const char*)(v_allT + (size_t)(b*8+kvh)*128*1024);

  const int vrb = w*8 + (lane>>3);
  const int vsl = lane & 7;

  auto stK = [&](int buf, int t){            // 2 issues: 32 rows x 256B
    #pragma unroll
    for (int i=0;i<2;i++){
      int row = i*16 + w*4 + (lane>>4);
      const char* s = kbase + (size_t)(t*32 + row)*256 + (((lane&15) ^ (row&7))<<4);
      gload16(s, smem + buf*8192 + i*4096 + w*1024);
    }
  };
  auto stV = [&](int buf, int t){            // 4 issues: 128 rows x 128B
    #pragma unroll
    for (int i=0;i<4;i++){
      int d = i*32 + vrb;
      const char* s = vbase + (size_t)d*4096 + (size_t)t*128 + ((vsl ^ (d&7))<<4);
      gload16(s, smem + 16384 + buf*16384 + i*4096 + w*1024);
    }
  };

  stK(0, 0); stV(0, 0);
  if (nt > 1){ stK(1, 1); stV(1, 1); }

  for (int tile=0; tile<nt; ++tile){
    const int cur = tile & 1;
    const int kv0 = tile*32;
    // wait tile's 6 loads; leave tile+1's 6 in flight
    if (tile+1 < nt) asm volatile("s_waitcnt vmcnt(6)" ::: "memory");
    else             asm volatile("s_waitcnt vmcnt(0)" ::: "memory");
    __builtin_amdgcn_s_barrier();

    // ---- S = Q K^T (bf16, D=128): 4 ks-steps, two 2-deep chains ----
    const u16* Kc = (const u16*)(smem + cur*8192);
    f32x4 sa0=z, sa1=z, sb0=z, sb1=z;
    #pragma unroll
    for (int ks=0; ks<2; ks++){
      int so = ((ks*4+lg) ^ (ln&7)) << 3;
      FragU kf0, kf1;
      kf0.q = *reinterpret_cast<const u32x4*>(&Kc[ln*128 + so]);
      kf1.q = *reinterpret_cast<const u32x4*>(&Kc[(16+ln)*128 + so]);
      sa0 = __builtin_amdgcn_mfma_f32_16x16x32_bf16(qf[ks].v, kf0.v, sa0, 0,0,0);
      sa1 = __builtin_amdgcn_mfma_f32_16x16x32_bf16(qf[ks].v, kf1.v, sa1, 0,0,0);
    }
    #pragma unroll
    for (int ks=2; ks<4; ks++){
      int so = ((ks*4+lg) ^ (ln&7)) << 3;
      FragU kf0, kf1;
      kf0.q = *reinterpret_cast<const u32x4*>(&Kc[ln*128 + so]);
      kf1.q = *reinterpret_cast<const u32x4*>(&Kc[(16+ln)*128 + so]);
      sb0 = __builtin_amdgcn_mfma_f32_16x16x32_bf16(qf[ks].v, kf0.v, sb0, 0,0,0);
      sb1 = __builtin_amdgcn_mfma_f32_16x16x32_bf16(qf[ks].v, kf1.v, sb1, 0,0,0);
    }
    f32x4 s[2]; s[0] = sa0 + sb0; s[1] = sa1 + sb1;

    // ---- no-max softmax: p = exp(s), causal mask only on boundary tiles ----
    float pv[2][4];
    if (kv0 + 31 <= cs + q0){          // interior: wave-uniform, no mask
      #pragma unroll
      for (int n=0;n<2;n++){
        #pragma unroll
        for (int r=0;r<4;r++) pv[n][r] = __expf(s[n][r]);
      }
    } else {
      #pragma unroll
      for (int n=0;n<2;n++){
        #pragma unroll
        for (int r=0;r<4;r++){
          bool ok = (kv0 + n*16 + ln) <= (prow0 + r);
          pv[n][r] = ok ? __expf(s[n][r]) : 0.f;
        }
      }
    }
    #pragma unroll
    for (int r=0;r<4;r++) lacc[r] += pv[0][r] + pv[1][r];

    // ---- split-pack P via cvt_pk + perm, store packed u32 to LDS ----
    #pragma unroll
    for (int n=0;n<2;n++){
      #pragma unroll
      for (int rp=0; rp<2; rp++){
        float p0 = pv[n][rp*2], p1 = pv[n][rp*2+1];
        u32 hpk, lpk;
        asm("v_cvt_pk_bf16_f32 %0, %1, %2" : "=v"(hpk) : "v"(p0), "v"(p1));
        float l0 = p0 - u2f(hpk << 16);
        float l1 = p1 - u2f(hpk & 0xffff0000u);
        asm("v_cvt_pk_bf16_f32 %0, %1, %2" : "=v"(lpk) : "v"(l0), "v"(l1));
        u32 w0 = __builtin_amdgcn_perm(lpk, hpk, 0x05040100u);  // h0|l0<<16
        u32 w1 = __builtin_amdgcn_perm(lpk, hpk, 0x07060302u);  // h1|l1<<16
        int row0 = lg*4 + rp*2;
        Pl[w*512 + ((row0*32 + n*16 + ln) ^ ((row0&7)<<2))] = w0;
        int row1 = row0 + 1;
        Pl[w*512 + ((row1*32 + n*16 + ln) ^ ((row1&7)<<2))] = w1;
      }
    }
    FragU pah[2], pal[2];
    #pragma unroll
    for (int ks2=0; ks2<2; ks2++){
      int fi = (ln*32 + ks2*16 + lg*4) ^ ((ln&7)<<2);
      u32x4 pp = *reinterpret_cast<const u32x4*>(&Pl[w*512 + fi]);
      #pragma unroll
      for (int i=0;i<4;i++){
        pah[ks2].q[i] = __builtin_amdgcn_perm(pp[i], pp[i], 0x01000100u); // h,h
        pal[ks2].q[i] = __builtin_amdgcn_perm(pp[i], pp[i], 0x03020302u); // l,l
      }
    }
    // ---- O += (Ph+Pl) x (Vh+Vl) ----
    const u16* Vc = (const u16*)(smem + 16384 + cur*16384);
    #pragma unroll
    for (int nf=0; nf<8; nf++){
      int dr = nf*16 + ln;
      #pragma unroll
      for (int ks2=0; ks2<2; ks2++){
        FragU vf;
        vf.q = *reinterpret_cast<const u32x4*>(&Vc[(dr*64 + ks2*32 + lg*8) ^ ((dr&7)<<3)]);
        O[nf] = __builtin_amdgcn_mfma_f32_16x16x32_bf16(pah[ks2].v, vf.v, O[nf], 0,0,0);
        O[nf] = __builtin_amdgcn_mfma_f32_16x16x32_bf16(pal[ks2].v, vf.v, O[nf], 0,0,0);
      }
    }
    asm volatile("s_waitcnt lgkmcnt(0)" ::: "memory");
    __builtin_amdgcn_s_barrier();
    if (tile+2 < nt){ stK(cur, tile+2); stV(cur, tile+2); }
  }

  // deferred row-sum reduce (once)
  #pragma unroll
  for (int off=1; off<16; off<<=1){
    #pragma unroll
    for (int r=0;r<4;r++) lacc[r] += __shfl_xor(lacc[r], off);
  }
  float il[4];
  #pragma unroll
  for (int r=0;r<4;r++) il[r] = 1.0f / lacc[r];
  u16* op = attnO + (size_t)(b*512 + q0 + lg*4)*4096 + h*128 + ln;
  #pragma unroll
  for (int nf=0; nf<8; nf++){
    #pragma unroll
    for (int r=0;r<4;r++)
      op[(size_t)r*4096 + nf*16] = bfhi(O[nf][r] * il[r]);
  }
}

// ---------------------------------------------------------------------------
extern "C" void kernel_launch(void* const* d_in, const int* in_sizes, int n_in,
                              void* d_out, int out_size, void* d_ws, size_t ws_size,
                              hipStream_t stream) {
  const float* hidden    = (const float*)d_in[0];
  const float* cosT      = (const float*)d_in[1];
  const float* sinT      = (const float*)d_in[2];
  const int*   positions = (const int*)  d_in[3];
  const float* k_cache   = (const float*)d_in[4];
  const float* v_cache   = (const float*)d_in[5];
  const int*   page_tab  = (const int*)  d_in[6];
  const int*   cache_sl  = (const int*)  d_in[7];
  const float* qkv_w     = (const float*)d_in[9];
  const float* o_w       = (const float*)d_in[10];
  const float* qnw       = (const float*)d_in[11];
  const float* knw       = (const float*)d_in[12];
  float* out = (float*)d_out;

  u32* ws      = (u32*)d_ws;
  float* qkv   = (float*)ws;                     // 12582912 f32
  u16* k_all   = (u16*)(ws + 12582912);          // 4194304 u16 (2097152 u32)
  u32* v_allT  = ws + 12582912 + 2097152;        // 4194304 u32 (packed)
  u16* attnPk  = (u16*)(v_allT + 4194304);       // 8388608 u16
  u16* hidPk   = attnPk + 8388608;               // 8388608 u16
  u16* qkvwPk  = hidPk  + 8388608;               // 25165824 u16
  u16* owPk    = qkvwPk + 25165824;              // 16777216 u16
  (void)in_sizes; (void)n_in; (void)out_size; (void)ws_size;

  (void)hipFuncSetAttribute(reinterpret_cast<const void*>(gemm_pkA2),
                            hipFuncAttributeMaxDynamicSharedMemorySize, 81920);
  (void)hipFuncSetAttribute(reinterpret_cast<const void*>(gemm_pkB2),
                            hipFuncAttributeMaxDynamicSharedMemorySize, 65536);
  (void)hipFuncSetAttribute(reinterpret_cast<const void*>(attn_fused5),
                            hipFuncAttributeMaxDynamicSharedMemorySize, 57344);

  hipLaunchKernelGGL(bf16_pack3, dim3(2048), dim3(256), 0, stream,
                     hidden, hidPk, 2097152,
                     qkv_w, qkvwPk, 6291456,
                     o_w, owPk, 4194304);
  hipLaunchKernelGGL(copy_cache, dim3(1024), dim3(256), 0, stream,
                     k_cache, v_cache, page_tab, k_all, v_allT);
  hipLaunchKernelGGL(gemm_pkA2, dim3(512), dim3(256), 81920, stream,
                     hidPk, qkvwPk, qkv, 2048, 6144, 4096);
  hipLaunchKernelGGL(norm_rope_scatter, dim3(2048), dim3(256), 0, stream,
                     qkv, cosT, sinT, positions, cache_sl, qnw, knw, k_all, v_allT);
  hipLaunchKernelGGL(attn_fused5, dim3(1024), dim3(256), 57344, stream,
                     qkv, k_all, v_allT, cache_sl, attnPk);
  hipLaunchKernelGGL(gemm_pkB2, dim3(512), dim3(256), 65536, stream,
                     attnPk, owPk, out, 2048, 4096, 4096);
}

// Round 12
// 310.408 us; speedup vs baseline: 2.6064x; 1.1773x over previous
//
#include <hip/hip_runtime.h>

typedef unsigned int   u32;
typedef unsigned short u16;

typedef float  f32x4  __attribute__((ext_vector_type(4)));
typedef u32    u32x4  __attribute__((ext_vector_type(4)));
typedef u16    u16x4  __attribute__((ext_vector_type(4)));
typedef __bf16 bf16x8 __attribute__((ext_vector_type(8)));

union FragU { u16 us[8]; u32x4 q; bf16x8 v; };

__device__ __forceinline__ u32 f2u(float x){ union{float f;u32 u;}c; c.f=x; return c.u; }
__device__ __forceinline__ float u2f(u32 u){ union{float f;u32 u;}c; c.u=u; return c.f; }
__device__ __forceinline__ u16 bfhi(float x){ u32 u=f2u(x); return (u16)((u + 0x7fffu + ((u>>16)&1u))>>16); }
__device__ __forceinline__ float bff(u16 h){ return u2f(((u32)h)<<16); }

__device__ __forceinline__ void gload16(const void* g, void* l){
  __builtin_amdgcn_global_load_lds(
      (const __attribute__((address_space(1))) unsigned int*)g,
      (__attribute__((address_space(3))) unsigned int*)l, 16, 0, 0);
}

// ---------------------------------------------------------------------------
// Fused elementwise fp32 -> bf16 over three buffers (4 elems per index).
// ---------------------------------------------------------------------------
__global__ __launch_bounds__(256)
void bf16_pack3(const float* __restrict__ s0, u16* __restrict__ d0, int n0,
                const float* __restrict__ s1, u16* __restrict__ d1, int n1,
                const float* __restrict__ s2, u16* __restrict__ d2, int n2)
{
  const int total = n0 + n1 + n2;
  for (int i = blockIdx.x*256 + threadIdx.x; i < total; i += gridDim.x*256){
    const float* s; u16* d; int j = i;
    if (j < n0)            { s = s0; d = d0; }
    else if (j < n0 + n1)  { s = s1; d = d1; j -= n0; }
    else                   { s = s2; d = d2; j -= n0 + n1; }
    float4 v = reinterpret_cast<const float4*>(s)[j];
    reinterpret_cast<u16x4*>(d)[j] =
      (u16x4){ bfhi(v.x), bfhi(v.y), bfhi(v.z), bfhi(v.w) };
  }
}

// ---------------------------------------------------------------------------
// 128x192-tile GEMM on bf16 (grid 512 = 2 blocks/CU).
// 4 waves (2Mx2N), wave tile 64x96, BK=64 bf16 (=128B/row), dbuf 80KB LDS,
// 2 fat phases/K-tile, counted vmcnt(6), both-sides swizzle, setprio.
// ---------------------------------------------------------------------------
__global__ __launch_bounds__(256, 2)
void gemm_pkA2(const u16* __restrict__ A, const u16* __restrict__ B,
               float* __restrict__ C, int M, int N, int K)  // K = bf16 per row
{
  extern __shared__ char smem[];   // 81920 B: [buf2][ A 16KB | B 24KB ]
  const int tid  = threadIdx.x;
  const int lane = tid & 63;
  const int w    = tid >> 6;       // 0..3
  const int wm = w >> 1, wn = w & 1;
  const int ln = lane & 15, lg = lane >> 4;

  const int nbm = M >> 7;          // 128-row tiles
  const int nbn = N / 192;
  const int nwg = nbm * nbn;
  const int swz = (blockIdx.x & 7) * (nwg >> 3) + (blockIdx.x >> 3);
  const int bm = swz % nbm, bn = swz / nbm;

  const size_t rb = (size_t)K * 2;           // row bytes
  const int lrow  = lane >> 3;               // 0..7
  const int lslot = (lane & 7) ^ (lrow & 7); // pre-swizzled source slot
  const char* As0 = (const char*)A + (size_t)(bm*128 + w*8 + lrow)*rb + lslot*16;
  const char* Bs0 = (const char*)B + (size_t)(bn*192 + w*8 + lrow)*rb + lslot*16;

  auto stA = [&](int buf, int t) {           // 4 issues: 128 rows
    const char* s = As0 + ((size_t)t << 7);
    char* d = smem + buf*40960 + w*1024;
    gload16(s,           d);
    gload16(s +  32*rb,  d + 4096);
    gload16(s +  64*rb,  d + 8192);
    gload16(s +  96*rb,  d + 12288);
  };
  auto stB = [&](int buf, int t) {           // 6 issues: 192 rows
    const char* s = Bs0 + ((size_t)t << 7);
    char* d = smem + buf*40960 + 16384 + w*1024;
    gload16(s,           d);
    gload16(s +  32*rb,  d + 4096);
    gload16(s +  64*rb,  d + 8192);
    gload16(s +  96*rb,  d + 12288);
    gload16(s + 128*rb,  d + 16384);
    gload16(s + 160*rb,  d + 20480);
  };

  f32x4 z = {0.f,0.f,0.f,0.f};
  f32x4 acc[4][6];
  #pragma unroll
  for (int i=0;i<4;i++){
    #pragma unroll
    for (int j=0;j<6;j++) acc[i][j] = z;
  }

  const int nt = K >> 6;           // K-tiles of 64 bf16
  stA(0, 0); stB(0, 0);            // 10 loads
  if (nt > 1) { stB(1, 1);         // +6
    asm volatile("s_waitcnt vmcnt(6)" ::: "memory");   // tile0's 10 complete
  } else {
    asm volatile("s_waitcnt vmcnt(0)" ::: "memory");
  }
  __builtin_amdgcn_s_barrier();
  asm volatile("" ::: "memory");

  const int lx7 = ln & 7;

  for (int t = 0; t < nt; ++t){
    const int cur = t & 1;
    const char* bufc = smem + cur*40960;

    // ---- phase 0: all B frags + A m-frags 0..1; stage A(t+1) ----
    FragU bfr[6][2];
    #pragma unroll
    for (int ni=0; ni<6; ni++){
      const int rofs = 16384 + (wn*96 + ni*16 + ln)*128;
      #pragma unroll
      for (int ks=0; ks<2; ks++)
        bfr[ni][ks].q = *reinterpret_cast<const u32x4*>(bufc + rofs + (((ks*4+lg)^lx7)<<4));
    }
    FragU af[2][2];
    #pragma unroll
    for (int mf=0; mf<2; mf++){
      const int rofs = (wm*64 + mf*16 + ln)*128;
      #pragma unroll
      for (int ks=0; ks<2; ks++)
        af[mf][ks].q = *reinterpret_cast<const u32x4*>(bufc + rofs + (((ks*4+lg)^lx7)<<4));
    }
    if (t+1 < nt) stA(cur^1, t+1);
    __builtin_amdgcn_s_barrier();
    __builtin_amdgcn_s_setprio(1);
    #pragma unroll
    for (int ks=0; ks<2; ks++){
      #pragma unroll
      for (int mf=0; mf<2; mf++){
        #pragma unroll
        for (int ni=0; ni<6; ni++)
          acc[mf][ni] = __builtin_amdgcn_mfma_f32_16x16x32_bf16(af[mf][ks].v, bfr[ni][ks].v, acc[mf][ni], 0,0,0);
      }
    }
    __builtin_amdgcn_s_setprio(0);
    // fence: all waves' B-frag reads done; licenses stB(t+2) into this buffer.
    asm volatile("s_waitcnt lgkmcnt(0)" ::: "memory");
    __builtin_amdgcn_s_barrier();

    // ---- phase 1: A m-frags 2..3; stage B(t+2) -> B[cur] ----
    FragU ag[2][2];
    #pragma unroll
    for (int mf=0; mf<2; mf++){
      const int rofs = (wm*64 + (mf+2)*16 + ln)*128;
      #pragma unroll
      for (int ks=0; ks<2; ks++)
        ag[mf][ks].q = *reinterpret_cast<const u32x4*>(bufc + rofs + (((ks*4+lg)^lx7)<<4));
    }
    if (t+2 < nt) stB(cur, t+2);
    __builtin_amdgcn_s_barrier();
    __builtin_amdgcn_s_setprio(1);
    #pragma unroll
    for (int ks=0; ks<2; ks++){
      #pragma unroll
      for (int mf=0; mf<2; mf++){
        #pragma unroll
        for (int ni=0; ni<6; ni++)
          acc[mf+2][ni] = __builtin_amdgcn_mfma_f32_16x16x32_bf16(ag[mf][ks].v, bfr[ni][ks].v, acc[mf+2][ni], 0,0,0);
      }
    }
    __builtin_amdgcn_s_setprio(0);
    // ---- iteration boundary: counted wait (never 0 mid-loop) ----
    if (t+1 < nt){
      if (t+2 < nt) asm volatile("s_waitcnt vmcnt(6)" ::: "memory");
      else          asm volatile("s_waitcnt vmcnt(0)" ::: "memory");
    }
    __builtin_amdgcn_s_barrier();
    asm volatile("" ::: "memory");
  }

  #pragma unroll
  for (int mi=0; mi<4; mi++){
    #pragma unroll
    for (int ni=0; ni<6; ni++){
      const int row0 = bm*128 + wm*64 + mi*16 + lg*4;
      const int col  = bn*192 + wn*96 + ni*16 + ln;
      #pragma unroll
      for (int r=0; r<4; r++)
        C[(size_t)(row0+r)*N + col] = acc[mi][ni][r];
    }
  }
}

// ---------------------------------------------------------------------------
// 128x128-tile bf16 GEMM (grid 512 = 2 blocks/CU for M=2048,N=4096).
// 4 waves (2Mx2N), wave tile 64x64, dbuf 64KB LDS, counted vmcnt(4).
// ---------------------------------------------------------------------------
__global__ __launch_bounds__(256, 2)
void gemm_pkB2(const u16* __restrict__ A, const u16* __restrict__ B,
               float* __restrict__ C, int M, int N, int K)  // K = bf16 per row
{
  extern __shared__ char smem[];   // 65536 B: [buf2][ A 16KB | B 16KB ]
  const int tid  = threadIdx.x;
  const int lane = tid & 63;
  const int w    = tid >> 6;       // 0..3
  const int wm = w >> 1, wn = w & 1;
  const int ln = lane & 15, lg = lane >> 4;

  const int nbm = M >> 7, nbn = N >> 7;
  const int nwg = nbm * nbn;
  const int swz = (blockIdx.x & 7) * (nwg >> 3) + (blockIdx.x >> 3);
  const int bm = swz % nbm, bn = swz / nbm;

  const size_t rb = (size_t)K * 2;           // row bytes
  const int lrow  = lane >> 3;               // 0..7
  const int lslot = (lane & 7) ^ (lrow & 7); // pre-swizzled source slot
  const char* As0 = (const char*)A + (size_t)(bm*128 + w*8 + lrow)*rb + lslot*16;
  const char* Bs0 = (const char*)B + (size_t)(bn*128 + w*8 + lrow)*rb + lslot*16;

  auto stA = [&](int buf, int t) {           // 4 issues: 128 rows
    const char* s = As0 + ((size_t)t << 7);
    char* d = smem + buf*32768 + w*1024;
    gload16(s,           d);
    gload16(s +  32*rb,  d + 4096);
    gload16(s +  64*rb,  d + 8192);
    gload16(s +  96*rb,  d + 12288);
  };
  auto stB = [&](int buf, int t) {           // 4 issues: 128 rows
    const char* s = Bs0 + ((size_t)t << 7);
    char* d = smem + buf*32768 + 16384 + w*1024;
    gload16(s,           d);
    gload16(s +  32*rb,  d + 4096);
    gload16(s +  64*rb,  d + 8192);
    gload16(s +  96*rb,  d + 12288);
  };

  f32x4 z = {0.f,0.f,0.f,0.f};
  f32x4 acc[4][4];
  #pragma unroll
  for (int i=0;i<4;i++){
    #pragma unroll
    for (int j=0;j<4;j++) acc[i][j] = z;
  }

  const int nt = K >> 6;           // K-tiles of 64 bf16
  stA(0, 0); stB(0, 0);            // 8 loads
  if (nt > 1) { stB(1, 1);         // +4
    asm volatile("s_waitcnt vmcnt(4)" ::: "memory");   // tile0's 8 complete
  } else {
    asm volatile("s_waitcnt vmcnt(0)" ::: "memory");
  }
  __builtin_amdgcn_s_barrier();
  asm volatile("" ::: "memory");

  const int lx7 = ln & 7;

  for (int t = 0; t < nt; ++t){
    const int cur = t & 1;
    const char* bufc = smem + cur*32768;

    // ---- phase 0: all B frags + A m-frags 0..1; stage A(t+1) ----
    FragU bfr[4][2];
    #pragma unroll
    for (int ni=0; ni<4; ni++){
      const int rofs = 16384 + (wn*64 + ni*16 + ln)*128;
      #pragma unroll
      for (int ks=0; ks<2; ks++)
        bfr[ni][ks].q = *reinterpret_cast<const u32x4*>(bufc + rofs + (((ks*4+lg)^lx7)<<4));
    }
    FragU af[2][2];
    #pragma unroll
    for (int mf=0; mf<2; mf++){
      const int rofs = (wm*64 + mf*16 + ln)*128;
      #pragma unroll
      for (int ks=0; ks<2; ks++)
        af[mf][ks].q = *reinterpret_cast<const u32x4*>(bufc + rofs + (((ks*4+lg)^lx7)<<4));
    }
    if (t+1 < nt) stA(cur^1, t+1);
    __builtin_amdgcn_s_barrier();
    __builtin_amdgcn_s_setprio(1);
    #pragma unroll
    for (int ks=0; ks<2; ks++){
      #pragma unroll
      for (int mf=0; mf<2; mf++){
        #pragma unroll
        for (int ni=0; ni<4; ni++)
          acc[mf][ni] = __builtin_amdgcn_mfma_f32_16x16x32_bf16(af[mf][ks].v, bfr[ni][ks].v, acc[mf][ni], 0,0,0);
      }
    }
    __builtin_amdgcn_s_setprio(0);
    asm volatile("s_waitcnt lgkmcnt(0)" ::: "memory");
    __builtin_amdgcn_s_barrier();

    // ---- phase 1: A m-frags 2..3; stage B(t+2) -> B[cur] ----
    FragU ag[2][2];
    #pragma unroll
    for (int mf=0; mf<2; mf++){
      const int rofs = (wm*64 + (mf+2)*16 + ln)*128;
      #pragma unroll
      for (int ks=0; ks<2; ks++)
        ag[mf][ks].q = *reinterpret_cast<const u32x4*>(bufc + rofs + (((ks*4+lg)^lx7)<<4));
    }
    if (t+2 < nt) stB(cur, t+2);
    __builtin_amdgcn_s_barrier();
    __builtin_amdgcn_s_setprio(1);
    #pragma unroll
    for (int ks=0; ks<2; ks++){
      #pragma unroll
      for (int mf=0; mf<2; mf++){
        #pragma unroll
        for (int ni=0; ni<4; ni++)
          acc[mf+2][ni] = __builtin_amdgcn_mfma_f32_16x16x32_bf16(ag[mf][ks].v, bfr[ni][ks].v, acc[mf+2][ni], 0,0,0);
      }
    }
    __builtin_amdgcn_s_setprio(0);
    if (t+1 < nt){
      if (t+2 < nt) asm volatile("s_waitcnt vmcnt(4)" ::: "memory");
      else          asm volatile("s_waitcnt vmcnt(0)" ::: "memory");
    }
    __builtin_amdgcn_s_barrier();
    asm volatile("" ::: "memory");
  }

  #pragma unroll
  for (int mi=0; mi<4; mi++){
    #pragma unroll
    for (int ni=0; ni<4; ni++){
      const int row0 = bm*128 + wm*64 + mi*16 + lg*4;
      const int col  = bn*128 + wn*64 + ni*16 + ln;
      #pragma unroll
      for (int r=0; r<4; r++)
        C[(size_t)(row0+r)*N + col] = acc[mi][ni][r];
    }
  }
}

// ---------------------------------------------------------------------------
// Gather old paged cache into contiguous ws buffers.
// k_all : bf16 [B][HKV][1024][128]   v_allT : bf16 [B][HKV][128][1024]
// ---------------------------------------------------------------------------
__global__ __launch_bounds__(256)
void copy_cache(const float* __restrict__ k_cache, const float* __restrict__ v_cache,
                const int* __restrict__ page_table,
                u16* __restrict__ k_all, u16* __restrict__ v_allT)
{
  __shared__ float tb[32][129];
  const int id = blockIdx.x;
  const int jt = id & 31, h = (id>>5)&7, b = id>>8;
  const int tid = threadIdx.x;
  const int j0 = jt*32;
  {
    int r = tid>>3, c = tid&7;
    int j = j0 + r;
    int page = page_table[b*64 + (j>>4)];
    int slot = j & 15;
    const float* ks = k_cache + (size_t)((page*16 + slot)*8 + h)*128;
    const float* vs = v_cache + (size_t)((page*16 + slot)*8 + h)*128;
    u16* kd = k_all + ((size_t)(b*8+h)*1024 + j)*128;
    #pragma unroll
    for (int i=0;i<4;i++){
      int d0 = (c + 8*i)*4;
      float4 k4 = *reinterpret_cast<const float4*>(ks + d0);
      *reinterpret_cast<u16x4*>(kd + d0) =
        (u16x4){ bfhi(k4.x), bfhi(k4.y), bfhi(k4.z), bfhi(k4.w) };
      float4 v4 = *reinterpret_cast<const float4*>(vs + d0);
      tb[r][d0+0]=v4.x; tb[r][d0+1]=v4.y; tb[r][d0+2]=v4.z; tb[r][d0+3]=v4.w;
    }
  }
  __syncthreads();
  {
    int dout = tid>>1, jh = tid&1;
    u16* vd = v_allT + ((size_t)(b*8+h)*128 + dout)*1024 + j0 + jh*16;
    #pragma unroll
    for (int i=0;i<4;i++){
      u16x4 o = { bfhi(tb[jh*16 + i*4 + 0][dout]),
                  bfhi(tb[jh*16 + i*4 + 1][dout]),
                  bfhi(tb[jh*16 + i*4 + 2][dout]),
                  bfhi(tb[jh*16 + i*4 + 3][dout]) };
      *reinterpret_cast<u16x4*>(vd + i*4) = o;
    }
  }
}

// ---------------------------------------------------------------------------
// Per-head RMSNorm + partial RoPE + scatter new K/V (both bf16).
// ---------------------------------------------------------------------------
__global__ __launch_bounds__(256)
void norm_rope_scatter(float* __restrict__ qkv, const float* __restrict__ cosT,
                       const float* __restrict__ sinT, const int* __restrict__ positions,
                       const int* __restrict__ cache_seqlens,
                       const float* __restrict__ qw, const float* __restrict__ kw,
                       u16* __restrict__ k_all, u16* __restrict__ v_allT)
{
  const int t = blockIdx.x;
  const int lane = threadIdx.x & 63;
  const int w = threadIdx.x >> 6;
  const int b = t >> 9;        // QL = 512
  const int q = t & 511;
  const int pos  = positions[t];
  const int cpos = cache_seqlens[b] + q;
  for (int it=0; it<12; ++it){
    int h = it*4 + w;          // 0..47
    float* xp = qkv + (size_t)t*6144 + h*128 + 2*lane;
    float2 x = *reinterpret_cast<const float2*>(xp);
    if (h < 40){               // q + k heads get RMSNorm + RoPE
      float ss = x.x*x.x + x.y*x.y;
      #pragma unroll
      for (int mk=1; mk<64; mk<<=1) ss += __shfl_xor(ss, mk);
      float var = ss*(1.0f/128.0f) + 1e-6f;
      float rq = rsqrtf(var);
      rq = rq*(1.5f - 0.5f*var*rq*rq);   // Newton refine
      const float* wt = (h<32) ? qw : kw;
      x.x *= rq*wt[2*lane]; x.y *= rq*wt[2*lane+1];
      float px = __shfl_xor(x.x, 16);
      float py = __shfl_xor(x.y, 16);
      if (lane < 32){
        int ci = pos*32 + 2*(lane&15);
        float2 cc = *reinterpret_cast<const float2*>(cosT + ci);
        float2 sc = *reinterpret_cast<const float2*>(sinT + ci);
        if (lane < 16){ x.x = x.x*cc.x - px*sc.x; x.y = x.y*cc.y - py*sc.y; }
        else          { x.x = x.x*cc.x + px*sc.x; x.y = x.y*cc.y + py*sc.y; }
      }
    }
    if (h < 32){
      *reinterpret_cast<float2*>(xp) = x;   // q back in place (fp32)
    } else if (h < 40){
      u16* kp = k_all + ((size_t)(b*8 + (h-32))*1024 + cpos)*128 + 2*lane;
      kp[0] = bfhi(x.x); kp[1] = bfhi(x.y);
    } else {
      u16* vp = v_allT + ((size_t)(b*8 + (h-40))*128 + 2*lane)*1024 + cpos;
      vp[0]    = bfhi(x.x);
      vp[1024] = bfhi(x.y);
    }
  }
}

// ---------------------------------------------------------------------------
// Fused GQA causal attention v6: all-bf16 (K, V, P), 16 MFMA/tile (8 QK + 8 PV),
// async dbuf staging via global_load_lds (4 issues/tile, counted vmcnt(4)),
// chunk-swizzled V/P LDS, no-max softmax, deferred l-reduce, bf16 output.
// LDS 36KB -> 4 blocks/CU.
// ---------------------------------------------------------------------------
__global__ __launch_bounds__(256)
void attn_fused6(const float* __restrict__ qkv, const u16* __restrict__ k_all,
                 const u16* __restrict__ v_allT, const int* __restrict__ cache_seqlens,
                 u16* __restrict__ attnO)
{
  extern __shared__ char smem[];          // 36KB: K dbuf 16K | V dbuf 16K | P 4K
  const int tid = threadIdx.x, lane = tid&63, w = tid>>6;
  const int ln = lane&15, lg = lane>>4;
  const int id = blockIdx.x;
  const int qt = id & 7, g = (id>>3)&3, kvh = (id>>5)&7, b = id>>8;
  const int cs = cache_seqlens[b];
  const int h  = kvh*4 + g;
  const int q0 = qt*64 + w*16;
  const float SCALE = 0.08838834764831845f;  // 1/sqrt(128)
  f32x4 z = {0.f,0.f,0.f,0.f};

  FragU qf[4];
  {
    const float* qp = qkv + (size_t)(b*512 + q0 + ln)*6144 + h*128;
    #pragma unroll
    for (int ks=0; ks<4; ks++){
      int d0 = ks*32 + lg*8;
      float4 a = *reinterpret_cast<const float4*>(qp + d0);
      float4 c = *reinterpret_cast<const float4*>(qp + d0 + 4);
      qf[ks].q = (u32x4){
        (u32)bfhi(a.x*SCALE) | ((u32)bfhi(a.y*SCALE)<<16),
        (u32)bfhi(a.z*SCALE) | ((u32)bfhi(a.w*SCALE)<<16),
        (u32)bfhi(c.x*SCALE) | ((u32)bfhi(c.y*SCALE)<<16),
        (u32)bfhi(c.z*SCALE) | ((u32)bfhi(c.w*SCALE)<<16) };
    }
  }
  f32x4 O[8];
  #pragma unroll
  for (int i=0;i<8;i++) O[i] = z;
  float lacc[4] = {0.f,0.f,0.f,0.f};
  const int prow0 = cs + q0 + lg*4;
  const int nt = (cs + qt*64 + 64 + 31) >> 5;
  const char* kbase = (const char*)(k_all  + (size_t)(b*8+kvh)*1024*128);
  const char* vbase = (const char*)(v_allT + (size_t)(b*8+kvh)*128*1024);

  auto stK = [&](int buf, int t){            // 2 issues: 32 rows x 256B
    #pragma unroll
    for (int i=0;i<2;i++){
      int row = i*16 + w*4 + (lane>>4);
      const char* s = kbase + (size_t)(t*32 + row)*256 + (((lane&15) ^ (row&7))<<4);
      gload16(s, smem + buf*8192 + i*4096 + w*1024);
    }
  };
  auto stV = [&](int buf, int t){            // 2 issues: 128 d-rows x 64B
    #pragma unroll
    for (int i=0;i<2;i++){
      int row = i*64 + w*16 + (lane>>2);
      int c   = lane & 3;
      const char* s = vbase + (size_t)row*2048 + (size_t)t*64 + ((c ^ ((row>>1)&3))<<4);
      gload16(s, smem + 16384 + buf*8192 + i*4096 + w*1024);
    }
  };

  stK(0, 0); stV(0, 0);
  if (nt > 1){ stK(1, 1); stV(1, 1); }

  for (int tile=0; tile<nt; ++tile){
    const int cur = tile & 1;
    const int kv0 = tile*32;
    // wait tile's 4 loads; leave tile+1's 4 in flight
    if (tile+1 < nt) asm volatile("s_waitcnt vmcnt(4)" ::: "memory");
    else             asm volatile("s_waitcnt vmcnt(0)" ::: "memory");
    __builtin_amdgcn_s_barrier();

    // ---- S = Q K^T (bf16, D=128): 4 ks-steps, two 2-deep chains ----
    const u16* Kc = (const u16*)(smem + cur*8192);
    f32x4 sa0=z, sa1=z, sb0=z, sb1=z;
    #pragma unroll
    for (int ks=0; ks<2; ks++){
      int so = ((ks*4+lg) ^ (ln&7)) << 3;
      FragU kf0, kf1;
      kf0.q = *reinterpret_cast<const u32x4*>(&Kc[ln*128 + so]);
      kf1.q = *reinterpret_cast<const u32x4*>(&Kc[(16+ln)*128 + so]);
      sa0 = __builtin_amdgcn_mfma_f32_16x16x32_bf16(qf[ks].v, kf0.v, sa0, 0,0,0);
      sa1 = __builtin_amdgcn_mfma_f32_16x16x32_bf16(qf[ks].v, kf1.v, sa1, 0,0,0);
    }
    #pragma unroll
    for (int ks=2; ks<4; ks++){
      int so = ((ks*4+lg) ^ (ln&7)) << 3;
      FragU kf0, kf1;
      kf0.q = *reinterpret_cast<const u32x4*>(&Kc[ln*128 + so]);
      kf1.q = *reinterpret_cast<const u32x4*>(&Kc[(16+ln)*128 + so]);
      sb0 = __builtin_amdgcn_mfma_f32_16x16x32_bf16(qf[ks].v, kf0.v, sb0, 0,0,0);
      sb1 = __builtin_amdgcn_mfma_f32_16x16x32_bf16(qf[ks].v, kf1.v, sb1, 0,0,0);
    }
    f32x4 s[2]; s[0] = sa0 + sb0; s[1] = sa1 + sb1;

    // ---- no-max softmax: p = exp(s), causal mask only on boundary tiles ----
    float pv[2][4];
    if (kv0 + 31 <= cs + q0){          // interior: wave-uniform, no mask
      #pragma unroll
      for (int n=0;n<2;n++){
        #pragma unroll
        for (int r=0;r<4;r++) pv[n][r] = __expf(s[n][r]);
      }
    } else {
      #pragma unroll
      for (int n=0;n<2;n++){
        #pragma unroll
        for (int r=0;r<4;r++){
          bool ok = (kv0 + n*16 + ln) <= (prow0 + r);
          pv[n][r] = ok ? __expf(s[n][r]) : 0.f;
        }
      }
    }
    #pragma unroll
    for (int r=0;r<4;r++) lacc[r] += pv[0][r] + pv[1][r];

    // ---- P -> LDS as plain bf16 (chunk-swizzled [16 q][32 kv], 64B rows) ----
    #pragma unroll
    for (int n=0;n<2;n++){
      #pragma unroll
      for (int rp=0; rp<2; rp++){
        float p0 = pv[n][rp*2], p1 = pv[n][rp*2+1];
        u32 hpk;
        asm("v_cvt_pk_bf16_f32 %0, %1, %2" : "=v"(hpk) : "v"(p0), "v"(p1));
        int col  = n*16 + ln;
        int row0 = lg*4 + rp*2;        // even; row0+1 shares the same swizzle
        int b0 = w*1024 + row0*64 + ((((col>>3) ^ ((row0>>1)&3)))<<4) + (col&7)*2;
        *(u16*)(smem + 32768 + b0)      = (u16)hpk;
        *(u16*)(smem + 32768 + b0 + 64) = (u16)(hpk >> 16);
      }
    }
    FragU pa;
    pa.q = *reinterpret_cast<const u32x4*>(
        smem + 32768 + w*1024 + ln*64 + ((lg ^ ((ln>>1)&3))<<4));

    // ---- O += P x V (8 MFMAs, K=32 covers the whole tile) ----
    const char* Vb = smem + 16384 + cur*8192;
    #pragma unroll
    for (int nf=0; nf<8; nf++){
      int dr = nf*16 + ln;
      FragU vf;
      vf.q = *reinterpret_cast<const u32x4*>(Vb + dr*64 + ((lg ^ ((dr>>1)&3))<<4));
      O[nf] = __builtin_amdgcn_mfma_f32_16x16x32_bf16(pa.v, vf.v, O[nf], 0,0,0);
    }
    asm volatile("s_waitcnt lgkmcnt(0)" ::: "memory");
    __builtin_amdgcn_s_barrier();
    if (tile+2 < nt){ stK(cur, tile+2); stV(cur, tile+2); }
  }

  // deferred row-sum reduce (once)
  #pragma unroll
  for (int off=1; off<16; off<<=1){
    #pragma unroll
    for (int r=0;r<4;r++) lacc[r] += __shfl_xor(lacc[r], off);
  }
  float il[4];
  #pragma unroll
  for (int r=0;r<4;r++) il[r] = 1.0f / lacc[r];
  u16* op = attnO + (size_t)(b*512 + q0 + lg*4)*4096 + h*128 + ln;
  #pragma unroll
  for (int nf=0; nf<8; nf++){
    #pragma unroll
    for (int r=0;r<4;r++)
      op[(size_t)r*4096 + nf*16] = bfhi(O[nf][r] * il[r]);
  }
}

// ---------------------------------------------------------------------------
extern "C" void kernel_launch(void* const* d_in, const int* in_sizes, int n_in,
                              void* d_out, int out_size, void* d_ws, size_t ws_size,
                              hipStream_t stream) {
  const float* hidden    = (const float*)d_in[0];
  const float* cosT      = (const float*)d_in[1];
  const float* sinT      = (const float*)d_in[2];
  const int*   positions = (const int*)  d_in[3];
  const float* k_cache   = (const float*)d_in[4];
  const float* v_cache   = (const float*)d_in[5];
  const int*   page_tab  = (const int*)  d_in[6];
  const int*   cache_sl  = (const int*)  d_in[7];
  const float* qkv_w     = (const float*)d_in[9];
  const float* o_w       = (const float*)d_in[10];
  const float* qnw       = (const float*)d_in[11];
  const float* knw       = (const float*)d_in[12];
  float* out = (float*)d_out;

  float* qkv   = (float*)d_ws;                   // 12582912 f32
  u16* k_all   = (u16*)(qkv + 12582912);         // 4194304 u16
  u16* v_allT  = k_all  + 4194304;               // 4194304 u16
  u16* attnPk  = v_allT + 4194304;               // 8388608 u16
  u16* hidPk   = attnPk + 8388608;               // 8388608 u16
  u16* qkvwPk  = hidPk  + 8388608;               // 25165824 u16
  u16* owPk    = qkvwPk + 25165824;              // 16777216 u16
  (void)in_sizes; (void)n_in; (void)out_size; (void)ws_size;

  (void)hipFuncSetAttribute(reinterpret_cast<const void*>(gemm_pkA2),
                            hipFuncAttributeMaxDynamicSharedMemorySize, 81920);
  (void)hipFuncSetAttribute(reinterpret_cast<const void*>(gemm_pkB2),
                            hipFuncAttributeMaxDynamicSharedMemorySize, 65536);
  (void)hipFuncSetAttribute(reinterpret_cast<const void*>(attn_fused6),
                            hipFuncAttributeMaxDynamicSharedMemorySize, 36864);

  hipLaunchKernelGGL(bf16_pack3, dim3(2048), dim3(256), 0, stream,
                     hidden, hidPk, 2097152,
                     qkv_w, qkvwPk, 6291456,
                     o_w, owPk, 4194304);
  hipLaunchKernelGGL(copy_cache, dim3(1024), dim3(256), 0, stream,
                     k_cache, v_cache, page_tab, k_all, v_allT);
  hipLaunchKernelGGL(gemm_pkA2, dim3(512), dim3(256), 81920, stream,
                     hidPk, qkvwPk, qkv, 2048, 6144, 4096);
  hipLaunchKernelGGL(norm_rope_scatter, dim3(2048), dim3(256), 0, stream,
                     qkv, cosT, sinT, positions, cache_sl, qnw, knw, k_all, v_allT);
  hipLaunchKernelGGL(attn_fused6, dim3(1024), dim3(256), 36864, stream,
                     qkv, k_all, v_allT, cache_sl, attnPk);
  hipLaunchKernelGGL(gemm_pkB2, dim3(512), dim3(256), 65536, stream,
                     attnPk, owPk, out, 2048, 4096, 4096);
}

// Round 13
// 306.152 us; speedup vs baseline: 2.6427x; 1.0139x over previous
//
#include <hip/hip_runtime.h>

typedef unsigned int   u32;
typedef unsigned short u16;

typedef float  f32x4  __attribute__((ext_vector_type(4)));
typedef u32    u32x4  __attribute__((ext_vector_type(4)));
typedef u16    u16x4  __attribute__((ext_vector_type(4)));
typedef __bf16 bf16x8 __attribute__((ext_vector_type(8)));

union FragU { u16 us[8]; u32x4 q; bf16x8 v; };

__device__ __forceinline__ u32 f2u(float x){ union{float f;u32 u;}c; c.f=x; return c.u; }
__device__ __forceinline__ float u2f(u32 u){ union{float f;u32 u;}c; c.u=u; return c.f; }
__device__ __forceinline__ u16 bfhi(float x){ u32 u=f2u(x); return (u16)((u + 0x7fffu + ((u>>16)&1u))>>16); }
__device__ __forceinline__ float bff(u16 h){ return u2f(((u32)h)<<16); }

__device__ __forceinline__ void gload16(const void* g, void* l){
  __builtin_amdgcn_global_load_lds(
      (const __attribute__((address_space(1))) unsigned int*)g,
      (__attribute__((address_space(3))) unsigned int*)l, 16, 0, 0);
}

// ---------------------------------------------------------------------------
// Fused elementwise fp32 -> bf16 over three buffers (4 elems per index).
// ---------------------------------------------------------------------------
__global__ __launch_bounds__(256)
void bf16_pack3(const float* __restrict__ s0, u16* __restrict__ d0, int n0,
                const float* __restrict__ s1, u16* __restrict__ d1, int n1,
                const float* __restrict__ s2, u16* __restrict__ d2, int n2)
{
  const int total = n0 + n1 + n2;
  for (int i = blockIdx.x*256 + threadIdx.x; i < total; i += gridDim.x*256){
    const float* s; u16* d; int j = i;
    if (j < n0)            { s = s0; d = d0; }
    else if (j < n0 + n1)  { s = s1; d = d1; j -= n0; }
    else                   { s = s2; d = d2; j -= n0 + n1; }
    float4 v = reinterpret_cast<const float4*>(s)[j];
    reinterpret_cast<u16x4*>(d)[j] =
      (u16x4){ bfhi(v.x), bfhi(v.y), bfhi(v.z), bfhi(v.w) };
  }
}

// ---------------------------------------------------------------------------
// 128x192-tile GEMM on bf16 (grid 512 = 2 blocks/CU).
// 4 waves (2Mx2N), wave tile 64x96, BK=64 bf16 (=128B/row), dbuf 80KB LDS,
// 2 fat phases/K-tile, counted vmcnt(6), both-sides swizzle, setprio.
// ---------------------------------------------------------------------------
__global__ __launch_bounds__(256, 2)
void gemm_pkA2(const u16* __restrict__ A, const u16* __restrict__ B,
               float* __restrict__ C, int M, int N, int K)  // K = bf16 per row
{
  extern __shared__ char smem[];   // 81920 B: [buf2][ A 16KB | B 24KB ]
  const int tid  = threadIdx.x;
  const int lane = tid & 63;
  const int w    = tid >> 6;       // 0..3
  const int wm = w >> 1, wn = w & 1;
  const int ln = lane & 15, lg = lane >> 4;

  const int nbm = M >> 7;          // 128-row tiles
  const int nbn = N / 192;
  const int nwg = nbm * nbn;
  const int swz = (blockIdx.x & 7) * (nwg >> 3) + (blockIdx.x >> 3);
  const int bm = swz % nbm, bn = swz / nbm;

  const size_t rb = (size_t)K * 2;           // row bytes
  const int lrow  = lane >> 3;               // 0..7
  const int lslot = (lane & 7) ^ (lrow & 7); // pre-swizzled source slot
  const char* As0 = (const char*)A + (size_t)(bm*128 + w*8 + lrow)*rb + lslot*16;
  const char* Bs0 = (const char*)B + (size_t)(bn*192 + w*8 + lrow)*rb + lslot*16;

  auto stA = [&](int buf, int t) {           // 4 issues: 128 rows
    const char* s = As0 + ((size_t)t << 7);
    char* d = smem + buf*40960 + w*1024;
    gload16(s,           d);
    gload16(s +  32*rb,  d + 4096);
    gload16(s +  64*rb,  d + 8192);
    gload16(s +  96*rb,  d + 12288);
  };
  auto stB = [&](int buf, int t) {           // 6 issues: 192 rows
    const char* s = Bs0 + ((size_t)t << 7);
    char* d = smem + buf*40960 + 16384 + w*1024;
    gload16(s,           d);
    gload16(s +  32*rb,  d + 4096);
    gload16(s +  64*rb,  d + 8192);
    gload16(s +  96*rb,  d + 12288);
    gload16(s + 128*rb,  d + 16384);
    gload16(s + 160*rb,  d + 20480);
  };

  f32x4 z = {0.f,0.f,0.f,0.f};
  f32x4 acc[4][6];
  #pragma unroll
  for (int i=0;i<4;i++){
    #pragma unroll
    for (int j=0;j<6;j++) acc[i][j] = z;
  }

  const int nt = K >> 6;           // K-tiles of 64 bf16
  stA(0, 0); stB(0, 0);            // 10 loads
  if (nt > 1) { stB(1, 1);         // +6
    asm volatile("s_waitcnt vmcnt(6)" ::: "memory");   // tile0's 10 complete
  } else {
    asm volatile("s_waitcnt vmcnt(0)" ::: "memory");
  }
  __builtin_amdgcn_s_barrier();
  asm volatile("" ::: "memory");

  const int lx7 = ln & 7;

  for (int t = 0; t < nt; ++t){
    const int cur = t & 1;
    const char* bufc = smem + cur*40960;

    // ---- phase 0: all B frags + A m-frags 0..1; stage A(t+1) ----
    FragU bfr[6][2];
    #pragma unroll
    for (int ni=0; ni<6; ni++){
      const int rofs = 16384 + (wn*96 + ni*16 + ln)*128;
      #pragma unroll
      for (int ks=0; ks<2; ks++)
        bfr[ni][ks].q = *reinterpret_cast<const u32x4*>(bufc + rofs + (((ks*4+lg)^lx7)<<4));
    }
    FragU af[2][2];
    #pragma unroll
    for (int mf=0; mf<2; mf++){
      const int rofs = (wm*64 + mf*16 + ln)*128;
      #pragma unroll
      for (int ks=0; ks<2; ks++)
        af[mf][ks].q = *reinterpret_cast<const u32x4*>(bufc + rofs + (((ks*4+lg)^lx7)<<4));
    }
    if (t+1 < nt) stA(cur^1, t+1);
    __builtin_amdgcn_s_barrier();
    __builtin_amdgcn_s_setprio(1);
    #pragma unroll
    for (int ks=0; ks<2; ks++){
      #pragma unroll
      for (int mf=0; mf<2; mf++){
        #pragma unroll
        for (int ni=0; ni<6; ni++)
          acc[mf][ni] = __builtin_amdgcn_mfma_f32_16x16x32_bf16(af[mf][ks].v, bfr[ni][ks].v, acc[mf][ni], 0,0,0);
      }
    }
    __builtin_amdgcn_s_setprio(0);
    // fence: all waves' B-frag reads done; licenses stB(t+2) into this buffer.
    asm volatile("s_waitcnt lgkmcnt(0)" ::: "memory");
    __builtin_amdgcn_s_barrier();

    // ---- phase 1: A m-frags 2..3; stage B(t+2) -> B[cur] ----
    FragU ag[2][2];
    #pragma unroll
    for (int mf=0; mf<2; mf++){
      const int rofs = (wm*64 + (mf+2)*16 + ln)*128;
      #pragma unroll
      for (int ks=0; ks<2; ks++)
        ag[mf][ks].q = *reinterpret_cast<const u32x4*>(bufc + rofs + (((ks*4+lg)^lx7)<<4));
    }
    if (t+2 < nt) stB(cur, t+2);
    __builtin_amdgcn_s_barrier();
    __builtin_amdgcn_s_setprio(1);
    #pragma unroll
    for (int ks=0; ks<2; ks++){
      #pragma unroll
      for (int mf=0; mf<2; mf++){
        #pragma unroll
        for (int ni=0; ni<6; ni++)
          acc[mf+2][ni] = __builtin_amdgcn_mfma_f32_16x16x32_bf16(ag[mf][ks].v, bfr[ni][ks].v, acc[mf+2][ni], 0,0,0);
      }
    }
    __builtin_amdgcn_s_setprio(0);
    // ---- iteration boundary: counted wait (never 0 mid-loop) ----
    if (t+1 < nt){
      if (t+2 < nt) asm volatile("s_waitcnt vmcnt(6)" ::: "memory");
      else          asm volatile("s_waitcnt vmcnt(0)" ::: "memory");
    }
    __builtin_amdgcn_s_barrier();
    asm volatile("" ::: "memory");
  }

  #pragma unroll
  for (int mi=0; mi<4; mi++){
    #pragma unroll
    for (int ni=0; ni<6; ni++){
      const int row0 = bm*128 + wm*64 + mi*16 + lg*4;
      const int col  = bn*192 + wn*96 + ni*16 + ln;
      #pragma unroll
      for (int r=0; r<4; r++)
        C[(size_t)(row0+r)*N + col] = acc[mi][ni][r];
    }
  }
}

// ---------------------------------------------------------------------------
// 128x128-tile bf16 GEMM (grid 512 = 2 blocks/CU for M=2048,N=4096).
// 4 waves (2Mx2N), wave tile 64x64, dbuf 64KB LDS, counted vmcnt(4).
// ---------------------------------------------------------------------------
__global__ __launch_bounds__(256, 2)
void gemm_pkB2(const u16* __restrict__ A, const u16* __restrict__ B,
               float* __restrict__ C, int M, int N, int K)  // K = bf16 per row
{
  extern __shared__ char smem[];   // 65536 B: [buf2][ A 16KB | B 16KB ]
  const int tid  = threadIdx.x;
  const int lane = tid & 63;
  const int w    = tid >> 6;       // 0..3
  const int wm = w >> 1, wn = w & 1;
  const int ln = lane & 15, lg = lane >> 4;

  const int nbm = M >> 7, nbn = N >> 7;
  const int nwg = nbm * nbn;
  const int swz = (blockIdx.x & 7) * (nwg >> 3) + (blockIdx.x >> 3);
  const int bm = swz % nbm, bn = swz / nbm;

  const size_t rb = (size_t)K * 2;           // row bytes
  const int lrow  = lane >> 3;               // 0..7
  const int lslot = (lane & 7) ^ (lrow & 7); // pre-swizzled source slot
  const char* As0 = (const char*)A + (size_t)(bm*128 + w*8 + lrow)*rb + lslot*16;
  const char* Bs0 = (const char*)B + (size_t)(bn*128 + w*8 + lrow)*rb + lslot*16;

  auto stA = [&](int buf, int t) {           // 4 issues: 128 rows
    const char* s = As0 + ((size_t)t << 7);
    char* d = smem + buf*32768 + w*1024;
    gload16(s,           d);
    gload16(s +  32*rb,  d + 4096);
    gload16(s +  64*rb,  d + 8192);
    gload16(s +  96*rb,  d + 12288);
  };
  auto stB = [&](int buf, int t) {           // 4 issues: 128 rows
    const char* s = Bs0 + ((size_t)t << 7);
    char* d = smem + buf*32768 + 16384 + w*1024;
    gload16(s,           d);
    gload16(s +  32*rb,  d + 4096);
    gload16(s +  64*rb,  d + 8192);
    gload16(s +  96*rb,  d + 12288);
  };

  f32x4 z = {0.f,0.f,0.f,0.f};
  f32x4 acc[4][4];
  #pragma unroll
  for (int i=0;i<4;i++){
    #pragma unroll
    for (int j=0;j<4;j++) acc[i][j] = z;
  }

  const int nt = K >> 6;           // K-tiles of 64 bf16
  stA(0, 0); stB(0, 0);            // 8 loads
  if (nt > 1) { stB(1, 1);         // +4
    asm volatile("s_waitcnt vmcnt(4)" ::: "memory");   // tile0's 8 complete
  } else {
    asm volatile("s_waitcnt vmcnt(0)" ::: "memory");
  }
  __builtin_amdgcn_s_barrier();
  asm volatile("" ::: "memory");

  const int lx7 = ln & 7;

  for (int t = 0; t < nt; ++t){
    const int cur = t & 1;
    const char* bufc = smem + cur*32768;

    // ---- phase 0: all B frags + A m-frags 0..1; stage A(t+1) ----
    FragU bfr[4][2];
    #pragma unroll
    for (int ni=0; ni<4; ni++){
      const int rofs = 16384 + (wn*64 + ni*16 + ln)*128;
      #pragma unroll
      for (int ks=0; ks<2; ks++)
        bfr[ni][ks].q = *reinterpret_cast<const u32x4*>(bufc + rofs + (((ks*4+lg)^lx7)<<4));
    }
    FragU af[2][2];
    #pragma unroll
    for (int mf=0; mf<2; mf++){
      const int rofs = (wm*64 + mf*16 + ln)*128;
      #pragma unroll
      for (int ks=0; ks<2; ks++)
        af[mf][ks].q = *reinterpret_cast<const u32x4*>(bufc + rofs + (((ks*4+lg)^lx7)<<4));
    }
    if (t+1 < nt) stA(cur^1, t+1);
    __builtin_amdgcn_s_barrier();
    __builtin_amdgcn_s_setprio(1);
    #pragma unroll
    for (int ks=0; ks<2; ks++){
      #pragma unroll
      for (int mf=0; mf<2; mf++){
        #pragma unroll
        for (int ni=0; ni<4; ni++)
          acc[mf][ni] = __builtin_amdgcn_mfma_f32_16x16x32_bf16(af[mf][ks].v, bfr[ni][ks].v, acc[mf][ni], 0,0,0);
      }
    }
    __builtin_amdgcn_s_setprio(0);
    asm volatile("s_waitcnt lgkmcnt(0)" ::: "memory");
    __builtin_amdgcn_s_barrier();

    // ---- phase 1: A m-frags 2..3; stage B(t+2) -> B[cur] ----
    FragU ag[2][2];
    #pragma unroll
    for (int mf=0; mf<2; mf++){
      const int rofs = (wm*64 + (mf+2)*16 + ln)*128;
      #pragma unroll
      for (int ks=0; ks<2; ks++)
        ag[mf][ks].q = *reinterpret_cast<const u32x4*>(bufc + rofs + (((ks*4+lg)^lx7)<<4));
    }
    if (t+2 < nt) stB(cur, t+2);
    __builtin_amdgcn_s_barrier();
    __builtin_amdgcn_s_setprio(1);
    #pragma unroll
    for (int ks=0; ks<2; ks++){
      #pragma unroll
      for (int mf=0; mf<2; mf++){
        #pragma unroll
        for (int ni=0; ni<4; ni++)
          acc[mf+2][ni] = __builtin_amdgcn_mfma_f32_16x16x32_bf16(ag[mf][ks].v, bfr[ni][ks].v, acc[mf+2][ni], 0,0,0);
      }
    }
    __builtin_amdgcn_s_setprio(0);
    if (t+1 < nt){
      if (t+2 < nt) asm volatile("s_waitcnt vmcnt(4)" ::: "memory");
      else          asm volatile("s_waitcnt vmcnt(0)" ::: "memory");
    }
    __builtin_amdgcn_s_barrier();
    asm volatile("" ::: "memory");
  }

  #pragma unroll
  for (int mi=0; mi<4; mi++){
    #pragma unroll
    for (int ni=0; ni<4; ni++){
      const int row0 = bm*128 + wm*64 + mi*16 + lg*4;
      const int col  = bn*128 + wn*64 + ni*16 + ln;
      #pragma unroll
      for (int r=0; r<4; r++)
        C[(size_t)(row0+r)*N + col] = acc[mi][ni][r];
    }
  }
}

// ---------------------------------------------------------------------------
// Gather old paged cache into contiguous ws buffers.
// k_all : bf16 [B][HKV][1024][128]   v_allT : bf16 [B][HKV][128][1024]
// ---------------------------------------------------------------------------
__global__ __launch_bounds__(256)
void copy_cache(const float* __restrict__ k_cache, const float* __restrict__ v_cache,
                const int* __restrict__ page_table,
                u16* __restrict__ k_all, u16* __restrict__ v_allT)
{
  __shared__ float tb[32][129];
  const int id = blockIdx.x;
  const int jt = id & 31, h = (id>>5)&7, b = id>>8;
  const int tid = threadIdx.x;
  const int j0 = jt*32;
  {
    int r = tid>>3, c = tid&7;
    int j = j0 + r;
    int page = page_table[b*64 + (j>>4)];
    int slot = j & 15;
    const float* ks = k_cache + (size_t)((page*16 + slot)*8 + h)*128;
    const float* vs = v_cache + (size_t)((page*16 + slot)*8 + h)*128;
    u16* kd = k_all + ((size_t)(b*8+h)*1024 + j)*128;
    #pragma unroll
    for (int i=0;i<4;i++){
      int d0 = (c + 8*i)*4;
      float4 k4 = *reinterpret_cast<const float4*>(ks + d0);
      *reinterpret_cast<u16x4*>(kd + d0) =
        (u16x4){ bfhi(k4.x), bfhi(k4.y), bfhi(k4.z), bfhi(k4.w) };
      float4 v4 = *reinterpret_cast<const float4*>(vs + d0);
      tb[r][d0+0]=v4.x; tb[r][d0+1]=v4.y; tb[r][d0+2]=v4.z; tb[r][d0+3]=v4.w;
    }
  }
  __syncthreads();
  {
    int dout = tid>>1, jh = tid&1;
    u16* vd = v_allT + ((size_t)(b*8+h)*128 + dout)*1024 + j0 + jh*16;
    #pragma unroll
    for (int i=0;i<4;i++){
      u16x4 o = { bfhi(tb[jh*16 + i*4 + 0][dout]),
                  bfhi(tb[jh*16 + i*4 + 1][dout]),
                  bfhi(tb[jh*16 + i*4 + 2][dout]),
                  bfhi(tb[jh*16 + i*4 + 3][dout]) };
      *reinterpret_cast<u16x4*>(vd + i*4) = o;
    }
  }
}

// ---------------------------------------------------------------------------
// Per-head RMSNorm + partial RoPE + scatter new K/V (both bf16).
// ---------------------------------------------------------------------------
__global__ __launch_bounds__(256)
void norm_rope_scatter(float* __restrict__ qkv, const float* __restrict__ cosT,
                       const float* __restrict__ sinT, const int* __restrict__ positions,
                       const int* __restrict__ cache_seqlens,
                       const float* __restrict__ qw, const float* __restrict__ kw,
                       u16* __restrict__ k_all, u16* __restrict__ v_allT)
{
  const int t = blockIdx.x;
  const int lane = threadIdx.x & 63;
  const int w = threadIdx.x >> 6;
  const int b = t >> 9;        // QL = 512
  const int q = t & 511;
  const int pos  = positions[t];
  const int cpos = cache_seqlens[b] + q;
  for (int it=0; it<12; ++it){
    int h = it*4 + w;          // 0..47
    float* xp = qkv + (size_t)t*6144 + h*128 + 2*lane;
    float2 x = *reinterpret_cast<const float2*>(xp);
    if (h < 40){               // q + k heads get RMSNorm + RoPE
      float ss = x.x*x.x + x.y*x.y;
      #pragma unroll
      for (int mk=1; mk<64; mk<<=1) ss += __shfl_xor(ss, mk);
      float var = ss*(1.0f/128.0f) + 1e-6f;
      float rq = rsqrtf(var);
      rq = rq*(1.5f - 0.5f*var*rq*rq);   // Newton refine
      const float* wt = (h<32) ? qw : kw;
      x.x *= rq*wt[2*lane]; x.y *= rq*wt[2*lane+1];
      float px = __shfl_xor(x.x, 16);
      float py = __shfl_xor(x.y, 16);
      if (lane < 32){
        int ci = pos*32 + 2*(lane&15);
        float2 cc = *reinterpret_cast<const float2*>(cosT + ci);
        float2 sc = *reinterpret_cast<const float2*>(sinT + ci);
        if (lane < 16){ x.x = x.x*cc.x - px*sc.x; x.y = x.y*cc.y - py*sc.y; }
        else          { x.x = x.x*cc.x + px*sc.x; x.y = x.y*cc.y + py*sc.y; }
      }
    }
    if (h < 32){
      *reinterpret_cast<float2*>(xp) = x;   // q back in place (fp32)
    } else if (h < 40){
      u16* kp = k_all + ((size_t)(b*8 + (h-32))*1024 + cpos)*128 + 2*lane;
      kp[0] = bfhi(x.x); kp[1] = bfhi(x.y);
    } else {
      u16* vp = v_allT + ((size_t)(b*8 + (h-40))*128 + 2*lane)*1024 + cpos;
      vp[0]    = bfhi(x.x);
      vp[1024] = bfhi(x.y);
    }
  }
}

// ---------------------------------------------------------------------------
// Fused GQA causal attention v7: QBLK=128 (8 waves x 16 q-rows, 512 thr),
// all-bf16, async dbuf K/V staging (1 gload_lds issue each per tile,
// counted vmcnt(2)), natural dispatch order, no-max softmax, deferred
// l-reduce, bf16 output.  LDS 40KB -> 2 blocks/CU.  Grid 512: halves KV
// re-reads and tile-step count vs QBLK=64.
// ---------------------------------------------------------------------------
__global__ __launch_bounds__(512)
void attn_fused7(const float* __restrict__ qkv, const u16* __restrict__ k_all,
                 const u16* __restrict__ v_allT, const int* __restrict__ cache_seqlens,
                 u16* __restrict__ attnO)
{
  extern __shared__ char smem[];          // 40KB: K dbuf 16K | V dbuf 16K | P 8K
  const int tid = threadIdx.x, lane = tid&63, w = tid>>6;   // w 0..7
  const int ln = lane&15, lg = lane>>4;
  const int id = blockIdx.x;
  const int qt = id & 3, g = (id>>2)&3, kvh = (id>>4)&7, b = id>>7;
  const int cs = cache_seqlens[b];
  const int h  = kvh*4 + g;
  const int q0 = qt*128 + w*16;
  const float SCALE = 0.08838834764831845f;  // 1/sqrt(128)
  f32x4 z = {0.f,0.f,0.f,0.f};

  FragU qf[4];
  {
    const float* qp = qkv + (size_t)(b*512 + q0 + ln)*6144 + h*128;
    #pragma unroll
    for (int ks=0; ks<4; ks++){
      int d0 = ks*32 + lg*8;
      float4 a = *reinterpret_cast<const float4*>(qp + d0);
      float4 c = *reinterpret_cast<const float4*>(qp + d0 + 4);
      qf[ks].q = (u32x4){
        (u32)bfhi(a.x*SCALE) | ((u32)bfhi(a.y*SCALE)<<16),
        (u32)bfhi(a.z*SCALE) | ((u32)bfhi(a.w*SCALE)<<16),
        (u32)bfhi(c.x*SCALE) | ((u32)bfhi(c.y*SCALE)<<16),
        (u32)bfhi(c.z*SCALE) | ((u32)bfhi(c.w*SCALE)<<16) };
    }
  }
  f32x4 O[8];
  #pragma unroll
  for (int i=0;i<8;i++) O[i] = z;
  float lacc[4] = {0.f,0.f,0.f,0.f};
  const int prow0 = cs + q0 + lg*4;
  const int nt = (cs + qt*128 + 128 + 31) >> 5;
  const char* kbase = (const char*)(k_all  + (size_t)(b*8+kvh)*1024*128);
  const char* vbase = (const char*)(v_allT + (size_t)(b*8+kvh)*128*1024);

  auto stK = [&](int buf, int t){            // 1 issue: 32 rows x 256B (8KB)
    int row = w*4 + (lane>>4);
    const char* s = kbase + (size_t)(t*32 + row)*256 + (((lane&15) ^ (row&7))<<4);
    gload16(s, smem + buf*8192 + w*1024);
  };
  auto stV = [&](int buf, int t){            // 1 issue: 128 d-rows x 64B (8KB)
    int row = w*16 + (lane>>2);
    int c   = lane & 3;
    const char* s = vbase + (size_t)row*2048 + (size_t)t*64 + ((c ^ ((row>>1)&3))<<4);
    gload16(s, smem + 16384 + buf*8192 + w*1024);
  };

  stK(0, 0); stV(0, 0);
  if (nt > 1){ stK(1, 1); stV(1, 1); }

  for (int tile=0; tile<nt; ++tile){
    const int cur = tile & 1;
    const int kv0 = tile*32;
    // wait tile's 2 loads; leave tile+1's 2 in flight
    if (tile+1 < nt) asm volatile("s_waitcnt vmcnt(2)" ::: "memory");
    else             asm volatile("s_waitcnt vmcnt(0)" ::: "memory");
    __builtin_amdgcn_s_barrier();

    // ---- S = Q K^T (bf16, D=128): 4 ks-steps, two 2-deep chains ----
    const u16* Kc = (const u16*)(smem + cur*8192);
    f32x4 sa0=z, sa1=z, sb0=z, sb1=z;
    #pragma unroll
    for (int ks=0; ks<2; ks++){
      int so = ((ks*4+lg) ^ (ln&7)) << 3;
      FragU kf0, kf1;
      kf0.q = *reinterpret_cast<const u32x4*>(&Kc[ln*128 + so]);
      kf1.q = *reinterpret_cast<const u32x4*>(&Kc[(16+ln)*128 + so]);
      sa0 = __builtin_amdgcn_mfma_f32_16x16x32_bf16(qf[ks].v, kf0.v, sa0, 0,0,0);
      sa1 = __builtin_amdgcn_mfma_f32_16x16x32_bf16(qf[ks].v, kf1.v, sa1, 0,0,0);
    }
    #pragma unroll
    for (int ks=2; ks<4; ks++){
      int so = ((ks*4+lg) ^ (ln&7)) << 3;
      FragU kf0, kf1;
      kf0.q = *reinterpret_cast<const u32x4*>(&Kc[ln*128 + so]);
      kf1.q = *reinterpret_cast<const u32x4*>(&Kc[(16+ln)*128 + so]);
      sb0 = __builtin_amdgcn_mfma_f32_16x16x32_bf16(qf[ks].v, kf0.v, sb0, 0,0,0);
      sb1 = __builtin_amdgcn_mfma_f32_16x16x32_bf16(qf[ks].v, kf1.v, sb1, 0,0,0);
    }
    f32x4 s[2]; s[0] = sa0 + sb0; s[1] = sa1 + sb1;

    // ---- no-max softmax: p = exp(s), causal mask only on boundary tiles ----
    float pv[2][4];
    if (kv0 + 31 <= cs + q0){          // interior: wave-uniform, no mask
      #pragma unroll
      for (int n=0;n<2;n++){
        #pragma unroll
        for (int r=0;r<4;r++) pv[n][r] = __expf(s[n][r]);
      }
    } else {
      #pragma unroll
      for (int n=0;n<2;n++){
        #pragma unroll
        for (int r=0;r<4;r++){
          bool ok = (kv0 + n*16 + ln) <= (prow0 + r);
          pv[n][r] = ok ? __expf(s[n][r]) : 0.f;
        }
      }
    }
    #pragma unroll
    for (int r=0;r<4;r++) lacc[r] += pv[0][r] + pv[1][r];

    // ---- P -> LDS as plain bf16 (chunk-swizzled [16 q][32 kv], 64B rows) ----
    #pragma unroll
    for (int n=0;n<2;n++){
      #pragma unroll
      for (int rp=0; rp<2; rp++){
        float p0 = pv[n][rp*2], p1 = pv[n][rp*2+1];
        u32 hpk;
        asm("v_cvt_pk_bf16_f32 %0, %1, %2" : "=v"(hpk) : "v"(p0), "v"(p1));
        int col  = n*16 + ln;
        int row0 = lg*4 + rp*2;        // even; row0+1 shares the same swizzle
        int b0 = w*1024 + row0*64 + ((((col>>3) ^ ((row0>>1)&3)))<<4) + (col&7)*2;
        *(u16*)(smem + 32768 + b0)      = (u16)hpk;
        *(u16*)(smem + 32768 + b0 + 64) = (u16)(hpk >> 16);
      }
    }
    FragU pa;
    pa.q = *reinterpret_cast<const u32x4*>(
        smem + 32768 + w*1024 + ln*64 + ((lg ^ ((ln>>1)&3))<<4));

    // ---- O += P x V (8 MFMAs, K=32 covers the whole tile) ----
    const char* Vb = smem + 16384 + cur*8192;
    #pragma unroll
    for (int nf=0; nf<8; nf++){
      int dr = nf*16 + ln;
      FragU vf;
      vf.q = *reinterpret_cast<const u32x4*>(Vb + dr*64 + ((lg ^ ((dr>>1)&3))<<4));
      O[nf] = __builtin_amdgcn_mfma_f32_16x16x32_bf16(pa.v, vf.v, O[nf], 0,0,0);
    }
    asm volatile("s_waitcnt lgkmcnt(0)" ::: "memory");
    __builtin_amdgcn_s_barrier();
    if (tile+2 < nt){ stK(cur, tile+2); stV(cur, tile+2); }
  }

  // deferred row-sum reduce (once)
  #pragma unroll
  for (int off=1; off<16; off<<=1){
    #pragma unroll
    for (int r=0;r<4;r++) lacc[r] += __shfl_xor(lacc[r], off);
  }
  float il[4];
  #pragma unroll
  for (int r=0;r<4;r++) il[r] = 1.0f / lacc[r];
  u16* op = attnO + (size_t)(b*512 + q0 + lg*4)*4096 + h*128 + ln;
  #pragma unroll
  for (int nf=0; nf<8; nf++){
    #pragma unroll
    for (int r=0;r<4;r++)
      op[(size_t)r*4096 + nf*16] = bfhi(O[nf][r] * il[r]);
  }
}

// ---------------------------------------------------------------------------
extern "C" void kernel_launch(void* const* d_in, const int* in_sizes, int n_in,
                              void* d_out, int out_size, void* d_ws, size_t ws_size,
                              hipStream_t stream) {
  const float* hidden    = (const float*)d_in[0];
  const float* cosT      = (const float*)d_in[1];
  const float* sinT      = (const float*)d_in[2];
  const int*   positions = (const int*)  d_in[3];
  const float* k_cache   = (const float*)d_in[4];
  const float* v_cache   = (const float*)d_in[5];
  const int*   page_tab  = (const int*)  d_in[6];
  const int*   cache_sl  = (const int*)  d_in[7];
  const float* qkv_w     = (const float*)d_in[9];
  const float* o_w       = (const float*)d_in[10];
  const float* qnw       = (const float*)d_in[11];
  const float* knw       = (const float*)d_in[12];
  float* out = (float*)d_out;

  float* qkv   = (float*)d_ws;                   // 12582912 f32
  u16* k_all   = (u16*)(qkv + 12582912);         // 4194304 u16
  u16* v_allT  = k_all  + 4194304;               // 4194304 u16
  u16* attnPk  = v_allT + 4194304;               // 8388608 u16
  u16* hidPk   = attnPk + 8388608;               // 8388608 u16
  u16* qkvwPk  = hidPk  + 8388608;               // 25165824 u16
  u16* owPk    = qkvwPk + 25165824;              // 16777216 u16
  (void)in_sizes; (void)n_in; (void)out_size; (void)ws_size;

  (void)hipFuncSetAttribute(reinterpret_cast<const void*>(gemm_pkA2),
                            hipFuncAttributeMaxDynamicSharedMemorySize, 81920);
  (void)hipFuncSetAttribute(reinterpret_cast<const void*>(gemm_pkB2),
                            hipFuncAttributeMaxDynamicSharedMemorySize, 65536);
  (void)hipFuncSetAttribute(reinterpret_cast<const void*>(attn_fused7),
                            hipFuncAttributeMaxDynamicSharedMemorySize, 40960);

  hipLaunchKernelGGL(bf16_pack3, dim3(2048), dim3(256), 0, stream,
                     hidden, hidPk, 2097152,
                     qkv_w, qkvwPk, 6291456,
                     o_w, owPk, 4194304);
  hipLaunchKernelGGL(copy_cache, dim3(1024), dim3(256), 0, stream,
                     k_cache, v_cache, page_tab, k_all, v_allT);
  hipLaunchKernelGGL(gemm_pkA2, dim3(512), dim3(256), 81920, stream,
                     hidPk, qkvwPk, qkv, 2048, 6144, 4096);
  hipLaunchKernelGGL(norm_rope_scatter, dim3(2048), dim3(256), 0, stream,
                     qkv, cosT, sinT, positions, cache_sl, qnw, knw, k_all, v_allT);
  hipLaunchKernelGGL(attn_fused7, dim3(512), dim3(512), 40960, stream,
                     qkv, k_all, v_allT, cache_sl, attnPk);
  hipLaunchKernelGGL(gemm_pkB2, dim3(512), dim3(256), 65536, stream,
                     attnPk, owPk, out, 2048, 4096, 4096);
}

// Round 14
// 301.669 us; speedup vs baseline: 2.6819x; 1.0149x over previous
//
#include <hip/hip_runtime.h>

typedef unsigned int   u32;
typedef unsigned short u16;

typedef float  f32x4  __attribute__((ext_vector_type(4)));
typedef u32    u32x4  __attribute__((ext_vector_type(4)));
typedef u16    u16x4  __attribute__((ext_vector_type(4)));
typedef __bf16 bf16x8 __attribute__((ext_vector_type(8)));

union FragU { u16 us[8]; u32x4 q; bf16x8 v; };

__device__ __forceinline__ u32 f2u(float x){ union{float f;u32 u;}c; c.f=x; return c.u; }
__device__ __forceinline__ float u2f(u32 u){ union{float f;u32 u;}c; c.u=u; return c.f; }
__device__ __forceinline__ u16 bfhi(float x){ u32 u=f2u(x); return (u16)((u + 0x7fffu + ((u>>16)&1u))>>16); }
__device__ __forceinline__ float bff(u16 h){ return u2f(((u32)h)<<16); }

__device__ __forceinline__ void gload16(const void* g, void* l){
  __builtin_amdgcn_global_load_lds(
      (const __attribute__((address_space(1))) unsigned int*)g,
      (__attribute__((address_space(3))) unsigned int*)l, 16, 0, 0);
}

// ---------------------------------------------------------------------------
// Fused prep: fp32->bf16 packing of 3 buffers (blocks 0..2047, grid-stride)
// + paged-cache gather (blocks 2048..3071).
// k_all : bf16 [B][HKV][1024][128]   v_allT : bf16 [B][HKV][128][1024]
// ---------------------------------------------------------------------------
__global__ __launch_bounds__(256)
void prep_all(const float* __restrict__ s0, u16* __restrict__ d0, int n0,
              const float* __restrict__ s1, u16* __restrict__ d1, int n1,
              const float* __restrict__ s2, u16* __restrict__ d2, int n2,
              const float* __restrict__ k_cache, const float* __restrict__ v_cache,
              const int* __restrict__ page_table,
              u16* __restrict__ k_all, u16* __restrict__ v_allT)
{
  const int tid = threadIdx.x;
  if (blockIdx.x < 2048){
    const int total = n0 + n1 + n2;
    for (int i = blockIdx.x*256 + tid; i < total; i += 2048*256){
      const float* s; u16* d; int j = i;
      if (j < n0)            { s = s0; d = d0; }
      else if (j < n0 + n1)  { s = s1; d = d1; j -= n0; }
      else                   { s = s2; d = d2; j -= n0 + n1; }
      float4 v = reinterpret_cast<const float4*>(s)[j];
      reinterpret_cast<u16x4*>(d)[j] =
        (u16x4){ bfhi(v.x), bfhi(v.y), bfhi(v.z), bfhi(v.w) };
    }
    return;
  }
  __shared__ float tb[32][129];
  const int id = blockIdx.x - 2048;
  const int jt = id & 31, h = (id>>5)&7, b = id>>8;
  const int j0 = jt*32;
  {
    int r = tid>>3, c = tid&7;
    int j = j0 + r;
    int page = page_table[b*64 + (j>>4)];
    int slot = j & 15;
    const float* ks = k_cache + (size_t)((page*16 + slot)*8 + h)*128;
    const float* vs = v_cache + (size_t)((page*16 + slot)*8 + h)*128;
    u16* kd = k_all + ((size_t)(b*8+h)*1024 + j)*128;
    #pragma unroll
    for (int i=0;i<4;i++){
      int d0i = (c + 8*i)*4;
      float4 k4 = *reinterpret_cast<const float4*>(ks + d0i);
      *reinterpret_cast<u16x4*>(kd + d0i) =
        (u16x4){ bfhi(k4.x), bfhi(k4.y), bfhi(k4.z), bfhi(k4.w) };
      float4 v4 = *reinterpret_cast<const float4*>(vs + d0i);
      tb[r][d0i+0]=v4.x; tb[r][d0i+1]=v4.y; tb[r][d0i+2]=v4.z; tb[r][d0i+3]=v4.w;
    }
  }
  __syncthreads();
  {
    int dout = tid>>1, jh = tid&1;
    u16* vd = v_allT + ((size_t)(b*8+h)*128 + dout)*1024 + j0 + jh*16;
    #pragma unroll
    for (int i=0;i<4;i++){
      u16x4 o = { bfhi(tb[jh*16 + i*4 + 0][dout]),
                  bfhi(tb[jh*16 + i*4 + 1][dout]),
                  bfhi(tb[jh*16 + i*4 + 2][dout]),
                  bfhi(tb[jh*16 + i*4 + 3][dout]) };
      *reinterpret_cast<u16x4*>(vd + i*4) = o;
    }
  }
}

// ---------------------------------------------------------------------------
// 128x192-tile GEMM on bf16 (grid 512 = 2 blocks/CU).
// 4 waves (2Mx2N), wave tile 64x96, BK=64 bf16 (=128B/row), dbuf 80KB LDS,
// 2 fat phases/K-tile, counted vmcnt(6), both-sides swizzle, setprio.
// ---------------------------------------------------------------------------
__global__ __launch_bounds__(256, 2)
void gemm_pkA2(const u16* __restrict__ A, const u16* __restrict__ B,
               float* __restrict__ C, int M, int N, int K)  // K = bf16 per row
{
  extern __shared__ char smem[];   // 81920 B: [buf2][ A 16KB | B 24KB ]
  const int tid  = threadIdx.x;
  const int lane = tid & 63;
  const int w    = tid >> 6;       // 0..3
  const int wm = w >> 1, wn = w & 1;
  const int ln = lane & 15, lg = lane >> 4;

  const int nbm = M >> 7;          // 128-row tiles
  const int nbn = N / 192;
  const int nwg = nbm * nbn;
  const int swz = (blockIdx.x & 7) * (nwg >> 3) + (blockIdx.x >> 3);
  const int bm = swz % nbm, bn = swz / nbm;

  const size_t rb = (size_t)K * 2;           // row bytes
  const int lrow  = lane >> 3;               // 0..7
  const int lslot = (lane & 7) ^ (lrow & 7); // pre-swizzled source slot
  const char* As0 = (const char*)A + (size_t)(bm*128 + w*8 + lrow)*rb + lslot*16;
  const char* Bs0 = (const char*)B + (size_t)(bn*192 + w*8 + lrow)*rb + lslot*16;

  auto stA = [&](int buf, int t) {           // 4 issues: 128 rows
    const char* s = As0 + ((size_t)t << 7);
    char* d = smem + buf*40960 + w*1024;
    gload16(s,           d);
    gload16(s +  32*rb,  d + 4096);
    gload16(s +  64*rb,  d + 8192);
    gload16(s +  96*rb,  d + 12288);
  };
  auto stB = [&](int buf, int t) {           // 6 issues: 192 rows
    const char* s = Bs0 + ((size_t)t << 7);
    char* d = smem + buf*40960 + 16384 + w*1024;
    gload16(s,           d);
    gload16(s +  32*rb,  d + 4096);
    gload16(s +  64*rb,  d + 8192);
    gload16(s +  96*rb,  d + 12288);
    gload16(s + 128*rb,  d + 16384);
    gload16(s + 160*rb,  d + 20480);
  };

  f32x4 z = {0.f,0.f,0.f,0.f};
  f32x4 acc[4][6];
  #pragma unroll
  for (int i=0;i<4;i++){
    #pragma unroll
    for (int j=0;j<6;j++) acc[i][j] = z;
  }

  const int nt = K >> 6;           // K-tiles of 64 bf16
  stA(0, 0); stB(0, 0);            // 10 loads
  if (nt > 1) { stB(1, 1);         // +6
    asm volatile("s_waitcnt vmcnt(6)" ::: "memory");   // tile0's 10 complete
  } else {
    asm volatile("s_waitcnt vmcnt(0)" ::: "memory");
  }
  __builtin_amdgcn_s_barrier();
  asm volatile("" ::: "memory");

  const int lx7 = ln & 7;

  for (int t = 0; t < nt; ++t){
    const int cur = t & 1;
    const char* bufc = smem + cur*40960;

    // ---- phase 0: all B frags + A m-frags 0..1; stage A(t+1) ----
    FragU bfr[6][2];
    #pragma unroll
    for (int ni=0; ni<6; ni++){
      const int rofs = 16384 + (wn*96 + ni*16 + ln)*128;
      #pragma unroll
      for (int ks=0; ks<2; ks++)
        bfr[ni][ks].q = *reinterpret_cast<const u32x4*>(bufc + rofs + (((ks*4+lg)^lx7)<<4));
    }
    FragU af[2][2];
    #pragma unroll
    for (int mf=0; mf<2; mf++){
      const int rofs = (wm*64 + mf*16 + ln)*128;
      #pragma unroll
      for (int ks=0; ks<2; ks++)
        af[mf][ks].q = *reinterpret_cast<const u32x4*>(bufc + rofs + (((ks*4+lg)^lx7)<<4));
    }
    if (t+1 < nt) stA(cur^1, t+1);
    __builtin_amdgcn_s_barrier();
    __builtin_amdgcn_s_setprio(1);
    #pragma unroll
    for (int ks=0; ks<2; ks++){
      #pragma unroll
      for (int mf=0; mf<2; mf++){
        #pragma unroll
        for (int ni=0; ni<6; ni++)
          acc[mf][ni] = __builtin_amdgcn_mfma_f32_16x16x32_bf16(af[mf][ks].v, bfr[ni][ks].v, acc[mf][ni], 0,0,0);
      }
    }
    __builtin_amdgcn_s_setprio(0);
    // fence: all waves' B-frag reads done; licenses stB(t+2) into this buffer.
    asm volatile("s_waitcnt lgkmcnt(0)" ::: "memory");
    __builtin_amdgcn_s_barrier();

    // ---- phase 1: A m-frags 2..3; stage B(t+2) -> B[cur] ----
    FragU ag[2][2];
    #pragma unroll
    for (int mf=0; mf<2; mf++){
      const int rofs = (wm*64 + (mf+2)*16 + ln)*128;
      #pragma unroll
      for (int ks=0; ks<2; ks++)
        ag[mf][ks].q = *reinterpret_cast<const u32x4*>(bufc + rofs + (((ks*4+lg)^lx7)<<4));
    }
    if (t+2 < nt) stB(cur, t+2);
    __builtin_amdgcn_s_barrier();
    __builtin_amdgcn_s_setprio(1);
    #pragma unroll
    for (int ks=0; ks<2; ks++){
      #pragma unroll
      for (int mf=0; mf<2; mf++){
        #pragma unroll
        for (int ni=0; ni<6; ni++)
          acc[mf+2][ni] = __builtin_amdgcn_mfma_f32_16x16x32_bf16(ag[mf][ks].v, bfr[ni][ks].v, acc[mf+2][ni], 0,0,0);
      }
    }
    __builtin_amdgcn_s_setprio(0);
    // ---- iteration boundary: counted wait (never 0 mid-loop) ----
    if (t+1 < nt){
      if (t+2 < nt) asm volatile("s_waitcnt vmcnt(6)" ::: "memory");
      else          asm volatile("s_waitcnt vmcnt(0)" ::: "memory");
    }
    __builtin_amdgcn_s_barrier();
    asm volatile("" ::: "memory");
  }

  #pragma unroll
  for (int mi=0; mi<4; mi++){
    #pragma unroll
    for (int ni=0; ni<6; ni++){
      const int row0 = bm*128 + wm*64 + mi*16 + lg*4;
      const int col  = bn*192 + wn*96 + ni*16 + ln;
      #pragma unroll
      for (int r=0; r<4; r++)
        C[(size_t)(row0+r)*N + col] = acc[mi][ni][r];
    }
  }
}

// ---------------------------------------------------------------------------
// 128x128-tile bf16 GEMM (grid 512 = 2 blocks/CU for M=2048,N=4096).
// 4 waves (2Mx2N), wave tile 64x64, dbuf 64KB LDS, counted vmcnt(4).
// ---------------------------------------------------------------------------
__global__ __launch_bounds__(256, 2)
void gemm_pkB2(const u16* __restrict__ A, const u16* __restrict__ B,
               float* __restrict__ C, int M, int N, int K)  // K = bf16 per row
{
  extern __shared__ char smem[];   // 65536 B: [buf2][ A 16KB | B 16KB ]
  const int tid  = threadIdx.x;
  const int lane = tid & 63;
  const int w    = tid >> 6;       // 0..3
  const int wm = w >> 1, wn = w & 1;
  const int ln = lane & 15, lg = lane >> 4;

  const int nbm = M >> 7, nbn = N >> 7;
  const int nwg = nbm * nbn;
  const int swz = (blockIdx.x & 7) * (nwg >> 3) + (blockIdx.x >> 3);
  const int bm = swz % nbm, bn = swz / nbm;

  const size_t rb = (size_t)K * 2;           // row bytes
  const int lrow  = lane >> 3;               // 0..7
  const int lslot = (lane & 7) ^ (lrow & 7); // pre-swizzled source slot
  const char* As0 = (const char*)A + (size_t)(bm*128 + w*8 + lrow)*rb + lslot*16;
  const char* Bs0 = (const char*)B + (size_t)(bn*128 + w*8 + lrow)*rb + lslot*16;

  auto stA = [&](int buf, int t) {           // 4 issues: 128 rows
    const char* s = As0 + ((size_t)t << 7);
    char* d = smem + buf*32768 + w*1024;
    gload16(s,           d);
    gload16(s +  32*rb,  d + 4096);
    gload16(s +  64*rb,  d + 8192);
    gload16(s +  96*rb,  d + 12288);
  };
  auto stB = [&](int buf, int t) {           // 4 issues: 128 rows
    const char* s = Bs0 + ((size_t)t << 7);
    char* d = smem + buf*32768 + 16384 + w*1024;
    gload16(s,           d);
    gload16(s +  32*rb,  d + 4096);
    gload16(s +  64*rb,  d + 8192);
    gload16(s +  96*rb,  d + 12288);
  };

  f32x4 z = {0.f,0.f,0.f,0.f};
  f32x4 acc[4][4];
  #pragma unroll
  for (int i=0;i<4;i++){
    #pragma unroll
    for (int j=0;j<4;j++) acc[i][j] = z;
  }

  const int nt = K >> 6;           // K-tiles of 64 bf16
  stA(0, 0); stB(0, 0);            // 8 loads
  if (nt > 1) { stB(1, 1);         // +4
    asm volatile("s_waitcnt vmcnt(4)" ::: "memory");   // tile0's 8 complete
  } else {
    asm volatile("s_waitcnt vmcnt(0)" ::: "memory");
  }
  __builtin_amdgcn_s_barrier();
  asm volatile("" ::: "memory");

  const int lx7 = ln & 7;

  for (int t = 0; t < nt; ++t){
    const int cur = t & 1;
    const char* bufc = smem + cur*32768;

    // ---- phase 0: all B frags + A m-frags 0..1; stage A(t+1) ----
    FragU bfr[4][2];
    #pragma unroll
    for (int ni=0; ni<4; ni++){
      const int rofs = 16384 + (wn*64 + ni*16 + ln)*128;
      #pragma unroll
      for (int ks=0; ks<2; ks++)
        bfr[ni][ks].q = *reinterpret_cast<const u32x4*>(bufc + rofs + (((ks*4+lg)^lx7)<<4));
    }
    FragU af[2][2];
    #pragma unroll
    for (int mf=0; mf<2; mf++){
      const int rofs = (wm*64 + mf*16 + ln)*128;
      #pragma unroll
      for (int ks=0; ks<2; ks++)
        af[mf][ks].q = *reinterpret_cast<const u32x4*>(bufc + rofs + (((ks*4+lg)^lx7)<<4));
    }
    if (t+1 < nt) stA(cur^1, t+1);
    __builtin_amdgcn_s_barrier();
    __builtin_amdgcn_s_setprio(1);
    #pragma unroll
    for (int ks=0; ks<2; ks++){
      #pragma unroll
      for (int mf=0; mf<2; mf++){
        #pragma unroll
        for (int ni=0; ni<4; ni++)
          acc[mf][ni] = __builtin_amdgcn_mfma_f32_16x16x32_bf16(af[mf][ks].v, bfr[ni][ks].v, acc[mf][ni], 0,0,0);
      }
    }
    __builtin_amdgcn_s_setprio(0);
    asm volatile("s_waitcnt lgkmcnt(0)" ::: "memory");
    __builtin_amdgcn_s_barrier();

    // ---- phase 1: A m-frags 2..3; stage B(t+2) -> B[cur] ----
    FragU ag[2][2];
    #pragma unroll
    for (int mf=0; mf<2; mf++){
      const int rofs = (wm*64 + (mf+2)*16 + ln)*128;
      #pragma unroll
      for (int ks=0; ks<2; ks++)
        ag[mf][ks].q = *reinterpret_cast<const u32x4*>(bufc + rofs + (((ks*4+lg)^lx7)<<4));
    }
    if (t+2 < nt) stB(cur, t+2);
    __builtin_amdgcn_s_barrier();
    __builtin_amdgcn_s_setprio(1);
    #pragma unroll
    for (int ks=0; ks<2; ks++){
      #pragma unroll
      for (int mf=0; mf<2; mf++){
        #pragma unroll
        for (int ni=0; ni<4; ni++)
          acc[mf+2][ni] = __builtin_amdgcn_mfma_f32_16x16x32_bf16(ag[mf][ks].v, bfr[ni][ks].v, acc[mf+2][ni], 0,0,0);
      }
    }
    __builtin_amdgcn_s_setprio(0);
    if (t+1 < nt){
      if (t+2 < nt) asm volatile("s_waitcnt vmcnt(4)" ::: "memory");
      else          asm volatile("s_waitcnt vmcnt(0)" ::: "memory");
    }
    __builtin_amdgcn_s_barrier();
    asm volatile("" ::: "memory");
  }

  #pragma unroll
  for (int mi=0; mi<4; mi++){
    #pragma unroll
    for (int ni=0; ni<4; ni++){
      const int row0 = bm*128 + wm*64 + mi*16 + lg*4;
      const int col  = bn*128 + wn*64 + ni*16 + ln;
      #pragma unroll
      for (int r=0; r<4; r++)
        C[(size_t)(row0+r)*N + col] = acc[mi][ni][r];
    }
  }
}

// ---------------------------------------------------------------------------
// Per-head RMSNorm + partial RoPE + scatter new K/V (both bf16).
// ---------------------------------------------------------------------------
__global__ __launch_bounds__(256)
void norm_rope_scatter(float* __restrict__ qkv, const float* __restrict__ cosT,
                       const float* __restrict__ sinT, const int* __restrict__ positions,
                       const int* __restrict__ cache_seqlens,
                       const float* __restrict__ qw, const float* __restrict__ kw,
                       u16* __restrict__ k_all, u16* __restrict__ v_allT)
{
  const int t = blockIdx.x;
  const int lane = threadIdx.x & 63;
  const int w = threadIdx.x >> 6;
  const int b = t >> 9;        // QL = 512
  const int q = t & 511;
  const int pos  = positions[t];
  const int cpos = cache_seqlens[b] + q;
  for (int it=0; it<12; ++it){
    int h = it*4 + w;          // 0..47
    float* xp = qkv + (size_t)t*6144 + h*128 + 2*lane;
    float2 x = *reinterpret_cast<const float2*>(xp);
    if (h < 40){               // q + k heads get RMSNorm + RoPE
      float ss = x.x*x.x + x.y*x.y;
      #pragma unroll
      for (int mk=1; mk<64; mk<<=1) ss += __shfl_xor(ss, mk);
      float var = ss*(1.0f/128.0f) + 1e-6f;
      float rq = rsqrtf(var);
      rq = rq*(1.5f - 0.5f*var*rq*rq);   // Newton refine
      const float* wt = (h<32) ? qw : kw;
      x.x *= rq*wt[2*lane]; x.y *= rq*wt[2*lane+1];
      float px = __shfl_xor(x.x, 16);
      float py = __shfl_xor(x.y, 16);
      if (lane < 32){
        int ci = pos*32 + 2*(lane&15);
        float2 cc = *reinterpret_cast<const float2*>(cosT + ci);
        float2 sc = *reinterpret_cast<const float2*>(sinT + ci);
        if (lane < 16){ x.x = x.x*cc.x - px*sc.x; x.y = x.y*cc.y - py*sc.y; }
        else          { x.x = x.x*cc.x + px*sc.x; x.y = x.y*cc.y + py*sc.y; }
      }
    }
    if (h < 32){
      *reinterpret_cast<float2*>(xp) = x;   // q back in place (fp32)
    } else if (h < 40){
      u16* kp = k_all + ((size_t)(b*8 + (h-32))*1024 + cpos)*128 + 2*lane;
      kp[0] = bfhi(x.x); kp[1] = bfhi(x.y);
    } else {
      u16* vp = v_allT + ((size_t)(b*8 + (h-40))*128 + 2*lane)*1024 + cpos;
      vp[0]    = bfhi(x.x);
      vp[1024] = bfhi(x.y);
    }
  }
}

// ---------------------------------------------------------------------------
// Fused GQA causal attention v8: QBLK=128 (8 waves), KVBLK=64 -- 32 MFMA per
// sync step.  All-bf16, async dbuf K/V staging (4 gload_lds issues/tile,
// counted vmcnt(4)), natural dispatch order, no-max softmax, deferred
// l-reduce, bf16 output.  LDS 80KB -> 2 blocks/CU, grid 512.
// ---------------------------------------------------------------------------
__global__ __launch_bounds__(512)
void attn_fused8(const float* __restrict__ qkv, const u16* __restrict__ k_all,
                 const u16* __restrict__ v_allT, const int* __restrict__ cache_seqlens,
                 u16* __restrict__ attnO)
{
  extern __shared__ char smem[];          // 80KB: K dbuf 32K | V dbuf 32K | P 16K
  const int tid = threadIdx.x, lane = tid&63, w = tid>>6;   // w 0..7
  const int ln = lane&15, lg = lane>>4;
  const int id = blockIdx.x;
  const int qt = id & 3, g = (id>>2)&3, kvh = (id>>4)&7, b = id>>7;
  const int cs = cache_seqlens[b];
  const int h  = kvh*4 + g;
  const int q0 = qt*128 + w*16;
  const float SCALE = 0.08838834764831845f;  // 1/sqrt(128)
  f32x4 z = {0.f,0.f,0.f,0.f};

  FragU qf[4];
  {
    const float* qp = qkv + (size_t)(b*512 + q0 + ln)*6144 + h*128;
    #pragma unroll
    for (int ks=0; ks<4; ks++){
      int d0 = ks*32 + lg*8;
      float4 a = *reinterpret_cast<const float4*>(qp + d0);
      float4 c = *reinterpret_cast<const float4*>(qp + d0 + 4);
      qf[ks].q = (u32x4){
        (u32)bfhi(a.x*SCALE) | ((u32)bfhi(a.y*SCALE)<<16),
        (u32)bfhi(a.z*SCALE) | ((u32)bfhi(a.w*SCALE)<<16),
        (u32)bfhi(c.x*SCALE) | ((u32)bfhi(c.y*SCALE)<<16),
        (u32)bfhi(c.z*SCALE) | ((u32)bfhi(c.w*SCALE)<<16) };
    }
  }
  f32x4 O[8];
  #pragma unroll
  for (int i=0;i<8;i++) O[i] = z;
  float lacc[4] = {0.f,0.f,0.f,0.f};
  const int prow0 = cs + q0 + lg*4;
  const int nt = (cs + qt*128 + 128 + 63) >> 6;
  const char* kbase = (const char*)(k_all  + (size_t)(b*8+kvh)*1024*128);
  const char* vbase = (const char*)(v_allT + (size_t)(b*8+kvh)*128*1024);

  auto stK = [&](int buf, int t){            // 2 issues: 64 rows x 256B (16KB)
    #pragma unroll
    for (int i=0;i<2;i++){
      int row = i*32 + w*4 + (lane>>4);
      const char* s = kbase + (size_t)(t*64 + row)*256 + (((lane&15) ^ (row&7))<<4);
      gload16(s, smem + buf*16384 + i*8192 + w*1024);
    }
  };
  auto stV = [&](int buf, int t){            // 2 issues: 128 d-rows x 128B (16KB)
    #pragma unroll
    for (int i=0;i<2;i++){
      int row = i*64 + w*8 + (lane>>3);
      const char* s = vbase + (size_t)row*2048 + (size_t)t*128 + (((lane&7) ^ (row&7))<<4);
      gload16(s, smem + 32768 + buf*16384 + i*8192 + w*1024);
    }
  };

  stK(0, 0); stV(0, 0);
  if (nt > 1){ stK(1, 1); stV(1, 1); }

  for (int tile=0; tile<nt; ++tile){
    const int cur = tile & 1;
    const int kv0 = tile*64;
    // wait tile's 4 loads; leave tile+1's 4 in flight
    if (tile+1 < nt) asm volatile("s_waitcnt vmcnt(4)" ::: "memory");
    else             asm volatile("s_waitcnt vmcnt(0)" ::: "memory");
    __builtin_amdgcn_s_barrier();

    // ---- S = Q K^T (bf16, D=128): 4 ks-steps x 4 kv-groups ----
    const u16* Kc = (const u16*)(smem + cur*16384);
    f32x4 s[4]; s[0]=z; s[1]=z; s[2]=z; s[3]=z;
    #pragma unroll
    for (int ks=0; ks<4; ks++){
      int so = ((ks*4+lg) ^ (ln&7)) << 3;
      #pragma unroll
      for (int n=0; n<4; n++){
        FragU kf;
        kf.q = *reinterpret_cast<const u32x4*>(&Kc[(n*16+ln)*128 + so]);
        s[n] = __builtin_amdgcn_mfma_f32_16x16x32_bf16(qf[ks].v, kf.v, s[n], 0,0,0);
      }
    }

    // ---- no-max softmax: p = exp(s), causal mask only on boundary tiles ----
    float pv[4][4];
    if (kv0 + 63 <= cs + q0){          // interior: wave-uniform, no mask
      #pragma unroll
      for (int n=0;n<4;n++){
        #pragma unroll
        for (int r=0;r<4;r++) pv[n][r] = __expf(s[n][r]);
      }
    } else {
      #pragma unroll
      for (int n=0;n<4;n++){
        #pragma unroll
        for (int r=0;r<4;r++){
          bool ok = (kv0 + n*16 + ln) <= (prow0 + r);
          pv[n][r] = ok ? __expf(s[n][r]) : 0.f;
        }
      }
    }
    #pragma unroll
    for (int r=0;r<4;r++) lacc[r] += (pv[0][r] + pv[1][r]) + (pv[2][r] + pv[3][r]);

    // ---- P -> LDS bf16 [16 q][64 kv] per wave (128B rows, 8-slot swizzle) ----
    #pragma unroll
    for (int n=0;n<4;n++){
      #pragma unroll
      for (int rp=0; rp<2; rp++){
        float p0 = pv[n][rp*2], p1 = pv[n][rp*2+1];
        u32 hpk;
        asm("v_cvt_pk_bf16_f32 %0, %1, %2" : "=v"(hpk) : "v"(p0), "v"(p1));
        int col  = n*16 + ln;
        int row0 = lg*4 + rp*2;        // even; row0+1 shares swizzle via (row>>1)
        int b0 = w*2048 + row0*128 + ((((col>>3) ^ ((row0>>1)&7)))<<4) + (col&7)*2;
        *(u16*)(smem + 65536 + b0)       = (u16)hpk;
        *(u16*)(smem + 65536 + b0 + 128) = (u16)(hpk >> 16);
      }
    }
    FragU pa[2];
    #pragma unroll
    for (int ks2=0; ks2<2; ks2++)
      pa[ks2].q = *reinterpret_cast<const u32x4*>(
          smem + 65536 + w*2048 + ln*128 + (((ks2*4+lg) ^ ((ln>>1)&7))<<4));

    // ---- O += P x V (16 MFMAs: 8 d-frags x 2 k-halves) ----
    const char* Vb = smem + 32768 + cur*16384;
    #pragma unroll
    for (int nf=0; nf<8; nf++){
      int dr = nf*16 + ln;
      #pragma unroll
      for (int ks2=0; ks2<2; ks2++){
        FragU vf;
        vf.q = *reinterpret_cast<const u32x4*>(Vb + dr*128 + (((ks2*4+lg) ^ (dr&7))<<4));
        O[nf] = __builtin_amdgcn_mfma_f32_16x16x32_bf16(pa[ks2].v, vf.v, O[nf], 0,0,0);
      }
    }
    asm volatile("s_waitcnt lgkmcnt(0)" ::: "memory");
    __builtin_amdgcn_s_barrier();
    if (tile+2 < nt){ stK(cur, tile+2); stV(cur, tile+2); }
  }

  // deferred row-sum reduce (once)
  #pragma unroll
  for (int off=1; off<16; off<<=1){
    #pragma unroll
    for (int r=0;r<4;r++) lacc[r] += __shfl_xor(lacc[r], off);
  }
  float il[4];
  #pragma unroll
  for (int r=0;r<4;r++) il[r] = 1.0f / lacc[r];
  u16* op = attnO + (size_t)(b*512 + q0 + lg*4)*4096 + h*128 + ln;
  #pragma unroll
  for (int nf=0; nf<8; nf++){
    #pragma unroll
    for (int r=0;r<4;r++)
      op[(size_t)r*4096 + nf*16] = bfhi(O[nf][r] * il[r]);
  }
}

// ---------------------------------------------------------------------------
extern "C" void kernel_launch(void* const* d_in, const int* in_sizes, int n_in,
                              void* d_out, int out_size, void* d_ws, size_t ws_size,
                              hipStream_t stream) {
  const float* hidden    = (const float*)d_in[0];
  const float* cosT      = (const float*)d_in[1];
  const float* sinT      = (const float*)d_in[2];
  const int*   positions = (const int*)  d_in[3];
  const float* k_cache   = (const float*)d_in[4];
  const float* v_cache   = (const float*)d_in[5];
  const int*   page_tab  = (const int*)  d_in[6];
  const int*   cache_sl  = (const int*)  d_in[7];
  const float* qkv_w     = (const float*)d_in[9];
  const float* o_w       = (const float*)d_in[10];
  const float* qnw       = (const float*)d_in[11];
  const float* knw       = (const float*)d_in[12];
  float* out = (float*)d_out;

  float* qkv   = (float*)d_ws;                   // 12582912 f32
  u16* k_all   = (u16*)(qkv + 12582912);         // 4194304 u16
  u16* v_allT  = k_all  + 4194304;               // 4194304 u16
  u16* attnPk  = v_allT + 4194304;               // 8388608 u16
  u16* hidPk   = attnPk + 8388608;               // 8388608 u16
  u16* qkvwPk  = hidPk  + 8388608;               // 25165824 u16
  u16* owPk    = qkvwPk + 25165824;              // 16777216 u16
  (void)in_sizes; (void)n_in; (void)out_size; (void)ws_size;

  (void)hipFuncSetAttribute(reinterpret_cast<const void*>(gemm_pkA2),
                            hipFuncAttributeMaxDynamicSharedMemorySize, 81920);
  (void)hipFuncSetAttribute(reinterpret_cast<const void*>(gemm_pkB2),
                            hipFuncAttributeMaxDynamicSharedMemorySize, 65536);
  (void)hipFuncSetAttribute(reinterpret_cast<const void*>(attn_fused8),
                            hipFuncAttributeMaxDynamicSharedMemorySize, 81920);

  hipLaunchKernelGGL(prep_all, dim3(3072), dim3(256), 0, stream,
                     hidden, hidPk, 2097152,
                     qkv_w, qkvwPk, 6291456,
                     o_w, owPk, 4194304,
                     k_cache, v_cache, page_tab, k_all, v_allT);
  hipLaunchKernelGGL(gemm_pkA2, dim3(512), dim3(256), 81920, stream,
                     hidPk, qkvwPk, qkv, 2048, 6144, 4096);
  hipLaunchKernelGGL(norm_rope_scatter, dim3(2048), dim3(256), 0, stream,
                     qkv, cosT, sinT, positions, cache_sl, qnw, knw, k_all, v_allT);
  hipLaunchKernelGGL(attn_fused8, dim3(512), dim3(512), 81920, stream,
                     qkv, k_all, v_allT, cache_sl, attnPk);
  hipLaunchKernelGGL(gemm_pkB2, dim3(512), dim3(256), 65536, stream,
                     attnPk, owPk, out, 2048, 4096, 4096);
}